// Round 7
// baseline (1975.862 us; speedup 1.0000x reference)
//
#include <hip/hip_runtime.h>
#include <hip/hip_bf16.h>

#define MC 4096
#define DD 128
#define NHH 4
#define DH 32
#define FFD 256
#define NS 3
#define NSPLIT 4
#define PLEN 1024

typedef __attribute__((ext_vector_type(8))) short short8_t;
typedef __attribute__((ext_vector_type(4))) float f32x4;

__device__ __forceinline__ int getM(int s, const int* M0, const int* M1, const int* M2) {
    return (s == 0) ? *M0 : (s == 1) ? *M1 : *M2;
}

__device__ __forceinline__ unsigned short f2bf(float f) {
    unsigned int u = __float_as_uint(f);
    u += 0x7FFFu + ((u >> 16) & 1u);   // RNE
    return (unsigned short)(u >> 16);
}

// ---------------- parent maps + scale-0 histogram in one pass ----------------
__global__ void k_parent(const int* __restrict__ inv0, const int* __restrict__ inv1,
                         const int* __restrict__ inv2,
                         int* __restrict__ parent10, int* __restrict__ parent21,
                         int* __restrict__ cnt, int N)
{
    int n = blockIdx.x * blockDim.x + threadIdx.x;
    if (n >= N) return;
    int i0 = inv0[n];
    parent10[i0] = inv1[n];   // duplicate writes all agree (grids nest)
    parent21[inv1[n]] = inv2[n];
    atomicAdd(&cnt[i0], 1);
}

// ---------------- exclusive scan over MC=4096 bins, single block 1024 thr ----------------
__global__ void k_scan(const int* __restrict__ cnt, int* __restrict__ offs)
{
    __shared__ int arr[1024];
    int tid = threadIdx.x;
    int base = tid * 4;
    int c0 = cnt[base], c1 = cnt[base + 1], c2 = cnt[base + 2], c3 = cnt[base + 3];
    int tot = c0 + c1 + c2 + c3;
    arr[tid] = tot;
    __syncthreads();
    for (int off = 1; off < 1024; off <<= 1) {
        int v = (tid >= off) ? arr[tid - off] : 0;
        __syncthreads();
        arr[tid] += v;
        __syncthreads();
    }
    int excl = arr[tid] - tot;
    offs[base] = excl;
    offs[base + 1] = excl + c0;
    offs[base + 2] = excl + c0 + c1;
    offs[base + 3] = excl + c0 + c1 + c2;
}

// ---------------- placement: order[] groups particles by voxel ----------------
__global__ void k_place(const int* __restrict__ inv0, const int* __restrict__ offs,
                        int* __restrict__ fill, int* __restrict__ order, int N)
{
    int n = blockIdx.x * blockDim.x + threadIdx.x;
    if (n >= N) return;
    int i0 = inv0[n];
    int pos = offs[i0] + atomicAdd(&fill[i0], 1);
    order[pos] = n;
}

// ---------------- pooled sums, no fp atomics: one block per voxel ----------------
__global__ __launch_bounds__(256) void k_pool(const float* __restrict__ h,
                                              const int* __restrict__ order,
                                              const int* __restrict__ offs,
                                              const int* __restrict__ cnt,
                                              float* __restrict__ sum0, float* __restrict__ cnt0,
                                              const int* __restrict__ M0)
{
    int v = blockIdx.x;
    if (v >= *M0) return;
    int beg = offs[v], len = cnt[v];
    int tid = threadIdx.x;
    int d = tid & 127, half = tid >> 7;
    float acc = 0.f;
    for (int j = half; j < len; j += 2) {
        int row = order[beg + j];
        acc += h[(size_t)row * DD + d];
    }
    __shared__ float red[DD];
    if (half == 1) red[d] = acc;
    __syncthreads();
    if (half == 0) {
        acc += red[d];
        sum0[(size_t)v * DD + d] = acc;
        if (d == 0) cnt0[v] = (float)len;
    }
}

// ---------------- roll coarse sums up the hierarchy ----------------
__global__ void k_rollup(const float* __restrict__ sumSrc, const float* __restrict__ cntSrc,
                         const int* __restrict__ parent,
                         float* __restrict__ sumDst, float* __restrict__ cntDst,
                         const int* __restrict__ Msrc, int cap)
{
    int idx = blockIdx.x * blockDim.x + threadIdx.x;   // < cap*DD
    int v = idx >> 7, d = idx & 127;
    int Ms = *Msrc;
    if (Ms > cap) Ms = cap;
    if (v >= Ms) return;
    int p = parent[v];
    atomicAdd(&sumDst[(size_t)p * DD + d], sumSrc[idx]);
    if (d == 0) atomicAdd(&cntDst[p], cntSrc[v]);
}

// ---------------- divide by clamped counts ----------------
__global__ void k_finalize(float* __restrict__ macro, const float* __restrict__ counts,
                           const int* M0, const int* M1, const int* M2)
{
    int idx = blockIdx.x * blockDim.x + threadIdx.x;  // < NS*MC*DD
    int s = idx / (MC * DD);
    int r = (idx >> 7) & (MC - 1);
    if (r >= getM(s, M0, M1, M2)) return;
    float c = counts[s * MC + r];
    macro[idx] /= fmaxf(c, 1.0f);
}

// ---------------- b0frag: MFMA B-operand fragments of Wf[:, :128] in bf16 ----------------
// b0f[((nt*4+kt)*64 + l)*8 + j] = bf16( Wf[nt*16 + (l&15)][kt*32 + (l>>4)*8 + j] )
__global__ void k_b0frag(const float* __restrict__ Wf, unsigned short* __restrict__ b0f)
{
    int idx = blockIdx.x * 256 + threadIdx.x;  // 16384
    int j = idx & 7, l = (idx >> 3) & 63, kt = (idx >> 9) & 3, nt = idx >> 11;
    int d = nt * 16 + (l & 15);
    int k = kt * 32 + (l >> 4) * 8 + j;
    b0f[idx] = f2bf(Wf[(size_t)d * (4 * DD) + k]);
}

// ---------------- qkv = macro @ Wqkv[s].T + bqkv[s], 8 rows/block ----------------
__global__ void k_qkv(const float* __restrict__ macro, const float* __restrict__ Wqkv,
                      const float* __restrict__ bqkv, float* __restrict__ qkv,
                      const int* M0, const int* M1, const int* M2)
{
    int s = blockIdx.y;
    int Ms = getM(s, M0, M1, M2);
    int row0 = blockIdx.x * 8;
    if (row0 >= Ms) return;
    __shared__ __align__(16) float mac[8][DD];
    int tid = threadIdx.x;
    for (int e = tid; e < 8 * DD; e += 256) {
        int r = e >> 7, d = e & 127;
        int row = row0 + r;
        mac[r][d] = (row < Ms) ? macro[(size_t)s * MC * DD + (size_t)row * DD + d] : 0.0f;
    }
    __syncthreads();
    for (int j = tid; j < 3 * DD; j += 256) {
        const float* w = Wqkv + ((size_t)s * 3 * DD + j) * DD;
        float b = bqkv[s * 3 * DD + j];
        float acc[8];
#pragma unroll
        for (int r = 0; r < 8; ++r) acc[r] = b;
        for (int k = 0; k < DD; k += 4) {
            float4 w4 = *(const float4*)(w + k);
#pragma unroll
            for (int r = 0; r < 8; ++r) {
                float4 m4 = *(const float4*)&mac[r][k];
                acc[r] += w4.x * m4.x + w4.y * m4.y + w4.z * m4.z + w4.w * m4.w;
            }
        }
        for (int r = 0; r < 8; ++r) {
            int row = row0 + r;
            if (row < Ms) qkv[((size_t)s * MC + row) * (3 * DD) + j] = acc[r];
        }
    }
}

// ---------------- flash attention partials: LDS-staged K/V, register p/m/l/o ----------------
// ALL p[] loops fully unrolled: partial unroll put p[16] in scratch (rule #20),
// generating ~1 GB/dispatch of scratch traffic (R5 counters: WRITE_SIZE 985 MB, VGPR 60).
__global__ __launch_bounds__(256) void k_attn_part(const float* __restrict__ qkv,
                                                   float* __restrict__ part_o,
                                                   float* __restrict__ part_ml,
                                                   const int* M0, const int* M1, const int* M2)
{
    int z = blockIdx.z;
    int s = z / NSPLIT, part = z % NSPLIT;
    int head = blockIdx.y;
    int Ms = getM(s, M0, M1, M2);
    int q0 = blockIdx.x * 64;
    if (q0 >= Ms) return;
    int kstart = part * PLEN;
    if (kstart >= Ms) return;
    int kend = kstart + PLEN; if (kend > Ms) kend = Ms;

    __shared__ __align__(16) float ks[64][36];
    __shared__ __align__(16) float vs[64][36];

    int tid = threadIdx.x;
    int qi = tid >> 2, sub = tid & 3;
    int qrow = q0 + qi;

    const float* base = qkv + (size_t)s * MC * 3 * DD;
    const float* Qb = base + head * DH;
    const float* Kb = base + DD + head * DH;
    const float* Vb = base + 2 * DD + head * DH;

    float4 q4[8];
#pragma unroll
    for (int r = 0; r < 8; ++r) q4[r] = make_float4(0.f, 0.f, 0.f, 0.f);
    if (qrow < Ms) {
#pragma unroll
        for (int r = 0; r < 8; ++r) q4[r] = *(const float4*)(Qb + (size_t)qrow * 3 * DD + r * 4);
    }

    float4 o4[8];
#pragma unroll
    for (int r = 0; r < 8; ++r) o4[r] = make_float4(0.f, 0.f, 0.f, 0.f);
    float m = -1e30f, l = 0.f;
    const float scale = 0.1767766952966369f;  // 1/sqrt(32)

    for (int kb = kstart; kb < kend; kb += 64) {
        __syncthreads();   // previous chunk's readers done
        for (int e = tid; e < 64 * 8; e += 256) {
            int r = e >> 3, qq = e & 7;
            int key = kb + r;
            float4 kv4 = make_float4(0.f, 0.f, 0.f, 0.f);
            float4 vv4 = make_float4(0.f, 0.f, 0.f, 0.f);
            if (key < kend) {
                kv4 = *(const float4*)(Kb + (size_t)key * 3 * DD + qq * 4);
                vv4 = *(const float4*)(Vb + (size_t)key * 3 * DD + qq * 4);
            }
            *(float4*)&ks[r][qq * 4] = kv4;
            *(float4*)&vs[r][qq * 4] = vv4;
        }
        __syncthreads();

        float p[16];
#pragma unroll
        for (int j = 0; j < 16; ++j) {
            int kk = j * 4 + sub;
            float acc = 0.f;
#pragma unroll
            for (int r = 0; r < 8; ++r) {
                float4 kv = *(const float4*)&ks[kk][r * 4];
                acc += q4[r].x * kv.x + q4[r].y * kv.y + q4[r].z * kv.z + q4[r].w * kv.w;
            }
            p[j] = (kb + kk < kend) ? acc * scale : -1e30f;
        }
        float lmax = p[0];
#pragma unroll
        for (int j = 1; j < 16; ++j) lmax = fmaxf(lmax, p[j]);
        lmax = fmaxf(lmax, __shfl_xor(lmax, 1));
        lmax = fmaxf(lmax, __shfl_xor(lmax, 2));
        float mnew = fmaxf(m, lmax);
        float alpha = __expf(m - mnew);
        m = mnew;
        l *= alpha;
#pragma unroll
        for (int r = 0; r < 8; ++r) {
            o4[r].x *= alpha; o4[r].y *= alpha; o4[r].z *= alpha; o4[r].w *= alpha;
        }
        float lsum = 0.f;
#pragma unroll
        for (int j = 0; j < 16; ++j) {
            float e = __expf(p[j] - mnew);
            p[j] = e;
            lsum += e;
        }
#pragma unroll
        for (int j = 0; j < 16; ++j) {
            int kk = j * 4 + sub;
            float pv = p[j];
#pragma unroll
            for (int r = 0; r < 8; ++r) {
                float4 vv = *(const float4*)&vs[kk][r * 4];
                o4[r].x += pv * vv.x; o4[r].y += pv * vv.y;
                o4[r].z += pv * vv.z; o4[r].w += pv * vv.w;
            }
        }
        lsum += __shfl_xor(lsum, 1);
        lsum += __shfl_xor(lsum, 2);
        l += lsum;
    }

#pragma unroll
    for (int r = 0; r < 8; ++r) {
        o4[r].x += __shfl_xor(o4[r].x, 1); o4[r].y += __shfl_xor(o4[r].y, 1);
        o4[r].z += __shfl_xor(o4[r].z, 1); o4[r].w += __shfl_xor(o4[r].w, 1);
        o4[r].x += __shfl_xor(o4[r].x, 2); o4[r].y += __shfl_xor(o4[r].y, 2);
        o4[r].z += __shfl_xor(o4[r].z, 2); o4[r].w += __shfl_xor(o4[r].w, 2);
    }

    int rec = ((s * NHH + head) * 64 + blockIdx.x) * NSPLIT + part;
    float* po = part_o + (size_t)rec * 2048;
    *(float4*)(po + qi * 32 + sub * 8)     = o4[2 * sub];
    *(float4*)(po + qi * 32 + sub * 8 + 4) = o4[2 * sub + 1];
    if (sub == 0) {
        part_ml[rec * 128 + qi] = m;
        part_ml[rec * 128 + 64 + qi] = l;
    }
}

// ---------------- merge split-K partials ----------------
__global__ void k_attn_comb(const float* __restrict__ part_o, const float* __restrict__ part_ml,
                            float* __restrict__ attno,
                            const int* M0, const int* M1, const int* M2)
{
    int s = blockIdx.z, head = blockIdx.y;
    int Ms = getM(s, M0, M1, M2);
    int q0 = blockIdx.x * 64;
    if (q0 >= Ms) return;
    int tid = threadIdx.x;
    int qi = tid >> 2, sub = tid & 3;
    int nparts = (Ms + PLEN - 1) / PLEN;
    if (nparts > NSPLIT) nparts = NSPLIT;
    int recbase = ((s * NHH + head) * 64 + blockIdx.x) * NSPLIT;

    float m = -1e30f;
    for (int p = 0; p < nparts; ++p)
        m = fmaxf(m, part_ml[(recbase + p) * 128 + qi]);
    float L = 0.f;
    float4 O0 = make_float4(0.f, 0.f, 0.f, 0.f);
    float4 O1 = make_float4(0.f, 0.f, 0.f, 0.f);
    for (int p = 0; p < nparts; ++p) {
        float mp = part_ml[(recbase + p) * 128 + qi];
        float lp = part_ml[(recbase + p) * 128 + 64 + qi];
        float w = __expf(mp - m);
        L += lp * w;
        const float* po = part_o + (size_t)(recbase + p) * 2048;
        float4 a = *(const float4*)(po + qi * 32 + sub * 4);
        float4 b = *(const float4*)(po + qi * 32 + (sub + 4) * 4);
        O0.x += a.x * w; O0.y += a.y * w; O0.z += a.z * w; O0.w += a.w * w;
        O1.x += b.x * w; O1.y += b.y * w; O1.z += b.z * w; O1.w += b.w * w;
    }
    if (q0 + qi < Ms) {
        float inv = 1.0f / fmaxf(L, 1e-30f);
        size_t orow = ((size_t)s * MC + q0 + qi) * DD + head * DH;
        float4 r0 = make_float4(O0.x * inv, O0.y * inv, O0.z * inv, O0.w * inv);
        float4 r1 = make_float4(O1.x * inv, O1.y * inv, O1.z * inv, O1.w * inv);
        *(float4*)(attno + orow + sub * 4) = r0;
        *(float4*)(attno + orow + (sub + 4) * 4) = r1;
    }
}

// ---------------- x1 = LN1(macro + attno @ Wo.T + bo) ----------------
__global__ void k_ln1(const float* __restrict__ macro, const float* __restrict__ attno,
                      const float* __restrict__ Wo, const float* __restrict__ bo,
                      const float* __restrict__ g, const float* __restrict__ b,
                      float* __restrict__ x1,
                      const int* M0, const int* M1, const int* M2)
{
    int s = blockIdx.y;
    int Ms = getM(s, M0, M1, M2);
    int m = blockIdx.x;
    if (m >= Ms) return;
    __shared__ __align__(16) float os[DD];
    __shared__ float red[4];
    int d = threadIdx.x;  // 128
    size_t row = (size_t)s * MC + m;
    os[d] = attno[row * DD + d];
    __syncthreads();
    const float* w = Wo + ((size_t)s * DD + d) * DD;
    float acc = bo[s * DD + d];
    for (int k = 0; k < DD; k += 4) {
        float4 w4 = *(const float4*)(w + k);
        float4 m4 = *(const float4*)&os[k];
        acc += w4.x * m4.x + w4.y * m4.y + w4.z * m4.z + w4.w * m4.w;
    }
    float xin = macro[row * DD + d] + acc;
    float sum = xin, sq = xin * xin;
    for (int off = 32; off >= 1; off >>= 1) { sum += __shfl_xor(sum, off); sq += __shfl_xor(sq, off); }
    if ((d & 63) == 0) { red[d >> 6] = sum; red[2 + (d >> 6)] = sq; }
    __syncthreads();
    sum = red[0] + red[1]; sq = red[2] + red[3];
    float mean = sum * (1.0f / DD);
    float var = fmaxf(sq * (1.0f / DD) - mean * mean, 0.0f);
    float xh = (xin - mean) * rsqrtf(var + 1e-5f);
    x1[row * DD + d] = xh * g[s * DD + d] + b[s * DD + d];
}

// ---------------- x2 = LN2(x1 + relu(x1@W1.T+b1)@W2.T + b2) ----------------
__global__ void k_ffn(const float* __restrict__ x1,
                      const float* __restrict__ W1, const float* __restrict__ b1,
                      const float* __restrict__ W2, const float* __restrict__ b2,
                      const float* __restrict__ g, const float* __restrict__ bb,
                      float* __restrict__ x2,
                      const int* M0, const int* M1, const int* M2)
{
    int s = blockIdx.y;
    int Ms = getM(s, M0, M1, M2);
    int m = blockIdx.x;
    if (m >= Ms) return;
    __shared__ __align__(16) float xr[DD];
    __shared__ __align__(16) float ts[FFD];
    __shared__ float red[8];
    int tid = threadIdx.x;  // 256
    size_t row = (size_t)s * MC + m;
    if (tid < DD) xr[tid] = x1[row * DD + tid];
    __syncthreads();
    {
        const float* w = W1 + ((size_t)s * FFD + tid) * DD;
        float acc = b1[s * FFD + tid];
        for (int k = 0; k < DD; k += 4) {
            float4 w4 = *(const float4*)(w + k);
            float4 m4 = *(const float4*)&xr[k];
            acc += w4.x * m4.x + w4.y * m4.y + w4.z * m4.z + w4.w * m4.w;
        }
        ts[tid] = fmaxf(acc, 0.0f);
    }
    __syncthreads();
    float xin = 0.0f;
    if (tid < DD) {
        const float* w = W2 + ((size_t)s * DD + tid) * FFD;
        float acc = b2[s * DD + tid];
        for (int k = 0; k < FFD; k += 4) {
            float4 w4 = *(const float4*)(w + k);
            float4 m4 = *(const float4*)&ts[k];
            acc += w4.x * m4.x + w4.y * m4.y + w4.z * m4.z + w4.w * m4.w;
        }
        xin = xr[tid] + acc;
    }
    float sum = xin, sq = xin * xin;
    for (int off = 32; off >= 1; off >>= 1) { sum += __shfl_xor(sum, off); sq += __shfl_xor(sq, off); }
    if ((tid & 63) == 0) { red[tid >> 6] = sum; red[4 + (tid >> 6)] = sq; }
    __syncthreads();
    sum = red[0] + red[1] + red[2] + red[3];
    sq = red[4] + red[5] + red[6] + red[7];
    float mean = sum * (1.0f / DD);
    float var = fmaxf(sq * (1.0f / DD) - mean * mean, 0.0f);
    if (tid < DD) {
        float xh = (xin - mean) * rsqrtf(var + 1e-5f);
        x2[row * DD + tid] = xh * g[s * DD + tid] + bb[s * DD + tid];
    }
}

// ---------------- y_s = x2_s @ Wf[:, 128*(s+1):128*(s+2)].T ----------------
__global__ void k_yproj(const float* __restrict__ x2, const float* __restrict__ Wf,
                        float* __restrict__ y,
                        const int* M0, const int* M1, const int* M2)
{
    int s = blockIdx.y;
    int Ms = getM(s, M0, M1, M2);
    int m = blockIdx.x;
    if (m >= Ms) return;
    __shared__ __align__(16) float xr[DD];
    int d = threadIdx.x;  // 128
    size_t row = (size_t)s * MC + m;
    xr[d] = x2[row * DD + d];
    __syncthreads();
    const float* w = Wf + (size_t)d * (4 * DD) + (s + 1) * DD;
    float acc = 0.0f;
    for (int k = 0; k < DD; k += 4) {
        float4 w4 = *(const float4*)(w + k);
        float4 m4 = *(const float4*)&xr[k];
        acc += w4.x * m4.x + w4.y * m4.y + w4.z * m4.z + w4.w * m4.w;
    }
    y[row * DD + d] = acc;
}

// ---------------- out = h@B0 (bf16 MFMA) + y0[inv0]+y1[inv1]+y2[inv2] + bf ----------------
__global__ __launch_bounds__(256) void k_final(const float* __restrict__ h,
                                               const unsigned short* __restrict__ b0f,
                                               const float* __restrict__ y,
                                               const int* __restrict__ inv0,
                                               const int* __restrict__ inv1,
                                               const int* __restrict__ inv2,
                                               const float* __restrict__ bf,
                                               float* __restrict__ out, int N)
{
    __shared__ __align__(16) unsigned short hs[64][136];  // 272B row: 4-bank shift, 16B aligned
    __shared__ int ivs[3][64];
    int tid = threadIdx.x;
    int wave = tid >> 6, lane = tid & 63;
    int ntiles = (N + 63) >> 6;
    const float* y0 = y;
    const float* y1 = y + (size_t)MC * DD;
    const float* y2 = y + (size_t)2 * MC * DD;

    for (int t = blockIdx.x; t < ntiles; t += gridDim.x) {
        int pb = t * 64;
        __syncthreads();  // previous tile's readers done
        if (tid < 64) {
            int p = pb + tid;
            ivs[0][tid] = (p < N) ? inv0[p] : 0;
        } else if (tid < 128) {
            int p = pb + tid - 64;
            ivs[1][tid - 64] = (p < N) ? inv1[p] : 0;
        } else if (tid < 192) {
            int p = pb + tid - 128;
            ivs[2][tid - 128] = (p < N) ? inv2[p] : 0;
        }
        for (int e = tid; e < 64 * 32; e += 256) {   // 64 rows x 32 float4-units
            int row = e >> 5, u = e & 31;
            int p = pb + row;
            float4 v4 = make_float4(0.f, 0.f, 0.f, 0.f);
            if (p < N) v4 = *(const float4*)(h + (size_t)p * DD + u * 4);
            ushort4 b;
            b.x = f2bf(v4.x); b.y = f2bf(v4.y); b.z = f2bf(v4.z); b.w = f2bf(v4.w);
            *(ushort4*)&hs[row][u * 4] = b;
        }
        __syncthreads();

        short8_t afr[4];
#pragma unroll
        for (int kt = 0; kt < 4; ++kt)
            afr[kt] = *(const short8_t*)&hs[wave * 16 + (lane & 15)][kt * 32 + (lane >> 4) * 8];

#pragma unroll
        for (int nt = 0; nt < 8; ++nt) {
            f32x4 acc = {0.f, 0.f, 0.f, 0.f};
#pragma unroll
            for (int kt = 0; kt < 4; ++kt) {
                short8_t bfr = *(const short8_t*)(b0f + (size_t)((nt * 4 + kt) * 64 + lane) * 8);
                acc = __builtin_amdgcn_mfma_f32_16x16x32_bf16(afr[kt], bfr, acc, 0, 0, 0);
            }
            int d = nt * 16 + (lane & 15);
            float bias = bf[d];
#pragma unroll
            for (int reg = 0; reg < 4; ++reg) {
                int pl = wave * 16 + (lane >> 4) * 4 + reg;
                int p = pb + pl;
                if (p < N) {
                    int i0 = ivs[0][pl], i1 = ivs[1][pl], i2 = ivs[2][pl];
                    out[(size_t)p * DD + d] = acc[reg]
                        + y0[(size_t)i0 * DD + d] + y1[(size_t)i1 * DD + d]
                        + y2[(size_t)i2 * DD + d] + bias;
                }
            }
        }
    }
}

extern "C" void kernel_launch(void* const* d_in, const int* in_sizes, int n_in,
                              void* d_out, int out_size, void* d_ws, size_t ws_size,
                              hipStream_t stream) {
    (void)n_in; (void)out_size; (void)ws_size;
    const float* h   = (const float*)d_in[0];
    const int* inv0  = (const int*)d_in[2];
    const int* inv1  = (const int*)d_in[3];
    const int* inv2  = (const int*)d_in[4];
    const int* M0    = (const int*)d_in[5];
    const int* M1    = (const int*)d_in[6];
    const int* M2    = (const int*)d_in[7];
    const float* Wqkv = (const float*)d_in[8];
    const float* bqkv = (const float*)d_in[9];
    const float* Wo   = (const float*)d_in[10];
    const float* bo   = (const float*)d_in[11];
    const float* ln1s = (const float*)d_in[12];
    const float* ln1b = (const float*)d_in[13];
    const float* W1   = (const float*)d_in[14];
    const float* b1   = (const float*)d_in[15];
    const float* W2   = (const float*)d_in[16];
    const float* b2   = (const float*)d_in[17];
    const float* ln2s = (const float*)d_in[18];
    const float* ln2b = (const float*)d_in[19];
    const float* Wf   = (const float*)d_in[20];
    const float* bf   = (const float*)d_in[21];
    int N = in_sizes[0] / DD;

    float* ws      = (float*)d_ws;
    float* macro   = ws;                                    // NS*MC*DD
    float* counts  = macro + (size_t)NS * MC * DD;          // NS*MC
    float* qkvb    = counts + (size_t)NS * MC;              // NS*MC*3*DD
    float* attno   = qkvb + (size_t)NS * MC * 3 * DD;       // NS*MC*DD
    float* x1      = attno + (size_t)NS * MC * DD;          // NS*MC*DD
    float* x2      = x1 + (size_t)NS * MC * DD;             // NS*MC*DD
    float* yb      = x2 + (size_t)NS * MC * DD;             // NS*MC*DD
    float* b0f_f   = yb + (size_t)NS * MC * DD;             // DD*DD floats of space (b0f uses half)
    unsigned short* b0f = (unsigned short*)b0f_f;
    float* part_o  = b0f_f + (size_t)DD * DD;               // NS*NHH*64*NSPLIT*2048
    float* part_ml = part_o + (size_t)NS * NHH * 64 * NSPLIT * 2048;  // NS*NHH*64*NSPLIT*128
    int* ip        = (int*)(part_ml + (size_t)NS * NHH * 64 * NSPLIT * 128);
    int* parent10  = ip;                // MC
    int* parent21  = parent10 + MC;     // 512
    int* cnt_i     = parent21 + 512;    // MC
    int* fill      = cnt_i + MC;        // MC
    int* offs      = fill + MC;         // MC
    int* order     = offs + MC;         // N

    float* sum0 = macro;
    float* sum1 = macro + (size_t)1 * MC * DD;
    float* sum2 = macro + (size_t)2 * MC * DD;
    float* cnt0 = counts;
    float* cnt1 = counts + MC;
    float* cnt2 = counts + 2 * MC;

    hipMemsetAsync(macro, 0, ((size_t)NS * MC * DD + NS * MC) * sizeof(float), stream);
    hipMemsetAsync(cnt_i, 0, (size_t)2 * MC * sizeof(int), stream);

    int nb = (N + 255) / 256;
    k_parent<<<nb, 256, 0, stream>>>(inv0, inv1, inv2, parent10, parent21, cnt_i, N);
    k_scan<<<1, 1024, 0, stream>>>(cnt_i, offs);
    k_place<<<nb, 256, 0, stream>>>(inv0, offs, fill, order, N);
    k_pool<<<MC, 256, 0, stream>>>(h, order, offs, cnt_i, sum0, cnt0, M0);
    k_rollup<<<(MC * DD) / 256, 256, 0, stream>>>(sum0, cnt0, parent10, sum1, cnt1, M0, MC);
    k_rollup<<<(512 * DD) / 256, 256, 0, stream>>>(sum1, cnt1, parent21, sum2, cnt2, M1, 512);
    k_finalize<<<(NS * MC * DD) / 256, 256, 0, stream>>>(macro, counts, M0, M1, M2);
    k_b0frag<<<64, 256, 0, stream>>>(Wf, b0f);
    k_qkv<<<dim3(MC / 8, NS), 256, 0, stream>>>(macro, Wqkv, bqkv, qkvb, M0, M1, M2);
    k_attn_part<<<dim3(MC / 64, NHH, NS * NSPLIT), 256, 0, stream>>>(qkvb, part_o, part_ml, M0, M1, M2);
    k_attn_comb<<<dim3(MC / 64, NHH, NS), 256, 0, stream>>>(part_o, part_ml, attno, M0, M1, M2);
    k_ln1<<<dim3(MC, NS), 128, 0, stream>>>(macro, attno, Wo, bo, ln1s, ln1b, x1, M0, M1, M2);
    k_ffn<<<dim3(MC, NS), 256, 0, stream>>>(x1, W1, b1, W2, b2, ln2s, ln2b, x2, M0, M1, M2);
    k_yproj<<<dim3(MC, NS), 128, 0, stream>>>(x2, Wf, yb, M0, M1, M2);
    k_final<<<2048, 256, 0, stream>>>(h, b0f, yb, inv0, inv1, inv2, bf, (float*)d_out, N);
}

// Round 8
// 1001.095 us; speedup vs baseline: 1.9737x; 1.9737x over previous
//
#include <hip/hip_runtime.h>
#include <hip/hip_bf16.h>

#define MC 4096
#define DD 128
#define NHH 4
#define DH 32
#define FFD 256
#define NS 3
#define NSPLIT 4
#define PLEN 1024

typedef __attribute__((ext_vector_type(8))) short short8_t;
typedef __attribute__((ext_vector_type(4))) float f32x4;

__device__ __forceinline__ int getM(int s, const int* M0, const int* M1, const int* M2) {
    return (s == 0) ? *M0 : (s == 1) ? *M1 : *M2;
}

__device__ __forceinline__ unsigned short f2bf(float f) {
    unsigned int u = __float_as_uint(f);
    u += 0x7FFFu + ((u >> 16) & 1u);   // RNE
    return (unsigned short)(u >> 16);
}

// ---------------- parent maps + scale-0 histogram in one pass ----------------
__global__ void k_parent(const int* __restrict__ inv0, const int* __restrict__ inv1,
                         const int* __restrict__ inv2,
                         int* __restrict__ parent10, int* __restrict__ parent21,
                         int* __restrict__ cnt, int N)
{
    int n = blockIdx.x * blockDim.x + threadIdx.x;
    if (n >= N) return;
    int i0 = inv0[n];
    parent10[i0] = inv1[n];   // duplicate writes all agree (grids nest)
    parent21[inv1[n]] = inv2[n];
    atomicAdd(&cnt[i0], 1);
}

// ---------------- exclusive scan over MC=4096 bins, single block 1024 thr ----------------
__global__ void k_scan(const int* __restrict__ cnt, int* __restrict__ offs)
{
    __shared__ int arr[1024];
    int tid = threadIdx.x;
    int base = tid * 4;
    int c0 = cnt[base], c1 = cnt[base + 1], c2 = cnt[base + 2], c3 = cnt[base + 3];
    int tot = c0 + c1 + c2 + c3;
    arr[tid] = tot;
    __syncthreads();
    for (int off = 1; off < 1024; off <<= 1) {
        int v = (tid >= off) ? arr[tid - off] : 0;
        __syncthreads();
        arr[tid] += v;
        __syncthreads();
    }
    int excl = arr[tid] - tot;
    offs[base] = excl;
    offs[base + 1] = excl + c0;
    offs[base + 2] = excl + c0 + c1;
    offs[base + 3] = excl + c0 + c1 + c2;
}

// ---------------- placement: order[] groups particles by voxel ----------------
__global__ void k_place(const int* __restrict__ inv0, const int* __restrict__ offs,
                        int* __restrict__ fill, int* __restrict__ order, int N)
{
    int n = blockIdx.x * blockDim.x + threadIdx.x;
    if (n >= N) return;
    int i0 = inv0[n];
    int pos = offs[i0] + atomicAdd(&fill[i0], 1);
    order[pos] = n;
}

// ---------------- pooled sums, no fp atomics: one block per voxel ----------------
__global__ __launch_bounds__(256) void k_pool(const float* __restrict__ h,
                                              const int* __restrict__ order,
                                              const int* __restrict__ offs,
                                              const int* __restrict__ cnt,
                                              float* __restrict__ sum0, float* __restrict__ cnt0,
                                              const int* __restrict__ M0)
{
    int v = blockIdx.x;
    if (v >= *M0) return;
    int beg = offs[v], len = cnt[v];
    int tid = threadIdx.x;
    int d = tid & 127, half = tid >> 7;
    float acc = 0.f;
    for (int j = half; j < len; j += 2) {
        int row = order[beg + j];
        acc += h[(size_t)row * DD + d];
    }
    __shared__ float red[DD];
    if (half == 1) red[d] = acc;
    __syncthreads();
    if (half == 0) {
        acc += red[d];
        sum0[(size_t)v * DD + d] = acc;
        if (d == 0) cnt0[v] = (float)len;
    }
}

// ---------------- roll coarse sums up the hierarchy ----------------
__global__ void k_rollup(const float* __restrict__ sumSrc, const float* __restrict__ cntSrc,
                         const int* __restrict__ parent,
                         float* __restrict__ sumDst, float* __restrict__ cntDst,
                         const int* __restrict__ Msrc, int cap)
{
    int idx = blockIdx.x * blockDim.x + threadIdx.x;   // < cap*DD
    int v = idx >> 7, d = idx & 127;
    int Ms = *Msrc;
    if (Ms > cap) Ms = cap;
    if (v >= Ms) return;
    int p = parent[v];
    atomicAdd(&sumDst[(size_t)p * DD + d], sumSrc[idx]);
    if (d == 0) atomicAdd(&cntDst[p], cntSrc[v]);
}

// ---------------- divide by clamped counts ----------------
__global__ void k_finalize(float* __restrict__ macro, const float* __restrict__ counts,
                           const int* M0, const int* M1, const int* M2)
{
    int idx = blockIdx.x * blockDim.x + threadIdx.x;  // < NS*MC*DD
    int s = idx / (MC * DD);
    int r = (idx >> 7) & (MC - 1);
    if (r >= getM(s, M0, M1, M2)) return;
    float c = counts[s * MC + r];
    macro[idx] /= fmaxf(c, 1.0f);
}

// ---------------- b0frag: MFMA B-operand fragments of Wf[:, :128] in bf16 ----------------
__global__ void k_b0frag(const float* __restrict__ Wf, unsigned short* __restrict__ b0f)
{
    int idx = blockIdx.x * 256 + threadIdx.x;  // 16384
    int j = idx & 7, l = (idx >> 3) & 63, kt = (idx >> 9) & 3, nt = idx >> 11;
    int d = nt * 16 + (l & 15);
    int k = kt * 32 + (l >> 4) * 8 + j;
    b0f[idx] = f2bf(Wf[(size_t)d * (4 * DD) + k]);
}

// ---------------- qkv = macro @ Wqkv[s].T + bqkv[s], 8 rows/block ----------------
__global__ void k_qkv(const float* __restrict__ macro, const float* __restrict__ Wqkv,
                      const float* __restrict__ bqkv, float* __restrict__ qkv,
                      const int* M0, const int* M1, const int* M2)
{
    int s = blockIdx.y;
    int Ms = getM(s, M0, M1, M2);
    int row0 = blockIdx.x * 8;
    if (row0 >= Ms) return;
    __shared__ __align__(16) float mac[8][DD];
    int tid = threadIdx.x;
    for (int e = tid; e < 8 * DD; e += 256) {
        int r = e >> 7, d = e & 127;
        int row = row0 + r;
        mac[r][d] = (row < Ms) ? macro[(size_t)s * MC * DD + (size_t)row * DD + d] : 0.0f;
    }
    __syncthreads();
    for (int j = tid; j < 3 * DD; j += 256) {
        const float* w = Wqkv + ((size_t)s * 3 * DD + j) * DD;
        float b = bqkv[s * 3 * DD + j];
        float acc[8];
#pragma unroll
        for (int r = 0; r < 8; ++r) acc[r] = b;
        for (int k = 0; k < DD; k += 4) {
            float4 w4 = *(const float4*)(w + k);
#pragma unroll
            for (int r = 0; r < 8; ++r) {
                float4 m4 = *(const float4*)&mac[r][k];
                acc[r] += w4.x * m4.x + w4.y * m4.y + w4.z * m4.z + w4.w * m4.w;
            }
        }
        for (int r = 0; r < 8; ++r) {
            int row = row0 + r;
            if (row < Ms) qkv[((size_t)s * MC + row) * (3 * DD) + j] = acc[r];
        }
    }
}

// ---------------- flash attention partials: LDS K/V, ALL state in NAMED registers ----------------
// R5/R6 post-mortem: private ARRAYS (q4[8]/o4[8]/p[16]) were kept in scratch (VGPR=64,
// ~700MB-1GB scratch traffic per dispatch). Fix per rule #20: named float4 variables only.

__device__ __forceinline__ float dot8row(const float* krow,
    float4 Q0, float4 Q1, float4 Q2, float4 Q3,
    float4 Q4, float4 Q5, float4 Q6, float4 Q7)
{
    const float4* kp = (const float4*)krow;
    float4 k0 = kp[0], k1 = kp[1], k2 = kp[2], k3 = kp[3];
    float4 k4 = kp[4], k5 = kp[5], k6 = kp[6], k7 = kp[7];
    return Q0.x*k0.x + Q0.y*k0.y + Q0.z*k0.z + Q0.w*k0.w
         + Q1.x*k1.x + Q1.y*k1.y + Q1.z*k1.z + Q1.w*k1.w
         + Q2.x*k2.x + Q2.y*k2.y + Q2.z*k2.z + Q2.w*k2.w
         + Q3.x*k3.x + Q3.y*k3.y + Q3.z*k3.z + Q3.w*k3.w
         + Q4.x*k4.x + Q4.y*k4.y + Q4.z*k4.z + Q4.w*k4.w
         + Q5.x*k5.x + Q5.y*k5.y + Q5.z*k5.z + Q5.w*k5.w
         + Q6.x*k6.x + Q6.y*k6.y + Q6.z*k6.z + Q6.w*k6.w
         + Q7.x*k7.x + Q7.y*k7.y + Q7.z*k7.z + Q7.w*k7.w;
}

#define PVS(KK, W) do { const float4* vp = (const float4*)&vs[(KK)][0]; \
    float4 v0=vp[0],v1=vp[1],v2=vp[2],v3=vp[3],v4=vp[4],v5=vp[5],v6=vp[6],v7=vp[7]; \
    O0.x+=(W)*v0.x; O0.y+=(W)*v0.y; O0.z+=(W)*v0.z; O0.w+=(W)*v0.w; \
    O1.x+=(W)*v1.x; O1.y+=(W)*v1.y; O1.z+=(W)*v1.z; O1.w+=(W)*v1.w; \
    O2.x+=(W)*v2.x; O2.y+=(W)*v2.y; O2.z+=(W)*v2.z; O2.w+=(W)*v2.w; \
    O3.x+=(W)*v3.x; O3.y+=(W)*v3.y; O3.z+=(W)*v3.z; O3.w+=(W)*v3.w; \
    O4.x+=(W)*v4.x; O4.y+=(W)*v4.y; O4.z+=(W)*v4.z; O4.w+=(W)*v4.w; \
    O5.x+=(W)*v5.x; O5.y+=(W)*v5.y; O5.z+=(W)*v5.z; O5.w+=(W)*v5.w; \
    O6.x+=(W)*v6.x; O6.y+=(W)*v6.y; O6.z+=(W)*v6.z; O6.w+=(W)*v6.w; \
    O7.x+=(W)*v7.x; O7.y+=(W)*v7.y; O7.z+=(W)*v7.z; O7.w+=(W)*v7.w; \
} while (0)

#define MUL4(V, A) do { (V).x*=(A); (V).y*=(A); (V).z*=(A); (V).w*=(A); } while (0)

#define RSUM(V) do { \
    (V).x+=__shfl_xor((V).x,1); (V).y+=__shfl_xor((V).y,1); (V).z+=__shfl_xor((V).z,1); (V).w+=__shfl_xor((V).w,1); \
    (V).x+=__shfl_xor((V).x,2); (V).y+=__shfl_xor((V).y,2); (V).z+=__shfl_xor((V).z,2); (V).w+=__shfl_xor((V).w,2); \
} while (0)

__global__ __launch_bounds__(256) void k_attn_part(const float* __restrict__ qkv,
                                                   float* __restrict__ part_o,
                                                   float* __restrict__ part_ml,
                                                   const int* M0, const int* M1, const int* M2)
{
    int z = blockIdx.z;
    int s = z / NSPLIT, part = z % NSPLIT;
    int head = blockIdx.y;
    int Ms = getM(s, M0, M1, M2);
    int q0 = blockIdx.x * 64;
    if (q0 >= Ms) return;
    int kstart = part * PLEN;
    if (kstart >= Ms) return;
    int kend = kstart + PLEN; if (kend > Ms) kend = Ms;

    __shared__ __align__(16) float ks[64][36];
    __shared__ __align__(16) float vs[64][36];

    int tid = threadIdx.x;
    int qi = tid >> 2, sub = tid & 3;
    int qrow = q0 + qi;

    const float* base = qkv + (size_t)s * MC * 3 * DD;
    const float* Qb = base + head * DH;
    const float* Kb = base + DD + head * DH;
    const float* Vb = base + 2 * DD + head * DH;

    float4 Q0 = {0,0,0,0}, Q1 = {0,0,0,0}, Q2 = {0,0,0,0}, Q3 = {0,0,0,0};
    float4 Q4 = {0,0,0,0}, Q5 = {0,0,0,0}, Q6 = {0,0,0,0}, Q7 = {0,0,0,0};
    if (qrow < Ms) {
        const float4* qp = (const float4*)(Qb + (size_t)qrow * 3 * DD);
        Q0 = qp[0]; Q1 = qp[1]; Q2 = qp[2]; Q3 = qp[3];
        Q4 = qp[4]; Q5 = qp[5]; Q6 = qp[6]; Q7 = qp[7];
    }

    float4 O0 = {0,0,0,0}, O1 = {0,0,0,0}, O2 = {0,0,0,0}, O3 = {0,0,0,0};
    float4 O4 = {0,0,0,0}, O5 = {0,0,0,0}, O6 = {0,0,0,0}, O7 = {0,0,0,0};
    float m = -1e30f, l = 0.f;
    const float scale = 0.1767766952966369f;  // 1/sqrt(32)

    for (int kb = kstart; kb < kend; kb += 64) {
        __syncthreads();   // previous chunk's readers done
        for (int e = tid; e < 64 * 8; e += 256) {
            int r = e >> 3, qq = e & 7;
            int key = kb + r;
            float4 kv4 = make_float4(0.f, 0.f, 0.f, 0.f);
            float4 vv4 = make_float4(0.f, 0.f, 0.f, 0.f);
            if (key < kend) {
                kv4 = *(const float4*)(Kb + (size_t)key * 3 * DD + qq * 4);
                vv4 = *(const float4*)(Vb + (size_t)key * 3 * DD + qq * 4);
            }
            *(float4*)&ks[r][qq * 4] = kv4;
            *(float4*)&vs[r][qq * 4] = vv4;
        }
        __syncthreads();

#define SCR(KK) ((kb + (KK) < kend) ? dot8row(&ks[(KK)][0], Q0,Q1,Q2,Q3,Q4,Q5,Q6,Q7) * scale : -1e30f)
        float t00 = SCR(sub +  0), t01 = SCR(sub +  4), t02 = SCR(sub +  8), t03 = SCR(sub + 12);
        float t04 = SCR(sub + 16), t05 = SCR(sub + 20), t06 = SCR(sub + 24), t07 = SCR(sub + 28);
        float t08 = SCR(sub + 32), t09 = SCR(sub + 36), t10 = SCR(sub + 40), t11 = SCR(sub + 44);
        float t12 = SCR(sub + 48), t13 = SCR(sub + 52), t14 = SCR(sub + 56), t15 = SCR(sub + 60);
#undef SCR

        float lmax = fmaxf(fmaxf(fmaxf(fmaxf(t00,t01),fmaxf(t02,t03)),
                                 fmaxf(fmaxf(t04,t05),fmaxf(t06,t07))),
                           fmaxf(fmaxf(fmaxf(t08,t09),fmaxf(t10,t11)),
                                 fmaxf(fmaxf(t12,t13),fmaxf(t14,t15))));
        lmax = fmaxf(lmax, __shfl_xor(lmax, 1));
        lmax = fmaxf(lmax, __shfl_xor(lmax, 2));
        float mnew = fmaxf(m, lmax);
        float alpha = __expf(m - mnew);
        m = mnew;
        l *= alpha;
        MUL4(O0, alpha); MUL4(O1, alpha); MUL4(O2, alpha); MUL4(O3, alpha);
        MUL4(O4, alpha); MUL4(O5, alpha); MUL4(O6, alpha); MUL4(O7, alpha);

        t00 = __expf(t00 - mnew); t01 = __expf(t01 - mnew); t02 = __expf(t02 - mnew); t03 = __expf(t03 - mnew);
        t04 = __expf(t04 - mnew); t05 = __expf(t05 - mnew); t06 = __expf(t06 - mnew); t07 = __expf(t07 - mnew);
        t08 = __expf(t08 - mnew); t09 = __expf(t09 - mnew); t10 = __expf(t10 - mnew); t11 = __expf(t11 - mnew);
        t12 = __expf(t12 - mnew); t13 = __expf(t13 - mnew); t14 = __expf(t14 - mnew); t15 = __expf(t15 - mnew);
        float lsum = ((t00 + t01) + (t02 + t03)) + ((t04 + t05) + (t06 + t07))
                   + ((t08 + t09) + (t10 + t11)) + ((t12 + t13) + (t14 + t15));

        PVS(sub +  0, t00); PVS(sub +  4, t01); PVS(sub +  8, t02); PVS(sub + 12, t03);
        PVS(sub + 16, t04); PVS(sub + 20, t05); PVS(sub + 24, t06); PVS(sub + 28, t07);
        PVS(sub + 32, t08); PVS(sub + 36, t09); PVS(sub + 40, t10); PVS(sub + 44, t11);
        PVS(sub + 48, t12); PVS(sub + 52, t13); PVS(sub + 56, t14); PVS(sub + 60, t15);

        lsum += __shfl_xor(lsum, 1);
        lsum += __shfl_xor(lsum, 2);
        l += lsum;
    }

    RSUM(O0); RSUM(O1); RSUM(O2); RSUM(O3);
    RSUM(O4); RSUM(O5); RSUM(O6); RSUM(O7);

    // each sub writes its 8-float slice of the 32-dim output
    float4 wa, wb;
    if (sub == 0)      { wa = O0; wb = O1; }
    else if (sub == 1) { wa = O2; wb = O3; }
    else if (sub == 2) { wa = O4; wb = O5; }
    else               { wa = O6; wb = O7; }

    int rec = ((s * NHH + head) * 64 + blockIdx.x) * NSPLIT + part;
    float* po = part_o + (size_t)rec * 2048;
    *(float4*)(po + qi * 32 + sub * 8)     = wa;
    *(float4*)(po + qi * 32 + sub * 8 + 4) = wb;
    if (sub == 0) {
        part_ml[rec * 128 + qi] = m;
        part_ml[rec * 128 + 64 + qi] = l;
    }
}

// ---------------- merge split-K partials ----------------
__global__ void k_attn_comb(const float* __restrict__ part_o, const float* __restrict__ part_ml,
                            float* __restrict__ attno,
                            const int* M0, const int* M1, const int* M2)
{
    int s = blockIdx.z, head = blockIdx.y;
    int Ms = getM(s, M0, M1, M2);
    int q0 = blockIdx.x * 64;
    if (q0 >= Ms) return;
    int tid = threadIdx.x;
    int qi = tid >> 2, sub = tid & 3;
    int nparts = (Ms + PLEN - 1) / PLEN;
    if (nparts > NSPLIT) nparts = NSPLIT;
    int recbase = ((s * NHH + head) * 64 + blockIdx.x) * NSPLIT;

    float m = -1e30f;
    for (int p = 0; p < nparts; ++p)
        m = fmaxf(m, part_ml[(recbase + p) * 128 + qi]);
    float L = 0.f;
    float4 A0 = {0,0,0,0}, A1 = {0,0,0,0};
    for (int p = 0; p < nparts; ++p) {
        float mp = part_ml[(recbase + p) * 128 + qi];
        float lp = part_ml[(recbase + p) * 128 + 64 + qi];
        float w = __expf(mp - m);
        L += lp * w;
        const float* po = part_o + (size_t)(recbase + p) * 2048;
        float4 a = *(const float4*)(po + qi * 32 + sub * 4);
        float4 b = *(const float4*)(po + qi * 32 + (sub + 4) * 4);
        A0.x += a.x * w; A0.y += a.y * w; A0.z += a.z * w; A0.w += a.w * w;
        A1.x += b.x * w; A1.y += b.y * w; A1.z += b.z * w; A1.w += b.w * w;
    }
    if (q0 + qi < Ms) {
        float inv = 1.0f / fmaxf(L, 1e-30f);
        size_t orow = ((size_t)s * MC + q0 + qi) * DD + head * DH;
        float4 r0 = make_float4(A0.x * inv, A0.y * inv, A0.z * inv, A0.w * inv);
        float4 r1 = make_float4(A1.x * inv, A1.y * inv, A1.z * inv, A1.w * inv);
        *(float4*)(attno + orow + sub * 4) = r0;
        *(float4*)(attno + orow + (sub + 4) * 4) = r1;
    }
}

// ---------------- x1 = LN1(macro + attno @ Wo.T + bo) ----------------
__global__ void k_ln1(const float* __restrict__ macro, const float* __restrict__ attno,
                      const float* __restrict__ Wo, const float* __restrict__ bo,
                      const float* __restrict__ g, const float* __restrict__ b,
                      float* __restrict__ x1,
                      const int* M0, const int* M1, const int* M2)
{
    int s = blockIdx.y;
    int Ms = getM(s, M0, M1, M2);
    int m = blockIdx.x;
    if (m >= Ms) return;
    __shared__ __align__(16) float os[DD];
    __shared__ float red[4];
    int d = threadIdx.x;  // 128
    size_t row = (size_t)s * MC + m;
    os[d] = attno[row * DD + d];
    __syncthreads();
    const float* w = Wo + ((size_t)s * DD + d) * DD;
    float acc = bo[s * DD + d];
    for (int k = 0; k < DD; k += 4) {
        float4 w4 = *(const float4*)(w + k);
        float4 m4 = *(const float4*)&os[k];
        acc += w4.x * m4.x + w4.y * m4.y + w4.z * m4.z + w4.w * m4.w;
    }
    float xin = macro[row * DD + d] + acc;
    float sum = xin, sq = xin * xin;
    for (int off = 32; off >= 1; off >>= 1) { sum += __shfl_xor(sum, off); sq += __shfl_xor(sq, off); }
    if ((d & 63) == 0) { red[d >> 6] = sum; red[2 + (d >> 6)] = sq; }
    __syncthreads();
    sum = red[0] + red[1]; sq = red[2] + red[3];
    float mean = sum * (1.0f / DD);
    float var = fmaxf(sq * (1.0f / DD) - mean * mean, 0.0f);
    float xh = (xin - mean) * rsqrtf(var + 1e-5f);
    x1[row * DD + d] = xh * g[s * DD + d] + b[s * DD + d];
}

// ---------------- x2 = LN2(x1 + relu(x1@W1.T+b1)@W2.T + b2) ----------------
__global__ void k_ffn(const float* __restrict__ x1,
                      const float* __restrict__ W1, const float* __restrict__ b1,
                      const float* __restrict__ W2, const float* __restrict__ b2,
                      const float* __restrict__ g, const float* __restrict__ bb,
                      float* __restrict__ x2,
                      const int* M0, const int* M1, const int* M2)
{
    int s = blockIdx.y;
    int Ms = getM(s, M0, M1, M2);
    int m = blockIdx.x;
    if (m >= Ms) return;
    __shared__ __align__(16) float xr[DD];
    __shared__ __align__(16) float ts[FFD];
    __shared__ float red[8];
    int tid = threadIdx.x;  // 256
    size_t row = (size_t)s * MC + m;
    if (tid < DD) xr[tid] = x1[row * DD + tid];
    __syncthreads();
    {
        const float* w = W1 + ((size_t)s * FFD + tid) * DD;
        float acc = b1[s * FFD + tid];
        for (int k = 0; k < DD; k += 4) {
            float4 w4 = *(const float4*)(w + k);
            float4 m4 = *(const float4*)&xr[k];
            acc += w4.x * m4.x + w4.y * m4.y + w4.z * m4.z + w4.w * m4.w;
        }
        ts[tid] = fmaxf(acc, 0.0f);
    }
    __syncthreads();
    float xin = 0.0f;
    if (tid < DD) {
        const float* w = W2 + ((size_t)s * DD + tid) * FFD;
        float acc = b2[s * DD + tid];
        for (int k = 0; k < FFD; k += 4) {
            float4 w4 = *(const float4*)(w + k);
            float4 m4 = *(const float4*)&ts[k];
            acc += w4.x * m4.x + w4.y * m4.y + w4.z * m4.z + w4.w * m4.w;
        }
        xin = xr[tid] + acc;
    }
    float sum = xin, sq = xin * xin;
    for (int off = 32; off >= 1; off >>= 1) { sum += __shfl_xor(sum, off); sq += __shfl_xor(sq, off); }
    if ((tid & 63) == 0) { red[tid >> 6] = sum; red[4 + (tid >> 6)] = sq; }
    __syncthreads();
    sum = red[0] + red[1] + red[2] + red[3];
    sq = red[4] + red[5] + red[6] + red[7];
    float mean = sum * (1.0f / DD);
    float var = fmaxf(sq * (1.0f / DD) - mean * mean, 0.0f);
    if (tid < DD) {
        float xh = (xin - mean) * rsqrtf(var + 1e-5f);
        x2[row * DD + tid] = xh * g[s * DD + tid] + bb[s * DD + tid];
    }
}

// ---------------- y_s = x2_s @ Wf[:, 128*(s+1):128*(s+2)].T ----------------
__global__ void k_yproj(const float* __restrict__ x2, const float* __restrict__ Wf,
                        float* __restrict__ y,
                        const int* M0, const int* M1, const int* M2)
{
    int s = blockIdx.y;
    int Ms = getM(s, M0, M1, M2);
    int m = blockIdx.x;
    if (m >= Ms) return;
    __shared__ __align__(16) float xr[DD];
    int d = threadIdx.x;  // 128
    size_t row = (size_t)s * MC + m;
    xr[d] = x2[row * DD + d];
    __syncthreads();
    const float* w = Wf + (size_t)d * (4 * DD) + (s + 1) * DD;
    float acc = 0.0f;
    for (int k = 0; k < DD; k += 4) {
        float4 w4 = *(const float4*)(w + k);
        float4 m4 = *(const float4*)&xr[k];
        acc += w4.x * m4.x + w4.y * m4.y + w4.z * m4.z + w4.w * m4.w;
    }
    y[row * DD + d] = acc;
}

// ---------------- out = h@B0 (bf16 MFMA) + y0[inv0]+y1[inv1]+y2[inv2] + bf ----------------
__global__ __launch_bounds__(256) void k_final(const float* __restrict__ h,
                                               const unsigned short* __restrict__ b0f,
                                               const float* __restrict__ y,
                                               const int* __restrict__ inv0,
                                               const int* __restrict__ inv1,
                                               const int* __restrict__ inv2,
                                               const float* __restrict__ bf,
                                               float* __restrict__ out, int N)
{
    __shared__ __align__(16) unsigned short hs[64][136];  // 272B row: 4-bank shift, 16B aligned
    __shared__ int ivs[3][64];
    int tid = threadIdx.x;
    int wave = tid >> 6, lane = tid & 63;
    int ntiles = (N + 63) >> 6;
    const float* y0 = y;
    const float* y1 = y + (size_t)MC * DD;
    const float* y2 = y + (size_t)2 * MC * DD;

    for (int t = blockIdx.x; t < ntiles; t += gridDim.x) {
        int pb = t * 64;
        __syncthreads();  // previous tile's readers done
        if (tid < 64) {
            int p = pb + tid;
            ivs[0][tid] = (p < N) ? inv0[p] : 0;
        } else if (tid < 128) {
            int p = pb + tid - 64;
            ivs[1][tid - 64] = (p < N) ? inv1[p] : 0;
        } else if (tid < 192) {
            int p = pb + tid - 128;
            ivs[2][tid - 128] = (p < N) ? inv2[p] : 0;
        }
        for (int e = tid; e < 64 * 32; e += 256) {   // 64 rows x 32 float4-units
            int row = e >> 5, u = e & 31;
            int p = pb + row;
            float4 v4 = make_float4(0.f, 0.f, 0.f, 0.f);
            if (p < N) v4 = *(const float4*)(h + (size_t)p * DD + u * 4);
            ushort4 b;
            b.x = f2bf(v4.x); b.y = f2bf(v4.y); b.z = f2bf(v4.z); b.w = f2bf(v4.w);
            *(ushort4*)&hs[row][u * 4] = b;
        }
        __syncthreads();

        short8_t afr[4];
#pragma unroll
        for (int kt = 0; kt < 4; ++kt)
            afr[kt] = *(const short8_t*)&hs[wave * 16 + (lane & 15)][kt * 32 + (lane >> 4) * 8];

#pragma unroll
        for (int nt = 0; nt < 8; ++nt) {
            f32x4 acc = {0.f, 0.f, 0.f, 0.f};
#pragma unroll
            for (int kt = 0; kt < 4; ++kt) {
                short8_t bfr = *(const short8_t*)(b0f + (size_t)((nt * 4 + kt) * 64 + lane) * 8);
                acc = __builtin_amdgcn_mfma_f32_16x16x32_bf16(afr[kt], bfr, acc, 0, 0, 0);
            }
            int d = nt * 16 + (lane & 15);
            float bias = bf[d];
#pragma unroll
            for (int reg = 0; reg < 4; ++reg) {
                int pl = wave * 16 + (lane >> 4) * 4 + reg;
                int p = pb + pl;
                if (p < N) {
                    int i0 = ivs[0][pl], i1 = ivs[1][pl], i2 = ivs[2][pl];
                    out[(size_t)p * DD + d] = acc[reg]
                        + y0[(size_t)i0 * DD + d] + y1[(size_t)i1 * DD + d]
                        + y2[(size_t)i2 * DD + d] + bias;
                }
            }
        }
    }
}

extern "C" void kernel_launch(void* const* d_in, const int* in_sizes, int n_in,
                              void* d_out, int out_size, void* d_ws, size_t ws_size,
                              hipStream_t stream) {
    (void)n_in; (void)out_size; (void)ws_size;
    const float* h   = (const float*)d_in[0];
    const int* inv0  = (const int*)d_in[2];
    const int* inv1  = (const int*)d_in[3];
    const int* inv2  = (const int*)d_in[4];
    const int* M0    = (const int*)d_in[5];
    const int* M1    = (const int*)d_in[6];
    const int* M2    = (const int*)d_in[7];
    const float* Wqkv = (const float*)d_in[8];
    const float* bqkv = (const float*)d_in[9];
    const float* Wo   = (const float*)d_in[10];
    const float* bo   = (const float*)d_in[11];
    const float* ln1s = (const float*)d_in[12];
    const float* ln1b = (const float*)d_in[13];
    const float* W1   = (const float*)d_in[14];
    const float* b1   = (const float*)d_in[15];
    const float* W2   = (const float*)d_in[16];
    const float* b2   = (const float*)d_in[17];
    const float* ln2s = (const float*)d_in[18];
    const float* ln2b = (const float*)d_in[19];
    const float* Wf   = (const float*)d_in[20];
    const float* bf   = (const float*)d_in[21];
    int N = in_sizes[0] / DD;

    float* ws      = (float*)d_ws;
    float* macro   = ws;                                    // NS*MC*DD
    float* counts  = macro + (size_t)NS * MC * DD;          // NS*MC
    float* qkvb    = counts + (size_t)NS * MC;              // NS*MC*3*DD
    float* attno   = qkvb + (size_t)NS * MC * 3 * DD;       // NS*MC*DD
    float* x1      = attno + (size_t)NS * MC * DD;          // NS*MC*DD
    float* x2      = x1 + (size_t)NS * MC * DD;             // NS*MC*DD
    float* yb      = x2 + (size_t)NS * MC * DD;             // NS*MC*DD
    float* b0f_f   = yb + (size_t)NS * MC * DD;             // DD*DD floats of space (b0f uses half)
    unsigned short* b0f = (unsigned short*)b0f_f;
    float* part_o  = b0f_f + (size_t)DD * DD;               // NS*NHH*64*NSPLIT*2048
    float* part_ml = part_o + (size_t)NS * NHH * 64 * NSPLIT * 2048;  // NS*NHH*64*NSPLIT*128
    int* ip        = (int*)(part_ml + (size_t)NS * NHH * 64 * NSPLIT * 128);
    int* parent10  = ip;                // MC
    int* parent21  = parent10 + MC;     // 512
    int* cnt_i     = parent21 + 512;    // MC
    int* fill      = cnt_i + MC;        // MC
    int* offs      = fill + MC;         // MC
    int* order     = offs + MC;         // N

    float* sum0 = macro;
    float* sum1 = macro + (size_t)1 * MC * DD;
    float* sum2 = macro + (size_t)2 * MC * DD;
    float* cnt0 = counts;
    float* cnt1 = counts + MC;
    float* cnt2 = counts + 2 * MC;

    hipMemsetAsync(macro, 0, ((size_t)NS * MC * DD + NS * MC) * sizeof(float), stream);
    hipMemsetAsync(cnt_i, 0, (size_t)2 * MC * sizeof(int), stream);

    int nb = (N + 255) / 256;
    k_parent<<<nb, 256, 0, stream>>>(inv0, inv1, inv2, parent10, parent21, cnt_i, N);
    k_scan<<<1, 1024, 0, stream>>>(cnt_i, offs);
    k_place<<<nb, 256, 0, stream>>>(inv0, offs, fill, order, N);
    k_pool<<<MC, 256, 0, stream>>>(h, order, offs, cnt_i, sum0, cnt0, M0);
    k_rollup<<<(MC * DD) / 256, 256, 0, stream>>>(sum0, cnt0, parent10, sum1, cnt1, M0, MC);
    k_rollup<<<(512 * DD) / 256, 256, 0, stream>>>(sum1, cnt1, parent21, sum2, cnt2, M1, 512);
    k_finalize<<<(NS * MC * DD) / 256, 256, 0, stream>>>(macro, counts, M0, M1, M2);
    k_b0frag<<<64, 256, 0, stream>>>(Wf, b0f);
    k_qkv<<<dim3(MC / 8, NS), 256, 0, stream>>>(macro, Wqkv, bqkv, qkvb, M0, M1, M2);
    k_attn_part<<<dim3(MC / 64, NHH, NS * NSPLIT), 256, 0, stream>>>(qkvb, part_o, part_ml, M0, M1, M2);
    k_attn_comb<<<dim3(MC / 64, NHH, NS), 256, 0, stream>>>(part_o, part_ml, attno, M0, M1, M2);
    k_ln1<<<dim3(MC, NS), 128, 0, stream>>>(macro, attno, Wo, bo, ln1s, ln1b, x1, M0, M1, M2);
    k_ffn<<<dim3(MC, NS), 256, 0, stream>>>(x1, W1, b1, W2, b2, ln2s, ln2b, x2, M0, M1, M2);
    k_yproj<<<dim3(MC, NS), 128, 0, stream>>>(x2, Wf, yb, M0, M1, M2);
    k_final<<<2048, 256, 0, stream>>>(h, b0f, yb, inv0, inv1, inv2, bf, (float*)d_out, N);
}

// Round 9
// 919.460 us; speedup vs baseline: 2.1489x; 1.0888x over previous
//
#include <hip/hip_runtime.h>
#include <hip/hip_bf16.h>

#define MC 4096
#define DD 128
#define NHH 4
#define DH 32
#define FFD 256
#define NS 3
#define NSPLIT 4
#define PLEN 1024

typedef __attribute__((ext_vector_type(8))) short short8_t;
typedef __attribute__((ext_vector_type(4))) float f32x4;

__device__ __forceinline__ int getM(int s, const int* M0, const int* M1, const int* M2) {
    return (s == 0) ? *M0 : (s == 1) ? *M1 : *M2;
}

__device__ __forceinline__ unsigned short f2bf(float f) {
    unsigned int u = __float_as_uint(f);
    u += 0x7FFFu + ((u >> 16) & 1u);   // RNE
    return (unsigned short)(u >> 16);
}

// ---------------- parent maps + scale-0 histogram in one pass ----------------
__global__ void k_parent(const int* __restrict__ inv0, const int* __restrict__ inv1,
                         const int* __restrict__ inv2,
                         int* __restrict__ parent10, int* __restrict__ parent21,
                         int* __restrict__ cnt, int N)
{
    int n = blockIdx.x * blockDim.x + threadIdx.x;
    if (n >= N) return;
    int i0 = inv0[n];
    parent10[i0] = inv1[n];   // duplicate writes all agree (grids nest)
    parent21[inv1[n]] = inv2[n];
    atomicAdd(&cnt[i0], 1);
}

// ---------------- exclusive scan over MC=4096 bins, single block 1024 thr ----------------
__global__ void k_scan(const int* __restrict__ cnt, int* __restrict__ offs)
{
    __shared__ int arr[1024];
    int tid = threadIdx.x;
    int base = tid * 4;
    int c0 = cnt[base], c1 = cnt[base + 1], c2 = cnt[base + 2], c3 = cnt[base + 3];
    int tot = c0 + c1 + c2 + c3;
    arr[tid] = tot;
    __syncthreads();
    for (int off = 1; off < 1024; off <<= 1) {
        int v = (tid >= off) ? arr[tid - off] : 0;
        __syncthreads();
        arr[tid] += v;
        __syncthreads();
    }
    int excl = arr[tid] - tot;
    offs[base] = excl;
    offs[base + 1] = excl + c0;
    offs[base + 2] = excl + c0 + c1;
    offs[base + 3] = excl + c0 + c1 + c2;
}

// ---------------- placement: order[] groups particles by voxel ----------------
__global__ void k_place(const int* __restrict__ inv0, const int* __restrict__ offs,
                        int* __restrict__ fill, int* __restrict__ order, int N)
{
    int n = blockIdx.x * blockDim.x + threadIdx.x;
    if (n >= N) return;
    int i0 = inv0[n];
    int pos = offs[i0] + atomicAdd(&fill[i0], 1);
    order[pos] = n;
}

// ---------------- pooled sums, no fp atomics: one block per voxel ----------------
__global__ __launch_bounds__(256) void k_pool(const float* __restrict__ h,
                                              const int* __restrict__ order,
                                              const int* __restrict__ offs,
                                              const int* __restrict__ cnt,
                                              float* __restrict__ sum0, float* __restrict__ cnt0,
                                              const int* __restrict__ M0)
{
    int v = blockIdx.x;
    if (v >= *M0) return;
    int beg = offs[v], len = cnt[v];
    int tid = threadIdx.x;
    int d = tid & 127, half = tid >> 7;
    float acc = 0.f;
    for (int j = half; j < len; j += 2) {
        int row = order[beg + j];
        acc += h[(size_t)row * DD + d];
    }
    __shared__ float red[DD];
    if (half == 1) red[d] = acc;
    __syncthreads();
    if (half == 0) {
        acc += red[d];
        sum0[(size_t)v * DD + d] = acc;
        if (d == 0) cnt0[v] = (float)len;
    }
}

// ---------------- roll coarse sums up the hierarchy ----------------
__global__ void k_rollup(const float* __restrict__ sumSrc, const float* __restrict__ cntSrc,
                         const int* __restrict__ parent,
                         float* __restrict__ sumDst, float* __restrict__ cntDst,
                         const int* __restrict__ Msrc, int cap)
{
    int idx = blockIdx.x * blockDim.x + threadIdx.x;   // < cap*DD
    int v = idx >> 7, d = idx & 127;
    int Ms = *Msrc;
    if (Ms > cap) Ms = cap;
    if (v >= Ms) return;
    int p = parent[v];
    atomicAdd(&sumDst[(size_t)p * DD + d], sumSrc[idx]);
    if (d == 0) atomicAdd(&cntDst[p], cntSrc[v]);
}

// ---------------- divide by clamped counts ----------------
__global__ void k_finalize(float* __restrict__ macro, const float* __restrict__ counts,
                           const int* M0, const int* M1, const int* M2)
{
    int idx = blockIdx.x * blockDim.x + threadIdx.x;  // < NS*MC*DD
    int s = idx / (MC * DD);
    int r = (idx >> 7) & (MC - 1);
    if (r >= getM(s, M0, M1, M2)) return;
    float c = counts[s * MC + r];
    macro[idx] /= fmaxf(c, 1.0f);
}

// ---------------- b0frag: MFMA fragments of Wf[:, :128] in bf16 ----------------
// b0f[((nt*4+kt)*64 + l)*8 + j] = bf16( Wf[nt*16 + (l&15)][kt*32 + (l>>4)*8 + j] )
__global__ void k_b0frag(const float* __restrict__ Wf, unsigned short* __restrict__ b0f)
{
    int idx = blockIdx.x * 256 + threadIdx.x;  // 16384
    int j = idx & 7, l = (idx >> 3) & 63, kt = (idx >> 9) & 3, nt = idx >> 11;
    int d = nt * 16 + (l & 15);
    int k = kt * 32 + (l >> 4) * 8 + j;
    b0f[idx] = f2bf(Wf[(size_t)d * (4 * DD) + k]);
}

// ---------------- qkv = macro @ Wqkv[s].T + bqkv[s], 8 rows/block ----------------
__global__ void k_qkv(const float* __restrict__ macro, const float* __restrict__ Wqkv,
                      const float* __restrict__ bqkv, float* __restrict__ qkv,
                      const int* M0, const int* M1, const int* M2)
{
    int s = blockIdx.y;
    int Ms = getM(s, M0, M1, M2);
    int row0 = blockIdx.x * 8;
    if (row0 >= Ms) return;
    __shared__ __align__(16) float mac[8][DD];
    int tid = threadIdx.x;
    for (int e = tid; e < 8 * DD; e += 256) {
        int r = e >> 7, d = e & 127;
        int row = row0 + r;
        mac[r][d] = (row < Ms) ? macro[(size_t)s * MC * DD + (size_t)row * DD + d] : 0.0f;
    }
    __syncthreads();
    for (int j = tid; j < 3 * DD; j += 256) {
        const float* w = Wqkv + ((size_t)s * 3 * DD + j) * DD;
        float b = bqkv[s * 3 * DD + j];
        float acc[8];
#pragma unroll
        for (int r = 0; r < 8; ++r) acc[r] = b;
        for (int k = 0; k < DD; k += 4) {
            float4 w4 = *(const float4*)(w + k);
#pragma unroll
            for (int r = 0; r < 8; ++r) {
                float4 m4 = *(const float4*)&mac[r][k];
                acc[r] += w4.x * m4.x + w4.y * m4.y + w4.z * m4.z + w4.w * m4.w;
            }
        }
        for (int r = 0; r < 8; ++r) {
            int row = row0 + r;
            if (row < Ms) qkv[((size_t)s * MC + row) * (3 * DD) + j] = acc[r];
        }
    }
}

// ---------------- flash attention partials: LDS K/V, ALL state in NAMED registers ----------------
__device__ __forceinline__ float dot8row(const float* krow,
    float4 Q0, float4 Q1, float4 Q2, float4 Q3,
    float4 Q4, float4 Q5, float4 Q6, float4 Q7)
{
    const float4* kp = (const float4*)krow;
    float4 k0 = kp[0], k1 = kp[1], k2 = kp[2], k3 = kp[3];
    float4 k4 = kp[4], k5 = kp[5], k6 = kp[6], k7 = kp[7];
    return Q0.x*k0.x + Q0.y*k0.y + Q0.z*k0.z + Q0.w*k0.w
         + Q1.x*k1.x + Q1.y*k1.y + Q1.z*k1.z + Q1.w*k1.w
         + Q2.x*k2.x + Q2.y*k2.y + Q2.z*k2.z + Q2.w*k2.w
         + Q3.x*k3.x + Q3.y*k3.y + Q3.z*k3.z + Q3.w*k3.w
         + Q4.x*k4.x + Q4.y*k4.y + Q4.z*k4.z + Q4.w*k4.w
         + Q5.x*k5.x + Q5.y*k5.y + Q5.z*k5.z + Q5.w*k5.w
         + Q6.x*k6.x + Q6.y*k6.y + Q6.z*k6.z + Q6.w*k6.w
         + Q7.x*k7.x + Q7.y*k7.y + Q7.z*k7.z + Q7.w*k7.w;
}

#define PVS(KK, W) do { const float4* vp = (const float4*)&vs[(KK)][0]; \
    float4 v0=vp[0],v1=vp[1],v2=vp[2],v3=vp[3],v4=vp[4],v5=vp[5],v6=vp[6],v7=vp[7]; \
    O0.x+=(W)*v0.x; O0.y+=(W)*v0.y; O0.z+=(W)*v0.z; O0.w+=(W)*v0.w; \
    O1.x+=(W)*v1.x; O1.y+=(W)*v1.y; O1.z+=(W)*v1.z; O1.w+=(W)*v1.w; \
    O2.x+=(W)*v2.x; O2.y+=(W)*v2.y; O2.z+=(W)*v2.z; O2.w+=(W)*v2.w; \
    O3.x+=(W)*v3.x; O3.y+=(W)*v3.y; O3.z+=(W)*v3.z; O3.w+=(W)*v3.w; \
    O4.x+=(W)*v4.x; O4.y+=(W)*v4.y; O4.z+=(W)*v4.z; O4.w+=(W)*v4.w; \
    O5.x+=(W)*v5.x; O5.y+=(W)*v5.y; O5.z+=(W)*v5.z; O5.w+=(W)*v5.w; \
    O6.x+=(W)*v6.x; O6.y+=(W)*v6.y; O6.z+=(W)*v6.z; O6.w+=(W)*v6.w; \
    O7.x+=(W)*v7.x; O7.y+=(W)*v7.y; O7.z+=(W)*v7.z; O7.w+=(W)*v7.w; \
} while (0)

#define MUL4(V, A) do { (V).x*=(A); (V).y*=(A); (V).z*=(A); (V).w*=(A); } while (0)

#define RSUM(V) do { \
    (V).x+=__shfl_xor((V).x,1); (V).y+=__shfl_xor((V).y,1); (V).z+=__shfl_xor((V).z,1); (V).w+=__shfl_xor((V).w,1); \
    (V).x+=__shfl_xor((V).x,2); (V).y+=__shfl_xor((V).y,2); (V).z+=__shfl_xor((V).z,2); (V).w+=__shfl_xor((V).w,2); \
} while (0)

__global__ __launch_bounds__(256) void k_attn_part(const float* __restrict__ qkv,
                                                   float* __restrict__ part_o,
                                                   float* __restrict__ part_ml,
                                                   const int* M0, const int* M1, const int* M2)
{
    int z = blockIdx.z;
    int s = z / NSPLIT, part = z % NSPLIT;
    int head = blockIdx.y;
    int Ms = getM(s, M0, M1, M2);
    int q0 = blockIdx.x * 64;
    if (q0 >= Ms) return;
    int kstart = part * PLEN;
    if (kstart >= Ms) return;
    int kend = kstart + PLEN; if (kend > Ms) kend = Ms;

    __shared__ __align__(16) float ks[64][36];
    __shared__ __align__(16) float vs[64][36];

    int tid = threadIdx.x;
    int qi = tid >> 2, sub = tid & 3;
    int qrow = q0 + qi;

    const float* base = qkv + (size_t)s * MC * 3 * DD;
    const float* Qb = base + head * DH;
    const float* Kb = base + DD + head * DH;
    const float* Vb = base + 2 * DD + head * DH;

    float4 Q0 = {0,0,0,0}, Q1 = {0,0,0,0}, Q2 = {0,0,0,0}, Q3 = {0,0,0,0};
    float4 Q4 = {0,0,0,0}, Q5 = {0,0,0,0}, Q6 = {0,0,0,0}, Q7 = {0,0,0,0};
    if (qrow < Ms) {
        const float4* qp = (const float4*)(Qb + (size_t)qrow * 3 * DD);
        Q0 = qp[0]; Q1 = qp[1]; Q2 = qp[2]; Q3 = qp[3];
        Q4 = qp[4]; Q5 = qp[5]; Q6 = qp[6]; Q7 = qp[7];
    }

    float4 O0 = {0,0,0,0}, O1 = {0,0,0,0}, O2 = {0,0,0,0}, O3 = {0,0,0,0};
    float4 O4 = {0,0,0,0}, O5 = {0,0,0,0}, O6 = {0,0,0,0}, O7 = {0,0,0,0};
    float m = -1e30f, l = 0.f;
    const float scale = 0.1767766952966369f;  // 1/sqrt(32)

    for (int kb = kstart; kb < kend; kb += 64) {
        __syncthreads();   // previous chunk's readers done
        for (int e = tid; e < 64 * 8; e += 256) {
            int r = e >> 3, qq = e & 7;
            int key = kb + r;
            float4 kv4 = make_float4(0.f, 0.f, 0.f, 0.f);
            float4 vv4 = make_float4(0.f, 0.f, 0.f, 0.f);
            if (key < kend) {
                kv4 = *(const float4*)(Kb + (size_t)key * 3 * DD + qq * 4);
                vv4 = *(const float4*)(Vb + (size_t)key * 3 * DD + qq * 4);
            }
            *(float4*)&ks[r][qq * 4] = kv4;
            *(float4*)&vs[r][qq * 4] = vv4;
        }
        __syncthreads();

#define SCR(KK) ((kb + (KK) < kend) ? dot8row(&ks[(KK)][0], Q0,Q1,Q2,Q3,Q4,Q5,Q6,Q7) * scale : -1e30f)
        float t00 = SCR(sub +  0), t01 = SCR(sub +  4), t02 = SCR(sub +  8), t03 = SCR(sub + 12);
        float t04 = SCR(sub + 16), t05 = SCR(sub + 20), t06 = SCR(sub + 24), t07 = SCR(sub + 28);
        float t08 = SCR(sub + 32), t09 = SCR(sub + 36), t10 = SCR(sub + 40), t11 = SCR(sub + 44);
        float t12 = SCR(sub + 48), t13 = SCR(sub + 52), t14 = SCR(sub + 56), t15 = SCR(sub + 60);
#undef SCR

        float lmax = fmaxf(fmaxf(fmaxf(fmaxf(t00,t01),fmaxf(t02,t03)),
                                 fmaxf(fmaxf(t04,t05),fmaxf(t06,t07))),
                           fmaxf(fmaxf(fmaxf(t08,t09),fmaxf(t10,t11)),
                                 fmaxf(fmaxf(t12,t13),fmaxf(t14,t15))));
        lmax = fmaxf(lmax, __shfl_xor(lmax, 1));
        lmax = fmaxf(lmax, __shfl_xor(lmax, 2));
        float mnew = fmaxf(m, lmax);
        float alpha = __expf(m - mnew);
        m = mnew;
        l *= alpha;
        MUL4(O0, alpha); MUL4(O1, alpha); MUL4(O2, alpha); MUL4(O3, alpha);
        MUL4(O4, alpha); MUL4(O5, alpha); MUL4(O6, alpha); MUL4(O7, alpha);

        t00 = __expf(t00 - mnew); t01 = __expf(t01 - mnew); t02 = __expf(t02 - mnew); t03 = __expf(t03 - mnew);
        t04 = __expf(t04 - mnew); t05 = __expf(t05 - mnew); t06 = __expf(t06 - mnew); t07 = __expf(t07 - mnew);
        t08 = __expf(t08 - mnew); t09 = __expf(t09 - mnew); t10 = __expf(t10 - mnew); t11 = __expf(t11 - mnew);
        t12 = __expf(t12 - mnew); t13 = __expf(t13 - mnew); t14 = __expf(t14 - mnew); t15 = __expf(t15 - mnew);
        float lsum = ((t00 + t01) + (t02 + t03)) + ((t04 + t05) + (t06 + t07))
                   + ((t08 + t09) + (t10 + t11)) + ((t12 + t13) + (t14 + t15));

        PVS(sub +  0, t00); PVS(sub +  4, t01); PVS(sub +  8, t02); PVS(sub + 12, t03);
        PVS(sub + 16, t04); PVS(sub + 20, t05); PVS(sub + 24, t06); PVS(sub + 28, t07);
        PVS(sub + 32, t08); PVS(sub + 36, t09); PVS(sub + 40, t10); PVS(sub + 44, t11);
        PVS(sub + 48, t12); PVS(sub + 52, t13); PVS(sub + 56, t14); PVS(sub + 60, t15);

        lsum += __shfl_xor(lsum, 1);
        lsum += __shfl_xor(lsum, 2);
        l += lsum;
    }

    RSUM(O0); RSUM(O1); RSUM(O2); RSUM(O3);
    RSUM(O4); RSUM(O5); RSUM(O6); RSUM(O7);

    float4 wa, wb;
    if (sub == 0)      { wa = O0; wb = O1; }
    else if (sub == 1) { wa = O2; wb = O3; }
    else if (sub == 2) { wa = O4; wb = O5; }
    else               { wa = O6; wb = O7; }

    int rec = ((s * NHH + head) * 64 + blockIdx.x) * NSPLIT + part;
    float* po = part_o + (size_t)rec * 2048;
    *(float4*)(po + qi * 32 + sub * 8)     = wa;
    *(float4*)(po + qi * 32 + sub * 8 + 4) = wb;
    if (sub == 0) {
        part_ml[rec * 128 + qi] = m;
        part_ml[rec * 128 + 64 + qi] = l;
    }
}

// ---------------- merge split-K partials ----------------
__global__ void k_attn_comb(const float* __restrict__ part_o, const float* __restrict__ part_ml,
                            float* __restrict__ attno,
                            const int* M0, const int* M1, const int* M2)
{
    int s = blockIdx.z, head = blockIdx.y;
    int Ms = getM(s, M0, M1, M2);
    int q0 = blockIdx.x * 64;
    if (q0 >= Ms) return;
    int tid = threadIdx.x;
    int qi = tid >> 2, sub = tid & 3;
    int nparts = (Ms + PLEN - 1) / PLEN;
    if (nparts > NSPLIT) nparts = NSPLIT;
    int recbase = ((s * NHH + head) * 64 + blockIdx.x) * NSPLIT;

    float m = -1e30f;
    for (int p = 0; p < nparts; ++p)
        m = fmaxf(m, part_ml[(recbase + p) * 128 + qi]);
    float L = 0.f;
    float4 A0 = {0,0,0,0}, A1 = {0,0,0,0};
    for (int p = 0; p < nparts; ++p) {
        float mp = part_ml[(recbase + p) * 128 + qi];
        float lp = part_ml[(recbase + p) * 128 + 64 + qi];
        float w = __expf(mp - m);
        L += lp * w;
        const float* po = part_o + (size_t)(recbase + p) * 2048;
        float4 a = *(const float4*)(po + qi * 32 + sub * 4);
        float4 b = *(const float4*)(po + qi * 32 + (sub + 4) * 4);
        A0.x += a.x * w; A0.y += a.y * w; A0.z += a.z * w; A0.w += a.w * w;
        A1.x += b.x * w; A1.y += b.y * w; A1.z += b.z * w; A1.w += b.w * w;
    }
    if (q0 + qi < Ms) {
        float inv = 1.0f / fmaxf(L, 1e-30f);
        size_t orow = ((size_t)s * MC + q0 + qi) * DD + head * DH;
        float4 r0 = make_float4(A0.x * inv, A0.y * inv, A0.z * inv, A0.w * inv);
        float4 r1 = make_float4(A1.x * inv, A1.y * inv, A1.z * inv, A1.w * inv);
        *(float4*)(attno + orow + sub * 4) = r0;
        *(float4*)(attno + orow + (sub + 4) * 4) = r1;
    }
}

// ---------------- x1 = LN1(macro + attno @ Wo.T + bo) ----------------
__global__ void k_ln1(const float* __restrict__ macro, const float* __restrict__ attno,
                      const float* __restrict__ Wo, const float* __restrict__ bo,
                      const float* __restrict__ g, const float* __restrict__ b,
                      float* __restrict__ x1,
                      const int* M0, const int* M1, const int* M2)
{
    int s = blockIdx.y;
    int Ms = getM(s, M0, M1, M2);
    int m = blockIdx.x;
    if (m >= Ms) return;
    __shared__ __align__(16) float os[DD];
    __shared__ float red[4];
    int d = threadIdx.x;  // 128
    size_t row = (size_t)s * MC + m;
    os[d] = attno[row * DD + d];
    __syncthreads();
    const float* w = Wo + ((size_t)s * DD + d) * DD;
    float acc = bo[s * DD + d];
    for (int k = 0; k < DD; k += 4) {
        float4 w4 = *(const float4*)(w + k);
        float4 m4 = *(const float4*)&os[k];
        acc += w4.x * m4.x + w4.y * m4.y + w4.z * m4.z + w4.w * m4.w;
    }
    float xin = macro[row * DD + d] + acc;
    float sum = xin, sq = xin * xin;
    for (int off = 32; off >= 1; off >>= 1) { sum += __shfl_xor(sum, off); sq += __shfl_xor(sq, off); }
    if ((d & 63) == 0) { red[d >> 6] = sum; red[2 + (d >> 6)] = sq; }
    __syncthreads();
    sum = red[0] + red[1]; sq = red[2] + red[3];
    float mean = sum * (1.0f / DD);
    float var = fmaxf(sq * (1.0f / DD) - mean * mean, 0.0f);
    float xh = (xin - mean) * rsqrtf(var + 1e-5f);
    x1[row * DD + d] = xh * g[s * DD + d] + b[s * DD + d];
}

// ---------------- x2 = LN2(x1 + relu(x1@W1.T+b1)@W2.T + b2) ----------------
__global__ void k_ffn(const float* __restrict__ x1,
                      const float* __restrict__ W1, const float* __restrict__ b1,
                      const float* __restrict__ W2, const float* __restrict__ b2,
                      const float* __restrict__ g, const float* __restrict__ bb,
                      float* __restrict__ x2,
                      const int* M0, const int* M1, const int* M2)
{
    int s = blockIdx.y;
    int Ms = getM(s, M0, M1, M2);
    int m = blockIdx.x;
    if (m >= Ms) return;
    __shared__ __align__(16) float xr[DD];
    __shared__ __align__(16) float ts[FFD];
    __shared__ float red[8];
    int tid = threadIdx.x;  // 256
    size_t row = (size_t)s * MC + m;
    if (tid < DD) xr[tid] = x1[row * DD + tid];
    __syncthreads();
    {
        const float* w = W1 + ((size_t)s * FFD + tid) * DD;
        float acc = b1[s * FFD + tid];
        for (int k = 0; k < DD; k += 4) {
            float4 w4 = *(const float4*)(w + k);
            float4 m4 = *(const float4*)&xr[k];
            acc += w4.x * m4.x + w4.y * m4.y + w4.z * m4.z + w4.w * m4.w;
        }
        ts[tid] = fmaxf(acc, 0.0f);
    }
    __syncthreads();
    float xin = 0.0f;
    if (tid < DD) {
        const float* w = W2 + ((size_t)s * DD + tid) * FFD;
        float acc = b2[s * DD + tid];
        for (int k = 0; k < FFD; k += 4) {
            float4 w4 = *(const float4*)(w + k);
            float4 m4 = *(const float4*)&ts[k];
            acc += w4.x * m4.x + w4.y * m4.y + w4.z * m4.z + w4.w * m4.w;
        }
        xin = xr[tid] + acc;
    }
    float sum = xin, sq = xin * xin;
    for (int off = 32; off >= 1; off >>= 1) { sum += __shfl_xor(sum, off); sq += __shfl_xor(sq, off); }
    if ((tid & 63) == 0) { red[tid >> 6] = sum; red[4 + (tid >> 6)] = sq; }
    __syncthreads();
    sum = red[0] + red[1] + red[2] + red[3];
    sq = red[4] + red[5] + red[6] + red[7];
    float mean = sum * (1.0f / DD);
    float var = fmaxf(sq * (1.0f / DD) - mean * mean, 0.0f);
    if (tid < DD) {
        float xh = (xin - mean) * rsqrtf(var + 1e-5f);
        x2[row * DD + tid] = xh * g[s * DD + tid] + bb[s * DD + tid];
    }
}

// ---------------- y_s = x2_s @ Wf[:, 128*(s+1):128*(s+2)].T ----------------
__global__ void k_yproj(const float* __restrict__ x2, const float* __restrict__ Wf,
                        float* __restrict__ y,
                        const int* M0, const int* M1, const int* M2)
{
    int s = blockIdx.y;
    int Ms = getM(s, M0, M1, M2);
    int m = blockIdx.x;
    if (m >= Ms) return;
    __shared__ __align__(16) float xr[DD];
    int d = threadIdx.x;  // 128
    size_t row = (size_t)s * MC + m;
    xr[d] = x2[row * DD + d];
    __syncthreads();
    const float* w = Wf + (size_t)d * (4 * DD) + (s + 1) * DD;
    float acc = 0.0f;
    for (int k = 0; k < DD; k += 4) {
        float4 w4 = *(const float4*)(w + k);
        float4 m4 = *(const float4*)&xr[k];
        acc += w4.x * m4.x + w4.y * m4.y + w4.z * m4.z + w4.w * m4.w;
    }
    y[row * DD + d] = acc;
}

// ---------------- out = h@B0 (bf16 MFMA, weights-as-A) + gathers + bf ----------------
// SWAPPED operand order vs R7: A = b0f (dims->rows), B = h fragment (particles->cols).
// C/D map (col=l&15, row=(l>>4)*4+reg): lane owns ONE particle p=pb+wave*16+(l&15)
// and 4 CONSECUTIVE dims d=nt*16+(l>>4)*4+reg -> float4 gathers/stores (was 128
// scalar vmem ops/lane/tile, now 40 float4 ops).
__global__ __launch_bounds__(256) void k_final(const float* __restrict__ h,
                                               const unsigned short* __restrict__ b0f,
                                               const float* __restrict__ y,
                                               const int* __restrict__ inv0,
                                               const int* __restrict__ inv1,
                                               const int* __restrict__ inv2,
                                               const float* __restrict__ bf,
                                               float* __restrict__ out, int N)
{
    __shared__ __align__(16) unsigned short hs[64][136];  // 272B row: 4-bank shift, 16B aligned
    int tid = threadIdx.x;
    int wave = tid >> 6, lane = tid & 63;
    int ntiles = (N + 63) >> 6;
    const float* y0 = y;
    const float* y1 = y + (size_t)MC * DD;
    const float* y2 = y + (size_t)2 * MC * DD;

    for (int t = blockIdx.x; t < ntiles; t += gridDim.x) {
        int pb = t * 64;
        __syncthreads();  // previous tile's readers done
        for (int e = tid; e < 64 * 32; e += 256) {   // 64 rows x 32 float4-units
            int row = e >> 5, u = e & 31;
            int p = pb + row;
            float4 v4 = make_float4(0.f, 0.f, 0.f, 0.f);
            if (p < N) v4 = *(const float4*)(h + (size_t)p * DD + u * 4);
            ushort4 b;
            b.x = f2bf(v4.x); b.y = f2bf(v4.y); b.z = f2bf(v4.z); b.w = f2bf(v4.w);
            *(ushort4*)&hs[row][u * 4] = b;
        }
        __syncthreads();

        // this lane's particle (B-operand col) and its gather rows
        int pl = wave * 16 + (lane & 15);
        int p = pb + pl;
        int i0 = 0, i1 = 0, i2 = 0;
        if (p < N) { i0 = inv0[p]; i1 = inv1[p]; i2 = inv2[p]; }
        const float* yr0 = y0 + (size_t)i0 * DD;
        const float* yr1 = y1 + (size_t)i1 * DD;
        const float* yr2 = y2 + (size_t)i2 * DD;

        // h fragments (B operand): col = pl, k = kt*32 + (lane>>4)*8
        short8_t hfr[4];
#pragma unroll
        for (int kt = 0; kt < 4; ++kt)
            hfr[kt] = *(const short8_t*)&hs[pl][kt * 32 + (lane >> 4) * 8];

#pragma unroll
        for (int nt = 0; nt < 8; ++nt) {
            f32x4 acc = {0.f, 0.f, 0.f, 0.f};
#pragma unroll
            for (int kt = 0; kt < 4; ++kt) {
                short8_t wfr = *(const short8_t*)(b0f + (size_t)((nt * 4 + kt) * 64 + lane) * 8);
                acc = __builtin_amdgcn_mfma_f32_16x16x32_bf16(wfr, hfr[kt], acc, 0, 0, 0);
            }
            if (p < N) {
                int d = nt * 16 + (lane >> 4) * 4;
                float4 g0 = *(const float4*)(yr0 + d);
                float4 g1 = *(const float4*)(yr1 + d);
                float4 g2 = *(const float4*)(yr2 + d);
                float4 b4 = *(const float4*)(bf + d);
                float4 r;
                r.x = acc[0] + g0.x + g1.x + g2.x + b4.x;
                r.y = acc[1] + g0.y + g1.y + g2.y + b4.y;
                r.z = acc[2] + g0.z + g1.z + g2.z + b4.z;
                r.w = acc[3] + g0.w + g1.w + g2.w + b4.w;
                *(float4*)(out + (size_t)p * DD + d) = r;
            }
        }
    }
}

extern "C" void kernel_launch(void* const* d_in, const int* in_sizes, int n_in,
                              void* d_out, int out_size, void* d_ws, size_t ws_size,
                              hipStream_t stream) {
    (void)n_in; (void)out_size; (void)ws_size;
    const float* h   = (const float*)d_in[0];
    const int* inv0  = (const int*)d_in[2];
    const int* inv1  = (const int*)d_in[3];
    const int* inv2  = (const int*)d_in[4];
    const int* M0    = (const int*)d_in[5];
    const int* M1    = (const int*)d_in[6];
    const int* M2    = (const int*)d_in[7];
    const float* Wqkv = (const float*)d_in[8];
    const float* bqkv = (const float*)d_in[9];
    const float* Wo   = (const float*)d_in[10];
    const float* bo   = (const float*)d_in[11];
    const float* ln1s = (const float*)d_in[12];
    const float* ln1b = (const float*)d_in[13];
    const float* W1   = (const float*)d_in[14];
    const float* b1   = (const float*)d_in[15];
    const float* W2   = (const float*)d_in[16];
    const float* b2   = (const float*)d_in[17];
    const float* ln2s = (const float*)d_in[18];
    const float* ln2b = (const float*)d_in[19];
    const float* Wf   = (const float*)d_in[20];
    const float* bf   = (const float*)d_in[21];
    int N = in_sizes[0] / DD;

    float* ws      = (float*)d_ws;
    float* macro   = ws;                                    // NS*MC*DD
    float* counts  = macro + (size_t)NS * MC * DD;          // NS*MC
    float* qkvb    = counts + (size_t)NS * MC;              // NS*MC*3*DD
    float* attno   = qkvb + (size_t)NS * MC * 3 * DD;       // NS*MC*DD
    float* x1      = attno + (size_t)NS * MC * DD;          // NS*MC*DD
    float* x2      = x1 + (size_t)NS * MC * DD;             // NS*MC*DD
    float* yb      = x2 + (size_t)NS * MC * DD;             // NS*MC*DD
    float* b0f_f   = yb + (size_t)NS * MC * DD;             // DD*DD floats of space (b0f uses half)
    unsigned short* b0f = (unsigned short*)b0f_f;
    float* part_o  = b0f_f + (size_t)DD * DD;               // NS*NHH*64*NSPLIT*2048
    float* part_ml = part_o + (size_t)NS * NHH * 64 * NSPLIT * 2048;  // NS*NHH*64*NSPLIT*128
    int* ip        = (int*)(part_ml + (size_t)NS * NHH * 64 * NSPLIT * 128);
    int* parent10  = ip;                // MC
    int* parent21  = parent10 + MC;     // 512
    int* cnt_i     = parent21 + 512;    // MC
    int* fill      = cnt_i + MC;        // MC
    int* offs      = fill + MC;         // MC
    int* order     = offs + MC;         // N

    float* sum0 = macro;
    float* sum1 = macro + (size_t)1 * MC * DD;
    float* sum2 = macro + (size_t)2 * MC * DD;
    float* cnt0 = counts;
    float* cnt1 = counts + MC;
    float* cnt2 = counts + 2 * MC;

    hipMemsetAsync(macro, 0, ((size_t)NS * MC * DD + NS * MC) * sizeof(float), stream);
    hipMemsetAsync(cnt_i, 0, (size_t)2 * MC * sizeof(int), stream);

    int nb = (N + 255) / 256;
    k_parent<<<nb, 256, 0, stream>>>(inv0, inv1, inv2, parent10, parent21, cnt_i, N);
    k_scan<<<1, 1024, 0, stream>>>(cnt_i, offs);
    k_place<<<nb, 256, 0, stream>>>(inv0, offs, fill, order, N);
    k_pool<<<MC, 256, 0, stream>>>(h, order, offs, cnt_i, sum0, cnt0, M0);
    k_rollup<<<(MC * DD) / 256, 256, 0, stream>>>(sum0, cnt0, parent10, sum1, cnt1, M0, MC);
    k_rollup<<<(512 * DD) / 256, 256, 0, stream>>>(sum1, cnt1, parent21, sum2, cnt2, M1, 512);
    k_finalize<<<(NS * MC * DD) / 256, 256, 0, stream>>>(macro, counts, M0, M1, M2);
    k_b0frag<<<64, 256, 0, stream>>>(Wf, b0f);
    k_qkv<<<dim3(MC / 8, NS), 256, 0, stream>>>(macro, Wqkv, bqkv, qkvb, M0, M1, M2);
    k_attn_part<<<dim3(MC / 64, NHH, NS * NSPLIT), 256, 0, stream>>>(qkvb, part_o, part_ml, M0, M1, M2);
    k_attn_comb<<<dim3(MC / 64, NHH, NS), 256, 0, stream>>>(part_o, part_ml, attno, M0, M1, M2);
    k_ln1<<<dim3(MC, NS), 128, 0, stream>>>(macro, attno, Wo, bo, ln1s, ln1b, x1, M0, M1, M2);
    k_ffn<<<dim3(MC, NS), 256, 0, stream>>>(x1, W1, b1, W2, b2, ln2s, ln2b, x2, M0, M1, M2);
    k_yproj<<<dim3(MC, NS), 128, 0, stream>>>(x2, Wf, yb, M0, M1, M2);
    k_final<<<2048, 256, 0, stream>>>(h, b0f, yb, inv0, inv1, inv2, bf, (float*)d_out, N);
}

// Round 10
// 756.474 us; speedup vs baseline: 2.6119x; 1.2155x over previous
//
#include <hip/hip_runtime.h>
#include <hip/hip_bf16.h>

#define MC 4096
#define DD 128
#define NHH 4
#define DH 32
#define FFD 256
#define NS 3
#define NSPLIT 4
#define PLEN 1024

typedef __attribute__((ext_vector_type(8))) short short8_t;
typedef __attribute__((ext_vector_type(4))) float f32x4;

__device__ __forceinline__ int getM(int s, const int* M0, const int* M1, const int* M2) {
    return (s == 0) ? *M0 : (s == 1) ? *M1 : *M2;
}

__device__ __forceinline__ unsigned short f2bf(float f) {
    unsigned int u = __float_as_uint(f);
    u += 0x7FFFu + ((u >> 16) & 1u);   // RNE
    return (unsigned short)(u >> 16);
}

__device__ __forceinline__ short8_t pack8(float4 a, float4 b) {
    short8_t r;
    r[0] = (short)f2bf(a.x); r[1] = (short)f2bf(a.y);
    r[2] = (short)f2bf(a.z); r[3] = (short)f2bf(a.w);
    r[4] = (short)f2bf(b.x); r[5] = (short)f2bf(b.y);
    r[6] = (short)f2bf(b.z); r[7] = (short)f2bf(b.w);
    return r;
}

__device__ __forceinline__ f32x4 max4(f32x4 a, f32x4 b) {
    f32x4 r;
    r[0] = fmaxf(a[0], b[0]); r[1] = fmaxf(a[1], b[1]);
    r[2] = fmaxf(a[2], b[2]); r[3] = fmaxf(a[3], b[3]);
    return r;
}
__device__ __forceinline__ f32x4 shflx4(f32x4 a, int m) {
    f32x4 r;
    r[0] = __shfl_xor(a[0], m); r[1] = __shfl_xor(a[1], m);
    r[2] = __shfl_xor(a[2], m); r[3] = __shfl_xor(a[3], m);
    return r;
}
__device__ __forceinline__ f32x4 exp4(f32x4 a) {
    f32x4 r;
    r[0] = __expf(a[0]); r[1] = __expf(a[1]);
    r[2] = __expf(a[2]); r[3] = __expf(a[3]);
    return r;
}

// ---------------- parent maps + scale-0 histogram in one pass ----------------
__global__ void k_parent(const int* __restrict__ inv0, const int* __restrict__ inv1,
                         const int* __restrict__ inv2,
                         int* __restrict__ parent10, int* __restrict__ parent21,
                         int* __restrict__ cnt, int N)
{
    int n = blockIdx.x * blockDim.x + threadIdx.x;
    if (n >= N) return;
    int i0 = inv0[n];
    parent10[i0] = inv1[n];   // duplicate writes all agree (grids nest)
    parent21[inv1[n]] = inv2[n];
    atomicAdd(&cnt[i0], 1);
}

// ---------------- exclusive scan over MC=4096 bins, single block 1024 thr ----------------
__global__ void k_scan(const int* __restrict__ cnt, int* __restrict__ offs)
{
    __shared__ int arr[1024];
    int tid = threadIdx.x;
    int base = tid * 4;
    int c0 = cnt[base], c1 = cnt[base + 1], c2 = cnt[base + 2], c3 = cnt[base + 3];
    int tot = c0 + c1 + c2 + c3;
    arr[tid] = tot;
    __syncthreads();
    for (int off = 1; off < 1024; off <<= 1) {
        int v = (tid >= off) ? arr[tid - off] : 0;
        __syncthreads();
        arr[tid] += v;
        __syncthreads();
    }
    int excl = arr[tid] - tot;
    offs[base] = excl;
    offs[base + 1] = excl + c0;
    offs[base + 2] = excl + c0 + c1;
    offs[base + 3] = excl + c0 + c1 + c2;
}

// ---------------- placement: order[] groups particles by voxel ----------------
__global__ void k_place(const int* __restrict__ inv0, const int* __restrict__ offs,
                        int* __restrict__ fill, int* __restrict__ order, int N)
{
    int n = blockIdx.x * blockDim.x + threadIdx.x;
    if (n >= N) return;
    int i0 = inv0[n];
    int pos = offs[i0] + atomicAdd(&fill[i0], 1);
    order[pos] = n;
}

// ---------------- pooled sums, no fp atomics: one block per voxel ----------------
__global__ __launch_bounds__(256) void k_pool(const float* __restrict__ h,
                                              const int* __restrict__ order,
                                              const int* __restrict__ offs,
                                              const int* __restrict__ cnt,
                                              float* __restrict__ sum0, float* __restrict__ cnt0,
                                              const int* __restrict__ M0)
{
    int v = blockIdx.x;
    if (v >= *M0) return;
    int beg = offs[v], len = cnt[v];
    int tid = threadIdx.x;
    int d = tid & 127, half = tid >> 7;
    float acc = 0.f;
    for (int j = half; j < len; j += 2) {
        int row = order[beg + j];
        acc += h[(size_t)row * DD + d];
    }
    __shared__ float red[DD];
    if (half == 1) red[d] = acc;
    __syncthreads();
    if (half == 0) {
        acc += red[d];
        sum0[(size_t)v * DD + d] = acc;
        if (d == 0) cnt0[v] = (float)len;
    }
}

// ---------------- roll coarse sums up the hierarchy ----------------
__global__ void k_rollup(const float* __restrict__ sumSrc, const float* __restrict__ cntSrc,
                         const int* __restrict__ parent,
                         float* __restrict__ sumDst, float* __restrict__ cntDst,
                         const int* __restrict__ Msrc, int cap)
{
    int idx = blockIdx.x * blockDim.x + threadIdx.x;   // < cap*DD
    int v = idx >> 7, d = idx & 127;
    int Ms = *Msrc;
    if (Ms > cap) Ms = cap;
    if (v >= Ms) return;
    int p = parent[v];
    atomicAdd(&sumDst[(size_t)p * DD + d], sumSrc[idx]);
    if (d == 0) atomicAdd(&cntDst[p], cntSrc[v]);
}

// ---------------- divide by clamped counts ----------------
__global__ void k_finalize(float* __restrict__ macro, const float* __restrict__ counts,
                           const int* M0, const int* M1, const int* M2)
{
    int idx = blockIdx.x * blockDim.x + threadIdx.x;  // < NS*MC*DD
    int s = idx / (MC * DD);
    int r = (idx >> 7) & (MC - 1);
    if (r >= getM(s, M0, M1, M2)) return;
    float c = counts[s * MC + r];
    macro[idx] /= fmaxf(c, 1.0f);
}

// ---------------- b0frag: MFMA fragments of Wf[:, :128] in bf16 ----------------
__global__ void k_b0frag(const float* __restrict__ Wf, unsigned short* __restrict__ b0f)
{
    int idx = blockIdx.x * 256 + threadIdx.x;  // 16384
    int j = idx & 7, l = (idx >> 3) & 63, kt = (idx >> 9) & 3, nt = idx >> 11;
    int d = nt * 16 + (l & 15);
    int k = kt * 32 + (l >> 4) * 8 + j;
    b0f[idx] = f2bf(Wf[(size_t)d * (4 * DD) + k]);
}

// ---------------- qkv = macro @ Wqkv[s].T + bqkv[s], 8 rows/block ----------------
__global__ void k_qkv(const float* __restrict__ macro, const float* __restrict__ Wqkv,
                      const float* __restrict__ bqkv, float* __restrict__ qkv,
                      const int* M0, const int* M1, const int* M2)
{
    int s = blockIdx.y;
    int Ms = getM(s, M0, M1, M2);
    int row0 = blockIdx.x * 8;
    if (row0 >= Ms) return;
    __shared__ __align__(16) float mac[8][DD];
    int tid = threadIdx.x;
    for (int e = tid; e < 8 * DD; e += 256) {
        int r = e >> 7, d = e & 127;
        int row = row0 + r;
        mac[r][d] = (row < Ms) ? macro[(size_t)s * MC * DD + (size_t)row * DD + d] : 0.0f;
    }
    __syncthreads();
    for (int j = tid; j < 3 * DD; j += 256) {
        const float* w = Wqkv + ((size_t)s * 3 * DD + j) * DD;
        float b = bqkv[s * 3 * DD + j];
        float acc[8];
#pragma unroll
        for (int r = 0; r < 8; ++r) acc[r] = b;
        for (int k = 0; k < DD; k += 4) {
            float4 w4 = *(const float4*)(w + k);
#pragma unroll
            for (int r = 0; r < 8; ++r) {
                float4 m4 = *(const float4*)&mac[r][k];
                acc[r] += w4.x * m4.x + w4.y * m4.y + w4.z * m4.z + w4.w * m4.w;
            }
        }
        for (int r = 0; r < 8; ++r) {
            int row = row0 + r;
            if (row < Ms) qkv[((size_t)s * MC + row) * (3 * DD) + j] = acc[r];
        }
    }
}

// ---------------- MFMA flash attention partials ----------------
// R9 was at the LDS-BW roofline (16.8 GB LDS reads, ~69 TB/s -> 243us). MFMA raises
// arithmetic intensity 16x: QK^T and PV via mfma_f32_16x16x32_bf16. Wave w owns q rows
// [16w,16w+16). K/V staged in LDS PRE-SWIZZLED to fragment order (linear 16B/lane reads).
// Softmax on C/D layout in registers (rows=(l>>4)*4+reg, col=l&15), 16-lane butterfly.
// P -> bf16 in wave-private LDS (pad-80 rows). Layout conventions HW-verified in R5/R8.
__global__ __launch_bounds__(256) void k_attn_part(const float* __restrict__ qkv,
                                                   float* __restrict__ part_o,
                                                   float* __restrict__ part_ml,
                                                   const int* M0, const int* M1, const int* M2)
{
    int z = blockIdx.z;
    int s = z / NSPLIT, part = z % NSPLIT;
    int head = blockIdx.y;
    int Ms = getM(s, M0, M1, M2);
    int q0 = blockIdx.x * 64;
    if (q0 >= Ms) return;
    int kstart = part * PLEN;
    if (kstart >= Ms) return;
    int kend = kstart + PLEN; if (kend > Ms) kend = Ms;

    // K fragments: kf[nt][lane][j] = K[kb + nt*16 + (l&15)][(l>>4)*8+j]      (4 KB)
    // V fragments: vf[ks][nt][lane][j] = V[kb+ks*32+(l>>4)*8+j][nt*16+(l&15)] (4 KB)
    // P buffer  : pf[wave][qrow 0..15][key 0..63] bf16, rows padded to 80     (10 KB)
    __shared__ __align__(16) unsigned short kf[4][64][8];
    __shared__ __align__(16) unsigned short vf[2][2][64][8];
    __shared__ __align__(16) unsigned short pf[4][16][80];

    int tid = threadIdx.x;
    int wave = tid >> 6, lane = tid & 63;
    int c = lane & 15, g = lane >> 4;

    const float* base = qkv + (size_t)s * MC * 3 * DD;
    const float* Qb = base + head * DH;
    const float* Kb = base + DD + head * DH;
    const float* Vb = base + 2 * DD + head * DH;

    // Q fragment (A operand), loaded once: row = q0+wave*16+c, k = g*8+j
    short8_t qfrag = {0,0,0,0,0,0,0,0};
    {
        int qr = q0 + wave * 16 + c;
        if (qr < Ms) {
            const float* qp = Qb + (size_t)qr * 3 * DD + g * 8;
            qfrag = pack8(*(const float4*)qp, *(const float4*)(qp + 4));
        }
    }

    f32x4 o0 = {0.f, 0.f, 0.f, 0.f}, o1 = {0.f, 0.f, 0.f, 0.f};
    f32x4 mreg = {-1e30f, -1e30f, -1e30f, -1e30f};
    f32x4 lreg = {0.f, 0.f, 0.f, 0.f};
    const float scale = 0.1767766952966369f;  // 1/sqrt(32)

    // staging assignments (coalesced global reads)
    int sko = tid >> 2, sg = tid & 3;          // key-offset 0..63, dim-group 0..3
    int s_nt = sko >> 4;                        // K: fragment tile
    int s_l  = (sko & 15) | (sg << 4);          // K: fragment lane slot
    int s_ks = sko >> 5, s_kk = sko & 31;       // V: kstep, key-in-step
    int s_j  = s_kk & 7, s_hi = (s_kk >> 3) & 3;
    int s_vnt = sg >> 1, s_db = (sg & 1) * 8;   // V: dim tile, dim base within tile

    for (int kb = kstart; kb < kend; kb += 64) {
        __syncthreads();   // previous chunk's fragment readers done
        {   // stage K fragment-slot (one 16B slot per thread)
            int key = kb + sko;
            short8_t kv = {0,0,0,0,0,0,0,0};
            if (key < kend) {
                const float* kr = Kb + (size_t)key * 3 * DD + sg * 8;
                kv = pack8(*(const float4*)kr, *(const float4*)(kr + 4));
            }
            *(short8_t*)&kf[s_nt][s_l][0] = kv;
        }
        {   // stage V: thread covers (key sko, dims sg*8..+7) -> 8 scattered b16 writes
            int key = kb + sko;
            float4 a = make_float4(0.f, 0.f, 0.f, 0.f);
            float4 b = make_float4(0.f, 0.f, 0.f, 0.f);
            if (key < kend) {
                const float* vr = Vb + (size_t)key * 3 * DD + sg * 8;
                a = *(const float4*)vr;
                b = *(const float4*)(vr + 4);
            }
            unsigned short* vslot = &vf[s_ks][s_vnt][0][0];
            vslot[((s_db + 0) | (s_hi << 4)) * 8 + s_j] = f2bf(a.x);
            vslot[((s_db + 1) | (s_hi << 4)) * 8 + s_j] = f2bf(a.y);
            vslot[((s_db + 2) | (s_hi << 4)) * 8 + s_j] = f2bf(a.z);
            vslot[((s_db + 3) | (s_hi << 4)) * 8 + s_j] = f2bf(a.w);
            vslot[((s_db + 4) | (s_hi << 4)) * 8 + s_j] = f2bf(b.x);
            vslot[((s_db + 5) | (s_hi << 4)) * 8 + s_j] = f2bf(b.y);
            vslot[((s_db + 6) | (s_hi << 4)) * 8 + s_j] = f2bf(b.z);
            vslot[((s_db + 7) | (s_hi << 4)) * 8 + s_j] = f2bf(b.w);
        }
        __syncthreads();

        // ---- QK^T: 4 n-tiles, one MFMA each (K=32 = DH) ----
        f32x4 zero = {0.f, 0.f, 0.f, 0.f};
        short8_t kf0 = *(const short8_t*)&kf[0][lane][0];
        short8_t kf1 = *(const short8_t*)&kf[1][lane][0];
        short8_t kf2 = *(const short8_t*)&kf[2][lane][0];
        short8_t kf3 = *(const short8_t*)&kf[3][lane][0];
        f32x4 a0 = __builtin_amdgcn_mfma_f32_16x16x32_bf16(qfrag, kf0, zero, 0, 0, 0);
        f32x4 a1 = __builtin_amdgcn_mfma_f32_16x16x32_bf16(qfrag, kf1, zero, 0, 0, 0);
        f32x4 a2 = __builtin_amdgcn_mfma_f32_16x16x32_bf16(qfrag, kf2, zero, 0, 0, 0);
        f32x4 a3 = __builtin_amdgcn_mfma_f32_16x16x32_bf16(qfrag, kf3, zero, 0, 0, 0);

        // mask + scale (col = nt*16 + c)
        f32x4 neg = {-1e30f, -1e30f, -1e30f, -1e30f};
        a0 = (kb +  0 + c < kend) ? a0 * scale : neg;
        a1 = (kb + 16 + c < kend) ? a1 * scale : neg;
        a2 = (kb + 32 + c < kend) ? a2 * scale : neg;
        a3 = (kb + 48 + c < kend) ? a3 * scale : neg;

        // ---- online softmax on 4 rows/lane ----
        f32x4 rmax = max4(max4(a0, a1), max4(a2, a3));
        rmax = max4(rmax, shflx4(rmax, 1));
        rmax = max4(rmax, shflx4(rmax, 2));
        rmax = max4(rmax, shflx4(rmax, 4));
        rmax = max4(rmax, shflx4(rmax, 8));
        f32x4 mnew = max4(mreg, rmax);
        f32x4 alpha = exp4(mreg - mnew);
        mreg = mnew;
        lreg = lreg * alpha;
        o0 = o0 * alpha;
        o1 = o1 * alpha;

        a0 = exp4(a0 - mnew);
        a1 = exp4(a1 - mnew);
        a2 = exp4(a2 - mnew);
        a3 = exp4(a3 - mnew);
        f32x4 rsum = (a0 + a1) + (a2 + a3);
        rsum = rsum + shflx4(rsum, 1);
        rsum = rsum + shflx4(rsum, 2);
        rsum = rsum + shflx4(rsum, 4);
        rsum = rsum + shflx4(rsum, 8);
        lreg = lreg + rsum;

        // ---- write P (bf16) to wave-private LDS: row=(g)*4+reg, col=nt*16+c ----
        {
            unsigned short* prow = &pf[wave][0][0];
            int rb = g * 4;
            prow[(rb + 0) * 80 +  0 + c] = f2bf(a0[0]);
            prow[(rb + 1) * 80 +  0 + c] = f2bf(a0[1]);
            prow[(rb + 2) * 80 +  0 + c] = f2bf(a0[2]);
            prow[(rb + 3) * 80 +  0 + c] = f2bf(a0[3]);
            prow[(rb + 0) * 80 + 16 + c] = f2bf(a1[0]);
            prow[(rb + 1) * 80 + 16 + c] = f2bf(a1[1]);
            prow[(rb + 2) * 80 + 16 + c] = f2bf(a1[2]);
            prow[(rb + 3) * 80 + 16 + c] = f2bf(a1[3]);
            prow[(rb + 0) * 80 + 32 + c] = f2bf(a2[0]);
            prow[(rb + 1) * 80 + 32 + c] = f2bf(a2[1]);
            prow[(rb + 2) * 80 + 32 + c] = f2bf(a2[2]);
            prow[(rb + 3) * 80 + 32 + c] = f2bf(a2[3]);
            prow[(rb + 0) * 80 + 48 + c] = f2bf(a3[0]);
            prow[(rb + 1) * 80 + 48 + c] = f2bf(a3[1]);
            prow[(rb + 2) * 80 + 48 + c] = f2bf(a3[2]);
            prow[(rb + 3) * 80 + 48 + c] = f2bf(a3[3]);
        }

        // ---- PV: A = P frag (row=c=q, k=keys), B = V frag; 2 ksteps x 2 dim-tiles ----
        {
            short8_t p0 = *(const short8_t*)&pf[wave][c][ 0 + g * 8];
            short8_t v00 = *(const short8_t*)&vf[0][0][lane][0];
            short8_t v01 = *(const short8_t*)&vf[0][1][lane][0];
            o0 = __builtin_amdgcn_mfma_f32_16x16x32_bf16(p0, v00, o0, 0, 0, 0);
            o1 = __builtin_amdgcn_mfma_f32_16x16x32_bf16(p0, v01, o1, 0, 0, 0);
            short8_t p1 = *(const short8_t*)&pf[wave][c][32 + g * 8];
            short8_t v10 = *(const short8_t*)&vf[1][0][lane][0];
            short8_t v11 = *(const short8_t*)&vf[1][1][lane][0];
            o0 = __builtin_amdgcn_mfma_f32_16x16x32_bf16(p1, v10, o0, 0, 0, 0);
            o1 = __builtin_amdgcn_mfma_f32_16x16x32_bf16(p1, v11, o1, 0, 0, 0);
        }
    }

    // ---- write partials: lane holds rows wave*16 + g*4 + reg, dims {c, 16+c} ----
    int rec = ((s * NHH + head) * 64 + blockIdx.x) * NSPLIT + part;
    float* po = part_o + (size_t)rec * 2048;
    int qb = wave * 16 + g * 4;
    po[(qb + 0) * 32 + c] = o0[0];
    po[(qb + 1) * 32 + c] = o0[1];
    po[(qb + 2) * 32 + c] = o0[2];
    po[(qb + 3) * 32 + c] = o0[3];
    po[(qb + 0) * 32 + 16 + c] = o1[0];
    po[(qb + 1) * 32 + 16 + c] = o1[1];
    po[(qb + 2) * 32 + 16 + c] = o1[2];
    po[(qb + 3) * 32 + 16 + c] = o1[3];
    if (c == 0) {
        part_ml[rec * 128 + qb + 0] = mreg[0];
        part_ml[rec * 128 + qb + 1] = mreg[1];
        part_ml[rec * 128 + qb + 2] = mreg[2];
        part_ml[rec * 128 + qb + 3] = mreg[3];
        part_ml[rec * 128 + 64 + qb + 0] = lreg[0];
        part_ml[rec * 128 + 64 + qb + 1] = lreg[1];
        part_ml[rec * 128 + 64 + qb + 2] = lreg[2];
        part_ml[rec * 128 + 64 + qb + 3] = lreg[3];
    }
}

// ---------------- merge split-K partials ----------------
__global__ void k_attn_comb(const float* __restrict__ part_o, const float* __restrict__ part_ml,
                            float* __restrict__ attno,
                            const int* M0, const int* M1, const int* M2)
{
    int s = blockIdx.z, head = blockIdx.y;
    int Ms = getM(s, M0, M1, M2);
    int q0 = blockIdx.x * 64;
    if (q0 >= Ms) return;
    int tid = threadIdx.x;
    int qi = tid >> 2, sub = tid & 3;
    int nparts = (Ms + PLEN - 1) / PLEN;
    if (nparts > NSPLIT) nparts = NSPLIT;
    int recbase = ((s * NHH + head) * 64 + blockIdx.x) * NSPLIT;

    float m = -1e30f;
    for (int p = 0; p < nparts; ++p)
        m = fmaxf(m, part_ml[(recbase + p) * 128 + qi]);
    float L = 0.f;
    float4 A0 = {0,0,0,0}, A1 = {0,0,0,0};
    for (int p = 0; p < nparts; ++p) {
        float mp = part_ml[(recbase + p) * 128 + qi];
        float lp = part_ml[(recbase + p) * 128 + 64 + qi];
        float w = __expf(mp - m);
        L += lp * w;
        const float* po = part_o + (size_t)(recbase + p) * 2048;
        float4 a = *(const float4*)(po + qi * 32 + sub * 4);
        float4 b = *(const float4*)(po + qi * 32 + (sub + 4) * 4);
        A0.x += a.x * w; A0.y += a.y * w; A0.z += a.z * w; A0.w += a.w * w;
        A1.x += b.x * w; A1.y += b.y * w; A1.z += b.z * w; A1.w += b.w * w;
    }
    if (q0 + qi < Ms) {
        float inv = 1.0f / fmaxf(L, 1e-30f);
        size_t orow = ((size_t)s * MC + q0 + qi) * DD + head * DH;
        float4 r0 = make_float4(A0.x * inv, A0.y * inv, A0.z * inv, A0.w * inv);
        float4 r1 = make_float4(A1.x * inv, A1.y * inv, A1.z * inv, A1.w * inv);
        *(float4*)(attno + orow + sub * 4) = r0;
        *(float4*)(attno + orow + (sub + 4) * 4) = r1;
    }
}

// ---------------- x1 = LN1(macro + attno @ Wo.T + bo) ----------------
__global__ void k_ln1(const float* __restrict__ macro, const float* __restrict__ attno,
                      const float* __restrict__ Wo, const float* __restrict__ bo,
                      const float* __restrict__ g, const float* __restrict__ b,
                      float* __restrict__ x1,
                      const int* M0, const int* M1, const int* M2)
{
    int s = blockIdx.y;
    int Ms = getM(s, M0, M1, M2);
    int m = blockIdx.x;
    if (m >= Ms) return;
    __shared__ __align__(16) float os[DD];
    __shared__ float red[4];
    int d = threadIdx.x;  // 128
    size_t row = (size_t)s * MC + m;
    os[d] = attno[row * DD + d];
    __syncthreads();
    const float* w = Wo + ((size_t)s * DD + d) * DD;
    float acc = bo[s * DD + d];
    for (int k = 0; k < DD; k += 4) {
        float4 w4 = *(const float4*)(w + k);
        float4 m4 = *(const float4*)&os[k];
        acc += w4.x * m4.x + w4.y * m4.y + w4.z * m4.z + w4.w * m4.w;
    }
    float xin = macro[row * DD + d] + acc;
    float sum = xin, sq = xin * xin;
    for (int off = 32; off >= 1; off >>= 1) { sum += __shfl_xor(sum, off); sq += __shfl_xor(sq, off); }
    if ((d & 63) == 0) { red[d >> 6] = sum; red[2 + (d >> 6)] = sq; }
    __syncthreads();
    sum = red[0] + red[1]; sq = red[2] + red[3];
    float mean = sum * (1.0f / DD);
    float var = fmaxf(sq * (1.0f / DD) - mean * mean, 0.0f);
    float xh = (xin - mean) * rsqrtf(var + 1e-5f);
    x1[row * DD + d] = xh * g[s * DD + d] + b[s * DD + d];
}

// ---------------- x2 = LN2(x1 + relu(x1@W1.T+b1)@W2.T + b2) ----------------
__global__ void k_ffn(const float* __restrict__ x1,
                      const float* __restrict__ W1, const float* __restrict__ b1,
                      const float* __restrict__ W2, const float* __restrict__ b2,
                      const float* __restrict__ g, const float* __restrict__ bb,
                      float* __restrict__ x2,
                      const int* M0, const int* M1, const int* M2)
{
    int s = blockIdx.y;
    int Ms = getM(s, M0, M1, M2);
    int m = blockIdx.x;
    if (m >= Ms) return;
    __shared__ __align__(16) float xr[DD];
    __shared__ __align__(16) float ts[FFD];
    __shared__ float red[8];
    int tid = threadIdx.x;  // 256
    size_t row = (size_t)s * MC + m;
    if (tid < DD) xr[tid] = x1[row * DD + tid];
    __syncthreads();
    {
        const float* w = W1 + ((size_t)s * FFD + tid) * DD;
        float acc = b1[s * FFD + tid];
        for (int k = 0; k < DD; k += 4) {
            float4 w4 = *(const float4*)(w + k);
            float4 m4 = *(const float4*)&xr[k];
            acc += w4.x * m4.x + w4.y * m4.y + w4.z * m4.z + w4.w * m4.w;
        }
        ts[tid] = fmaxf(acc, 0.0f);
    }
    __syncthreads();
    float xin = 0.0f;
    if (tid < DD) {
        const float* w = W2 + ((size_t)s * DD + tid) * FFD;
        float acc = b2[s * DD + tid];
        for (int k = 0; k < FFD; k += 4) {
            float4 w4 = *(const float4*)(w + k);
            float4 m4 = *(const float4*)&ts[k];
            acc += w4.x * m4.x + w4.y * m4.y + w4.z * m4.z + w4.w * m4.w;
        }
        xin = xr[tid] + acc;
    }
    float sum = xin, sq = xin * xin;
    for (int off = 32; off >= 1; off >>= 1) { sum += __shfl_xor(sum, off); sq += __shfl_xor(sq, off); }
    if ((tid & 63) == 0) { red[tid >> 6] = sum; red[4 + (tid >> 6)] = sq; }
    __syncthreads();
    sum = red[0] + red[1] + red[2] + red[3];
    sq = red[4] + red[5] + red[6] + red[7];
    float mean = sum * (1.0f / DD);
    float var = fmaxf(sq * (1.0f / DD) - mean * mean, 0.0f);
    if (tid < DD) {
        float xh = (xin - mean) * rsqrtf(var + 1e-5f);
        x2[row * DD + tid] = xh * g[s * DD + tid] + bb[s * DD + tid];
    }
}

// ---------------- y_s = x2_s @ Wf[:, 128*(s+1):128*(s+2)].T ----------------
__global__ void k_yproj(const float* __restrict__ x2, const float* __restrict__ Wf,
                        float* __restrict__ y,
                        const int* M0, const int* M1, const int* M2)
{
    int s = blockIdx.y;
    int Ms = getM(s, M0, M1, M2);
    int m = blockIdx.x;
    if (m >= Ms) return;
    __shared__ __align__(16) float xr[DD];
    int d = threadIdx.x;  // 128
    size_t row = (size_t)s * MC + m;
    xr[d] = x2[row * DD + d];
    __syncthreads();
    const float* w = Wf + (size_t)d * (4 * DD) + (s + 1) * DD;
    float acc = 0.0f;
    for (int k = 0; k < DD; k += 4) {
        float4 w4 = *(const float4*)(w + k);
        float4 m4 = *(const float4*)&xr[k];
        acc += w4.x * m4.x + w4.y * m4.y + w4.z * m4.z + w4.w * m4.w;
    }
    y[row * DD + d] = acc;
}

// ---------------- out = h@B0 (bf16 MFMA, weights-as-A) + gathers + bf ----------------
__global__ __launch_bounds__(256) void k_final(const float* __restrict__ h,
                                               const unsigned short* __restrict__ b0f,
                                               const float* __restrict__ y,
                                               const int* __restrict__ inv0,
                                               const int* __restrict__ inv1,
                                               const int* __restrict__ inv2,
                                               const float* __restrict__ bf,
                                               float* __restrict__ out, int N)
{
    __shared__ __align__(16) unsigned short hs[64][136];  // 272B row: 4-bank shift, 16B aligned
    int tid = threadIdx.x;
    int wave = tid >> 6, lane = tid & 63;
    int ntiles = (N + 63) >> 6;
    const float* y0 = y;
    const float* y1 = y + (size_t)MC * DD;
    const float* y2 = y + (size_t)2 * MC * DD;

    for (int t = blockIdx.x; t < ntiles; t += gridDim.x) {
        int pb = t * 64;
        __syncthreads();  // previous tile's readers done
        for (int e = tid; e < 64 * 32; e += 256) {   // 64 rows x 32 float4-units
            int row = e >> 5, u = e & 31;
            int p = pb + row;
            float4 v4 = make_float4(0.f, 0.f, 0.f, 0.f);
            if (p < N) v4 = *(const float4*)(h + (size_t)p * DD + u * 4);
            ushort4 b;
            b.x = f2bf(v4.x); b.y = f2bf(v4.y); b.z = f2bf(v4.z); b.w = f2bf(v4.w);
            *(ushort4*)&hs[row][u * 4] = b;
        }
        __syncthreads();

        int pl = wave * 16 + (lane & 15);
        int p = pb + pl;
        int i0 = 0, i1 = 0, i2 = 0;
        if (p < N) { i0 = inv0[p]; i1 = inv1[p]; i2 = inv2[p]; }
        const float* yr0 = y0 + (size_t)i0 * DD;
        const float* yr1 = y1 + (size_t)i1 * DD;
        const float* yr2 = y2 + (size_t)i2 * DD;

        short8_t hfr[4];
#pragma unroll
        for (int kt = 0; kt < 4; ++kt)
            hfr[kt] = *(const short8_t*)&hs[pl][kt * 32 + (lane >> 4) * 8];

#pragma unroll
        for (int nt = 0; nt < 8; ++nt) {
            f32x4 acc = {0.f, 0.f, 0.f, 0.f};
#pragma unroll
            for (int kt = 0; kt < 4; ++kt) {
                short8_t wfr = *(const short8_t*)(b0f + (size_t)((nt * 4 + kt) * 64 + lane) * 8);
                acc = __builtin_amdgcn_mfma_f32_16x16x32_bf16(wfr, hfr[kt], acc, 0, 0, 0);
            }
            if (p < N) {
                int d = nt * 16 + (lane >> 4) * 4;
                float4 g0 = *(const float4*)(yr0 + d);
                float4 g1 = *(const float4*)(yr1 + d);
                float4 g2 = *(const float4*)(yr2 + d);
                float4 b4 = *(const float4*)(bf + d);
                float4 r;
                r.x = acc[0] + g0.x + g1.x + g2.x + b4.x;
                r.y = acc[1] + g0.y + g1.y + g2.y + b4.y;
                r.z = acc[2] + g0.z + g1.z + g2.z + b4.z;
                r.w = acc[3] + g0.w + g1.w + g2.w + b4.w;
                *(float4*)(out + (size_t)p * DD + d) = r;
            }
        }
    }
}

extern "C" void kernel_launch(void* const* d_in, const int* in_sizes, int n_in,
                              void* d_out, int out_size, void* d_ws, size_t ws_size,
                              hipStream_t stream) {
    (void)n_in; (void)out_size; (void)ws_size;
    const float* h   = (const float*)d_in[0];
    const int* inv0  = (const int*)d_in[2];
    const int* inv1  = (const int*)d_in[3];
    const int* inv2  = (const int*)d_in[4];
    const int* M0    = (const int*)d_in[5];
    const int* M1    = (const int*)d_in[6];
    const int* M2    = (const int*)d_in[7];
    const float* Wqkv = (const float*)d_in[8];
    const float* bqkv = (const float*)d_in[9];
    const float* Wo   = (const float*)d_in[10];
    const float* bo   = (const float*)d_in[11];
    const float* ln1s = (const float*)d_in[12];
    const float* ln1b = (const float*)d_in[13];
    const float* W1   = (const float*)d_in[14];
    const float* b1   = (const float*)d_in[15];
    const float* W2   = (const float*)d_in[16];
    const float* b2   = (const float*)d_in[17];
    const float* ln2s = (const float*)d_in[18];
    const float* ln2b = (const float*)d_in[19];
    const float* Wf   = (const float*)d_in[20];
    const float* bf   = (const float*)d_in[21];
    int N = in_sizes[0] / DD;

    float* ws      = (float*)d_ws;
    float* macro   = ws;                                    // NS*MC*DD
    float* counts  = macro + (size_t)NS * MC * DD;          // NS*MC
    float* qkvb    = counts + (size_t)NS * MC;              // NS*MC*3*DD
    float* attno   = qkvb + (size_t)NS * MC * 3 * DD;       // NS*MC*DD
    float* x1      = attno + (size_t)NS * MC * DD;          // NS*MC*DD
    float* x2      = x1 + (size_t)NS * MC * DD;             // NS*MC*DD
    float* yb      = x2 + (size_t)NS * MC * DD;             // NS*MC*DD
    float* b0f_f   = yb + (size_t)NS * MC * DD;             // DD*DD floats of space (b0f uses half)
    unsigned short* b0f = (unsigned short*)b0f_f;
    float* part_o  = b0f_f + (size_t)DD * DD;               // NS*NHH*64*NSPLIT*2048
    float* part_ml = part_o + (size_t)NS * NHH * 64 * NSPLIT * 2048;  // NS*NHH*64*NSPLIT*128
    int* ip        = (int*)(part_ml + (size_t)NS * NHH * 64 * NSPLIT * 128);
    int* parent10  = ip;                // MC
    int* parent21  = parent10 + MC;     // 512
    int* cnt_i     = parent21 + 512;    // MC
    int* fill      = cnt_i + MC;        // MC
    int* offs      = fill + MC;         // MC
    int* order     = offs + MC;         // N

    float* sum0 = macro;
    float* sum1 = macro + (size_t)1 * MC * DD;
    float* sum2 = macro + (size_t)2 * MC * DD;
    float* cnt0 = counts;
    float* cnt1 = counts + MC;
    float* cnt2 = counts + 2 * MC;

    hipMemsetAsync(macro, 0, ((size_t)NS * MC * DD + NS * MC) * sizeof(float), stream);
    hipMemsetAsync(cnt_i, 0, (size_t)2 * MC * sizeof(int), stream);

    int nb = (N + 255) / 256;
    k_parent<<<nb, 256, 0, stream>>>(inv0, inv1, inv2, parent10, parent21, cnt_i, N);
    k_scan<<<1, 1024, 0, stream>>>(cnt_i, offs);
    k_place<<<nb, 256, 0, stream>>>(inv0, offs, fill, order, N);
    k_pool<<<MC, 256, 0, stream>>>(h, order, offs, cnt_i, sum0, cnt0, M0);
    k_rollup<<<(MC * DD) / 256, 256, 0, stream>>>(sum0, cnt0, parent10, sum1, cnt1, M0, MC);
    k_rollup<<<(512 * DD) / 256, 256, 0, stream>>>(sum1, cnt1, parent21, sum2, cnt2, M1, 512);
    k_finalize<<<(NS * MC * DD) / 256, 256, 0, stream>>>(macro, counts, M0, M1, M2);
    k_b0frag<<<64, 256, 0, stream>>>(Wf, b0f);
    k_qkv<<<dim3(MC / 8, NS), 256, 0, stream>>>(macro, Wqkv, bqkv, qkvb, M0, M1, M2);
    k_attn_part<<<dim3(MC / 64, NHH, NS * NSPLIT), 256, 0, stream>>>(qkvb, part_o, part_ml, M0, M1, M2);
    k_attn_comb<<<dim3(MC / 64, NHH, NS), 256, 0, stream>>>(part_o, part_ml, attno, M0, M1, M2);
    k_ln1<<<dim3(MC, NS), 128, 0, stream>>>(macro, attno, Wo, bo, ln1s, ln1b, x1, M0, M1, M2);
    k_ffn<<<dim3(MC, NS), 256, 0, stream>>>(x1, W1, b1, W2, b2, ln2s, ln2b, x2, M0, M1, M2);
    k_yproj<<<dim3(MC, NS), 128, 0, stream>>>(x2, Wf, yb, M0, M1, M2);
    k_final<<<2048, 256, 0, stream>>>(h, b0f, yb, inv0, inv1, inv2, bf, (float*)d_out, N);
}

// Round 11
// 722.041 us; speedup vs baseline: 2.7365x; 1.0477x over previous
//
#include <hip/hip_runtime.h>
#include <hip/hip_bf16.h>

#define MC 4096
#define DD 128
#define NHH 4
#define DH 32
#define FFD 256
#define NS 3
#define NSPLIT 4
#define PLEN 1024

typedef __attribute__((ext_vector_type(8))) short short8_t;
typedef __attribute__((ext_vector_type(4))) float f32x4;

__device__ __forceinline__ int getM(int s, const int* M0, const int* M1, const int* M2) {
    return (s == 0) ? *M0 : (s == 1) ? *M1 : *M2;
}

__device__ __forceinline__ unsigned short f2bf(float f) {
    unsigned int u = __float_as_uint(f);
    u += 0x7FFFu + ((u >> 16) & 1u);   // RNE
    return (unsigned short)(u >> 16);
}

__device__ __forceinline__ short8_t pack8(float4 a, float4 b) {
    short8_t r;
    r[0] = (short)f2bf(a.x); r[1] = (short)f2bf(a.y);
    r[2] = (short)f2bf(a.z); r[3] = (short)f2bf(a.w);
    r[4] = (short)f2bf(b.x); r[5] = (short)f2bf(b.y);
    r[6] = (short)f2bf(b.z); r[7] = (short)f2bf(b.w);
    return r;
}

__device__ __forceinline__ f32x4 max4(f32x4 a, f32x4 b) {
    f32x4 r;
    r[0] = fmaxf(a[0], b[0]); r[1] = fmaxf(a[1], b[1]);
    r[2] = fmaxf(a[2], b[2]); r[3] = fmaxf(a[3], b[3]);
    return r;
}
__device__ __forceinline__ f32x4 shflx4(f32x4 a, int m) {
    f32x4 r;
    r[0] = __shfl_xor(a[0], m); r[1] = __shfl_xor(a[1], m);
    r[2] = __shfl_xor(a[2], m); r[3] = __shfl_xor(a[3], m);
    return r;
}
__device__ __forceinline__ f32x4 exp4(f32x4 a) {
    f32x4 r;
    r[0] = __expf(a[0]); r[1] = __expf(a[1]);
    r[2] = __expf(a[2]); r[3] = __expf(a[3]);
    return r;
}

// ---------------- parent maps + scale-0 histogram in one pass ----------------
__global__ void k_parent(const int* __restrict__ inv0, const int* __restrict__ inv1,
                         const int* __restrict__ inv2,
                         int* __restrict__ parent10, int* __restrict__ parent21,
                         int* __restrict__ cnt, int N)
{
    int n = blockIdx.x * blockDim.x + threadIdx.x;
    if (n >= N) return;
    int i0 = inv0[n];
    parent10[i0] = inv1[n];   // duplicate writes all agree (grids nest)
    parent21[inv1[n]] = inv2[n];
    atomicAdd(&cnt[i0], 1);
}

// ---------------- exclusive scan over MC=4096 bins, single block 1024 thr ----------------
__global__ void k_scan(const int* __restrict__ cnt, int* __restrict__ offs)
{
    __shared__ int arr[1024];
    int tid = threadIdx.x;
    int base = tid * 4;
    int c0 = cnt[base], c1 = cnt[base + 1], c2 = cnt[base + 2], c3 = cnt[base + 3];
    int tot = c0 + c1 + c2 + c3;
    arr[tid] = tot;
    __syncthreads();
    for (int off = 1; off < 1024; off <<= 1) {
        int v = (tid >= off) ? arr[tid - off] : 0;
        __syncthreads();
        arr[tid] += v;
        __syncthreads();
    }
    int excl = arr[tid] - tot;
    offs[base] = excl;
    offs[base + 1] = excl + c0;
    offs[base + 2] = excl + c0 + c1;
    offs[base + 3] = excl + c0 + c1 + c2;
}

// ---------------- placement: order[] groups particles by voxel ----------------
__global__ void k_place(const int* __restrict__ inv0, const int* __restrict__ offs,
                        int* __restrict__ fill, int* __restrict__ order, int N)
{
    int n = blockIdx.x * blockDim.x + threadIdx.x;
    if (n >= N) return;
    int i0 = inv0[n];
    int pos = offs[i0] + atomicAdd(&fill[i0], 1);
    order[pos] = n;
}

// ---------------- pooled sums, no fp atomics: one block per voxel ----------------
__global__ __launch_bounds__(256) void k_pool(const float* __restrict__ h,
                                              const int* __restrict__ order,
                                              const int* __restrict__ offs,
                                              const int* __restrict__ cnt,
                                              float* __restrict__ sum0, float* __restrict__ cnt0,
                                              const int* __restrict__ M0)
{
    int v = blockIdx.x;
    if (v >= *M0) return;
    int beg = offs[v], len = cnt[v];
    int tid = threadIdx.x;
    int d = tid & 127, half = tid >> 7;
    float acc = 0.f;
    for (int j = half; j < len; j += 2) {
        int row = order[beg + j];
        acc += h[(size_t)row * DD + d];
    }
    __shared__ float red[DD];
    if (half == 1) red[d] = acc;
    __syncthreads();
    if (half == 0) {
        acc += red[d];
        sum0[(size_t)v * DD + d] = acc;
        if (d == 0) cnt0[v] = (float)len;
    }
}

// ---------------- roll coarse sums up the hierarchy ----------------
__global__ void k_rollup(const float* __restrict__ sumSrc, const float* __restrict__ cntSrc,
                         const int* __restrict__ parent,
                         float* __restrict__ sumDst, float* __restrict__ cntDst,
                         const int* __restrict__ Msrc, int cap)
{
    int idx = blockIdx.x * blockDim.x + threadIdx.x;   // < cap*DD
    int v = idx >> 7, d = idx & 127;
    int Ms = *Msrc;
    if (Ms > cap) Ms = cap;
    if (v >= Ms) return;
    int p = parent[v];
    atomicAdd(&sumDst[(size_t)p * DD + d], sumSrc[idx]);
    if (d == 0) atomicAdd(&cntDst[p], cntSrc[v]);
}

// ---------------- divide by clamped counts ----------------
__global__ void k_finalize(float* __restrict__ macro, const float* __restrict__ counts,
                           const int* M0, const int* M1, const int* M2)
{
    int idx = blockIdx.x * blockDim.x + threadIdx.x;  // < NS*MC*DD
    int s = idx / (MC * DD);
    int r = (idx >> 7) & (MC - 1);
    if (r >= getM(s, M0, M1, M2)) return;
    float c = counts[s * MC + r];
    macro[idx] /= fmaxf(c, 1.0f);
}

// ---------------- b0frag: MFMA fragments of Wf[:, :128] in bf16 ----------------
__global__ void k_b0frag(const float* __restrict__ Wf, unsigned short* __restrict__ b0f)
{
    int idx = blockIdx.x * 256 + threadIdx.x;  // 16384
    int j = idx & 7, l = (idx >> 3) & 63, kt = (idx >> 9) & 3, nt = idx >> 11;
    int d = nt * 16 + (l & 15);
    int k = kt * 32 + (l >> 4) * 8 + j;
    b0f[idx] = f2bf(Wf[(size_t)d * (4 * DD) + k]);
}

// ---------------- qkv = macro @ Wqkv[s].T + bqkv[s], 8 rows/block ----------------
__global__ void k_qkv(const float* __restrict__ macro, const float* __restrict__ Wqkv,
                      const float* __restrict__ bqkv, float* __restrict__ qkv,
                      const int* M0, const int* M1, const int* M2)
{
    int s = blockIdx.y;
    int Ms = getM(s, M0, M1, M2);
    int row0 = blockIdx.x * 8;
    if (row0 >= Ms) return;
    __shared__ __align__(16) float mac[8][DD];
    int tid = threadIdx.x;
    for (int e = tid; e < 8 * DD; e += 256) {
        int r = e >> 7, d = e & 127;
        int row = row0 + r;
        mac[r][d] = (row < Ms) ? macro[(size_t)s * MC * DD + (size_t)row * DD + d] : 0.0f;
    }
    __syncthreads();
    for (int j = tid; j < 3 * DD; j += 256) {
        const float* w = Wqkv + ((size_t)s * 3 * DD + j) * DD;
        float b = bqkv[s * 3 * DD + j];
        float acc[8];
#pragma unroll
        for (int r = 0; r < 8; ++r) acc[r] = b;
        for (int k = 0; k < DD; k += 4) {
            float4 w4 = *(const float4*)(w + k);
#pragma unroll
            for (int r = 0; r < 8; ++r) {
                float4 m4 = *(const float4*)&mac[r][k];
                acc[r] += w4.x * m4.x + w4.y * m4.y + w4.z * m4.z + w4.w * m4.w;
            }
        }
        for (int r = 0; r < 8; ++r) {
            int row = row0 + r;
            if (row < Ms) qkv[((size_t)s * MC + row) * (3 * DD) + j] = acc[r];
        }
    }
}

// ---------------- MFMA flash attention partials ----------------
__global__ __launch_bounds__(256) void k_attn_part(const float* __restrict__ qkv,
                                                   float* __restrict__ part_o,
                                                   float* __restrict__ part_ml,
                                                   const int* M0, const int* M1, const int* M2)
{
    int z = blockIdx.z;
    int s = z / NSPLIT, part = z % NSPLIT;
    int head = blockIdx.y;
    int Ms = getM(s, M0, M1, M2);
    int q0 = blockIdx.x * 64;
    if (q0 >= Ms) return;
    int kstart = part * PLEN;
    if (kstart >= Ms) return;
    int kend = kstart + PLEN; if (kend > Ms) kend = Ms;

    __shared__ __align__(16) unsigned short kf[4][64][8];
    __shared__ __align__(16) unsigned short vf[2][2][64][8];
    __shared__ __align__(16) unsigned short pf[4][16][80];

    int tid = threadIdx.x;
    int wave = tid >> 6, lane = tid & 63;
    int c = lane & 15, g = lane >> 4;

    const float* base = qkv + (size_t)s * MC * 3 * DD;
    const float* Qb = base + head * DH;
    const float* Kb = base + DD + head * DH;
    const float* Vb = base + 2 * DD + head * DH;

    short8_t qfrag = {0,0,0,0,0,0,0,0};
    {
        int qr = q0 + wave * 16 + c;
        if (qr < Ms) {
            const float* qp = Qb + (size_t)qr * 3 * DD + g * 8;
            qfrag = pack8(*(const float4*)qp, *(const float4*)(qp + 4));
        }
    }

    f32x4 o0 = {0.f, 0.f, 0.f, 0.f}, o1 = {0.f, 0.f, 0.f, 0.f};
    f32x4 mreg = {-1e30f, -1e30f, -1e30f, -1e30f};
    f32x4 lreg = {0.f, 0.f, 0.f, 0.f};
    const float scale = 0.1767766952966369f;  // 1/sqrt(32)

    int sko = tid >> 2, sg = tid & 3;
    int s_nt = sko >> 4;
    int s_l  = (sko & 15) | (sg << 4);
    int s_ks = sko >> 5, s_kk = sko & 31;
    int s_j  = s_kk & 7, s_hi = (s_kk >> 3) & 3;
    int s_vnt = sg >> 1, s_db = (sg & 1) * 8;

    for (int kb = kstart; kb < kend; kb += 64) {
        __syncthreads();
        {
            int key = kb + sko;
            short8_t kv = {0,0,0,0,0,0,0,0};
            if (key < kend) {
                const float* kr = Kb + (size_t)key * 3 * DD + sg * 8;
                kv = pack8(*(const float4*)kr, *(const float4*)(kr + 4));
            }
            *(short8_t*)&kf[s_nt][s_l][0] = kv;
        }
        {
            int key = kb + sko;
            float4 a = make_float4(0.f, 0.f, 0.f, 0.f);
            float4 b = make_float4(0.f, 0.f, 0.f, 0.f);
            if (key < kend) {
                const float* vr = Vb + (size_t)key * 3 * DD + sg * 8;
                a = *(const float4*)vr;
                b = *(const float4*)(vr + 4);
            }
            unsigned short* vslot = &vf[s_ks][s_vnt][0][0];
            vslot[((s_db + 0) | (s_hi << 4)) * 8 + s_j] = f2bf(a.x);
            vslot[((s_db + 1) | (s_hi << 4)) * 8 + s_j] = f2bf(a.y);
            vslot[((s_db + 2) | (s_hi << 4)) * 8 + s_j] = f2bf(a.z);
            vslot[((s_db + 3) | (s_hi << 4)) * 8 + s_j] = f2bf(a.w);
            vslot[((s_db + 4) | (s_hi << 4)) * 8 + s_j] = f2bf(b.x);
            vslot[((s_db + 5) | (s_hi << 4)) * 8 + s_j] = f2bf(b.y);
            vslot[((s_db + 6) | (s_hi << 4)) * 8 + s_j] = f2bf(b.z);
            vslot[((s_db + 7) | (s_hi << 4)) * 8 + s_j] = f2bf(b.w);
        }
        __syncthreads();

        f32x4 zero = {0.f, 0.f, 0.f, 0.f};
        short8_t kf0 = *(const short8_t*)&kf[0][lane][0];
        short8_t kf1 = *(const short8_t*)&kf[1][lane][0];
        short8_t kf2 = *(const short8_t*)&kf[2][lane][0];
        short8_t kf3 = *(const short8_t*)&kf[3][lane][0];
        f32x4 a0 = __builtin_amdgcn_mfma_f32_16x16x32_bf16(qfrag, kf0, zero, 0, 0, 0);
        f32x4 a1 = __builtin_amdgcn_mfma_f32_16x16x32_bf16(qfrag, kf1, zero, 0, 0, 0);
        f32x4 a2 = __builtin_amdgcn_mfma_f32_16x16x32_bf16(qfrag, kf2, zero, 0, 0, 0);
        f32x4 a3 = __builtin_amdgcn_mfma_f32_16x16x32_bf16(qfrag, kf3, zero, 0, 0, 0);

        f32x4 neg = {-1e30f, -1e30f, -1e30f, -1e30f};
        a0 = (kb +  0 + c < kend) ? a0 * scale : neg;
        a1 = (kb + 16 + c < kend) ? a1 * scale : neg;
        a2 = (kb + 32 + c < kend) ? a2 * scale : neg;
        a3 = (kb + 48 + c < kend) ? a3 * scale : neg;

        f32x4 rmax = max4(max4(a0, a1), max4(a2, a3));
        rmax = max4(rmax, shflx4(rmax, 1));
        rmax = max4(rmax, shflx4(rmax, 2));
        rmax = max4(rmax, shflx4(rmax, 4));
        rmax = max4(rmax, shflx4(rmax, 8));
        f32x4 mnew = max4(mreg, rmax);
        f32x4 alpha = exp4(mreg - mnew);
        mreg = mnew;
        lreg = lreg * alpha;
        o0 = o0 * alpha;
        o1 = o1 * alpha;

        a0 = exp4(a0 - mnew);
        a1 = exp4(a1 - mnew);
        a2 = exp4(a2 - mnew);
        a3 = exp4(a3 - mnew);
        f32x4 rsum = (a0 + a1) + (a2 + a3);
        rsum = rsum + shflx4(rsum, 1);
        rsum = rsum + shflx4(rsum, 2);
        rsum = rsum + shflx4(rsum, 4);
        rsum = rsum + shflx4(rsum, 8);
        lreg = lreg + rsum;

        {
            unsigned short* prow = &pf[wave][0][0];
            int rb = g * 4;
            prow[(rb + 0) * 80 +  0 + c] = f2bf(a0[0]);
            prow[(rb + 1) * 80 +  0 + c] = f2bf(a0[1]);
            prow[(rb + 2) * 80 +  0 + c] = f2bf(a0[2]);
            prow[(rb + 3) * 80 +  0 + c] = f2bf(a0[3]);
            prow[(rb + 0) * 80 + 16 + c] = f2bf(a1[0]);
            prow[(rb + 1) * 80 + 16 + c] = f2bf(a1[1]);
            prow[(rb + 2) * 80 + 16 + c] = f2bf(a1[2]);
            prow[(rb + 3) * 80 + 16 + c] = f2bf(a1[3]);
            prow[(rb + 0) * 80 + 32 + c] = f2bf(a2[0]);
            prow[(rb + 1) * 80 + 32 + c] = f2bf(a2[1]);
            prow[(rb + 2) * 80 + 32 + c] = f2bf(a2[2]);
            prow[(rb + 3) * 80 + 32 + c] = f2bf(a2[3]);
            prow[(rb + 0) * 80 + 48 + c] = f2bf(a3[0]);
            prow[(rb + 1) * 80 + 48 + c] = f2bf(a3[1]);
            prow[(rb + 2) * 80 + 48 + c] = f2bf(a3[2]);
            prow[(rb + 3) * 80 + 48 + c] = f2bf(a3[3]);
        }

        {
            short8_t p0 = *(const short8_t*)&pf[wave][c][ 0 + g * 8];
            short8_t v00 = *(const short8_t*)&vf[0][0][lane][0];
            short8_t v01 = *(const short8_t*)&vf[0][1][lane][0];
            o0 = __builtin_amdgcn_mfma_f32_16x16x32_bf16(p0, v00, o0, 0, 0, 0);
            o1 = __builtin_amdgcn_mfma_f32_16x16x32_bf16(p0, v01, o1, 0, 0, 0);
            short8_t p1 = *(const short8_t*)&pf[wave][c][32 + g * 8];
            short8_t v10 = *(const short8_t*)&vf[1][0][lane][0];
            short8_t v11 = *(const short8_t*)&vf[1][1][lane][0];
            o0 = __builtin_amdgcn_mfma_f32_16x16x32_bf16(p1, v10, o0, 0, 0, 0);
            o1 = __builtin_amdgcn_mfma_f32_16x16x32_bf16(p1, v11, o1, 0, 0, 0);
        }
    }

    int rec = ((s * NHH + head) * 64 + blockIdx.x) * NSPLIT + part;
    float* po = part_o + (size_t)rec * 2048;
    int qb = wave * 16 + g * 4;
    po[(qb + 0) * 32 + c] = o0[0];
    po[(qb + 1) * 32 + c] = o0[1];
    po[(qb + 2) * 32 + c] = o0[2];
    po[(qb + 3) * 32 + c] = o0[3];
    po[(qb + 0) * 32 + 16 + c] = o1[0];
    po[(qb + 1) * 32 + 16 + c] = o1[1];
    po[(qb + 2) * 32 + 16 + c] = o1[2];
    po[(qb + 3) * 32 + 16 + c] = o1[3];
    if (c == 0) {
        part_ml[rec * 128 + qb + 0] = mreg[0];
        part_ml[rec * 128 + qb + 1] = mreg[1];
        part_ml[rec * 128 + qb + 2] = mreg[2];
        part_ml[rec * 128 + qb + 3] = mreg[3];
        part_ml[rec * 128 + 64 + qb + 0] = lreg[0];
        part_ml[rec * 128 + 64 + qb + 1] = lreg[1];
        part_ml[rec * 128 + 64 + qb + 2] = lreg[2];
        part_ml[rec * 128 + 64 + qb + 3] = lreg[3];
    }
}

// ---------------- merge split-K partials ----------------
__global__ void k_attn_comb(const float* __restrict__ part_o, const float* __restrict__ part_ml,
                            float* __restrict__ attno,
                            const int* M0, const int* M1, const int* M2)
{
    int s = blockIdx.z, head = blockIdx.y;
    int Ms = getM(s, M0, M1, M2);
    int q0 = blockIdx.x * 64;
    if (q0 >= Ms) return;
    int tid = threadIdx.x;
    int qi = tid >> 2, sub = tid & 3;
    int nparts = (Ms + PLEN - 1) / PLEN;
    if (nparts > NSPLIT) nparts = NSPLIT;
    int recbase = ((s * NHH + head) * 64 + blockIdx.x) * NSPLIT;

    float m = -1e30f;
    for (int p = 0; p < nparts; ++p)
        m = fmaxf(m, part_ml[(recbase + p) * 128 + qi]);
    float L = 0.f;
    float4 A0 = {0,0,0,0}, A1 = {0,0,0,0};
    for (int p = 0; p < nparts; ++p) {
        float mp = part_ml[(recbase + p) * 128 + qi];
        float lp = part_ml[(recbase + p) * 128 + 64 + qi];
        float w = __expf(mp - m);
        L += lp * w;
        const float* po = part_o + (size_t)(recbase + p) * 2048;
        float4 a = *(const float4*)(po + qi * 32 + sub * 4);
        float4 b = *(const float4*)(po + qi * 32 + (sub + 4) * 4);
        A0.x += a.x * w; A0.y += a.y * w; A0.z += a.z * w; A0.w += a.w * w;
        A1.x += b.x * w; A1.y += b.y * w; A1.z += b.z * w; A1.w += b.w * w;
    }
    if (q0 + qi < Ms) {
        float inv = 1.0f / fmaxf(L, 1e-30f);
        size_t orow = ((size_t)s * MC + q0 + qi) * DD + head * DH;
        float4 r0 = make_float4(A0.x * inv, A0.y * inv, A0.z * inv, A0.w * inv);
        float4 r1 = make_float4(A1.x * inv, A1.y * inv, A1.z * inv, A1.w * inv);
        *(float4*)(attno + orow + sub * 4) = r0;
        *(float4*)(attno + orow + (sub + 4) * 4) = r1;
    }
}

// ---------------- x1 = LN1(macro + attno @ Wo.T + bo) ----------------
__global__ void k_ln1(const float* __restrict__ macro, const float* __restrict__ attno,
                      const float* __restrict__ Wo, const float* __restrict__ bo,
                      const float* __restrict__ g, const float* __restrict__ b,
                      float* __restrict__ x1,
                      const int* M0, const int* M1, const int* M2)
{
    int s = blockIdx.y;
    int Ms = getM(s, M0, M1, M2);
    int m = blockIdx.x;
    if (m >= Ms) return;
    __shared__ __align__(16) float os[DD];
    __shared__ float red[4];
    int d = threadIdx.x;  // 128
    size_t row = (size_t)s * MC + m;
    os[d] = attno[row * DD + d];
    __syncthreads();
    const float* w = Wo + ((size_t)s * DD + d) * DD;
    float acc = bo[s * DD + d];
    for (int k = 0; k < DD; k += 4) {
        float4 w4 = *(const float4*)(w + k);
        float4 m4 = *(const float4*)&os[k];
        acc += w4.x * m4.x + w4.y * m4.y + w4.z * m4.z + w4.w * m4.w;
    }
    float xin = macro[row * DD + d] + acc;
    float sum = xin, sq = xin * xin;
    for (int off = 32; off >= 1; off >>= 1) { sum += __shfl_xor(sum, off); sq += __shfl_xor(sq, off); }
    if ((d & 63) == 0) { red[d >> 6] = sum; red[2 + (d >> 6)] = sq; }
    __syncthreads();
    sum = red[0] + red[1]; sq = red[2] + red[3];
    float mean = sum * (1.0f / DD);
    float var = fmaxf(sq * (1.0f / DD) - mean * mean, 0.0f);
    float xh = (xin - mean) * rsqrtf(var + 1e-5f);
    x1[row * DD + d] = xh * g[s * DD + d] + b[s * DD + d];
}

// ---------------- x2 = LN2(x1 + relu(x1@W1.T+b1)@W2.T + b2) ----------------
__global__ void k_ffn(const float* __restrict__ x1,
                      const float* __restrict__ W1, const float* __restrict__ b1,
                      const float* __restrict__ W2, const float* __restrict__ b2,
                      const float* __restrict__ g, const float* __restrict__ bb,
                      float* __restrict__ x2,
                      const int* M0, const int* M1, const int* M2)
{
    int s = blockIdx.y;
    int Ms = getM(s, M0, M1, M2);
    int m = blockIdx.x;
    if (m >= Ms) return;
    __shared__ __align__(16) float xr[DD];
    __shared__ __align__(16) float ts[FFD];
    __shared__ float red[8];
    int tid = threadIdx.x;  // 256
    size_t row = (size_t)s * MC + m;
    if (tid < DD) xr[tid] = x1[row * DD + tid];
    __syncthreads();
    {
        const float* w = W1 + ((size_t)s * FFD + tid) * DD;
        float acc = b1[s * FFD + tid];
        for (int k = 0; k < DD; k += 4) {
            float4 w4 = *(const float4*)(w + k);
            float4 m4 = *(const float4*)&xr[k];
            acc += w4.x * m4.x + w4.y * m4.y + w4.z * m4.z + w4.w * m4.w;
        }
        ts[tid] = fmaxf(acc, 0.0f);
    }
    __syncthreads();
    float xin = 0.0f;
    if (tid < DD) {
        const float* w = W2 + ((size_t)s * DD + tid) * FFD;
        float acc = b2[s * DD + tid];
        for (int k = 0; k < FFD; k += 4) {
            float4 w4 = *(const float4*)(w + k);
            float4 m4 = *(const float4*)&ts[k];
            acc += w4.x * m4.x + w4.y * m4.y + w4.z * m4.z + w4.w * m4.w;
        }
        xin = xr[tid] + acc;
    }
    float sum = xin, sq = xin * xin;
    for (int off = 32; off >= 1; off >>= 1) { sum += __shfl_xor(sum, off); sq += __shfl_xor(sq, off); }
    if ((tid & 63) == 0) { red[tid >> 6] = sum; red[4 + (tid >> 6)] = sq; }
    __syncthreads();
    sum = red[0] + red[1] + red[2] + red[3];
    sq = red[4] + red[5] + red[6] + red[7];
    float mean = sum * (1.0f / DD);
    float var = fmaxf(sq * (1.0f / DD) - mean * mean, 0.0f);
    if (tid < DD) {
        float xh = (xin - mean) * rsqrtf(var + 1e-5f);
        x2[row * DD + tid] = xh * g[s * DD + tid] + bb[s * DD + tid];
    }
}

// ---------------- y_s = x2_s @ Wf[:, 128*(s+1):128*(s+2)].T ----------------
__global__ void k_yproj(const float* __restrict__ x2, const float* __restrict__ Wf,
                        float* __restrict__ y,
                        const int* M0, const int* M1, const int* M2)
{
    int s = blockIdx.y;
    int Ms = getM(s, M0, M1, M2);
    int m = blockIdx.x;
    if (m >= Ms) return;
    __shared__ __align__(16) float xr[DD];
    int d = threadIdx.x;  // 128
    size_t row = (size_t)s * MC + m;
    xr[d] = x2[row * DD + d];
    __syncthreads();
    const float* w = Wf + (size_t)d * (4 * DD) + (s + 1) * DD;
    float acc = 0.0f;
    for (int k = 0; k < DD; k += 4) {
        float4 w4 = *(const float4*)(w + k);
        float4 m4 = *(const float4*)&xr[k];
        acc += w4.x * m4.x + w4.y * m4.y + w4.z * m4.z + w4.w * m4.w;
    }
    y[row * DD + d] = acc;
}

// ---------------- out = h@B0 (bf16 MFMA) + gathers + bf: NO LDS, NO barriers ----------------
// R10 k_final was latency-bound (22% occ from 17.4KB LDS + 2 barriers/tile; both pipes idle).
// One WAVE owns a 16-particle task; h fragments packed global->register directly (the 4
// g-lanes of a row each read dims kt*32+g*8..+7 -> every 64B line fully consumed, no reuse
// lost). Zero LDS -> VGPR-bound occupancy; independent waves hide y-gather latency.
__global__ __launch_bounds__(256) void k_final(const float* __restrict__ h,
                                               const unsigned short* __restrict__ b0f,
                                               const float* __restrict__ y,
                                               const int* __restrict__ inv0,
                                               const int* __restrict__ inv1,
                                               const int* __restrict__ inv2,
                                               const float* __restrict__ bf,
                                               float* __restrict__ out, int N)
{
    int tid = threadIdx.x;
    int wave = tid >> 6, lane = tid & 63;
    int c = lane & 15, g = lane >> 4;
    const float* y0 = y;
    const float* y1 = y + (size_t)MC * DD;
    const float* y2 = y + (size_t)2 * MC * DD;

    int ntasks = (N + 15) >> 4;                 // 16-particle tasks
    int task = blockIdx.x * 4 + wave;
    int tstride = gridDim.x * 4;

    for (; task < ntasks; task += tstride) {
        int p = task * 16 + c;
        bool ok = (p < N);

        // h fragments (B operand): col = c (particle), k = kt*32 + g*8 + j
        short8_t hfr0 = {0,0,0,0,0,0,0,0};
        short8_t hfr1 = hfr0, hfr2 = hfr0, hfr3 = hfr0;
        int i0 = 0, i1 = 0, i2 = 0;
        if (ok) {
            const float* hrow = h + (size_t)p * DD + g * 8;
            hfr0 = pack8(*(const float4*)(hrow +  0), *(const float4*)(hrow +  4));
            hfr1 = pack8(*(const float4*)(hrow + 32), *(const float4*)(hrow + 36));
            hfr2 = pack8(*(const float4*)(hrow + 64), *(const float4*)(hrow + 68));
            hfr3 = pack8(*(const float4*)(hrow + 96), *(const float4*)(hrow + 100));
            i0 = inv0[p]; i1 = inv1[p]; i2 = inv2[p];
        }
        const float* yr0 = y0 + (size_t)i0 * DD;
        const float* yr1 = y1 + (size_t)i1 * DD;
        const float* yr2 = y2 + (size_t)i2 * DD;

#pragma unroll
        for (int nt = 0; nt < 8; ++nt) {
            f32x4 acc = {0.f, 0.f, 0.f, 0.f};
            {
                short8_t w0 = *(const short8_t*)(b0f + (size_t)((nt * 4 + 0) * 64 + lane) * 8);
                acc = __builtin_amdgcn_mfma_f32_16x16x32_bf16(w0, hfr0, acc, 0, 0, 0);
                short8_t w1 = *(const short8_t*)(b0f + (size_t)((nt * 4 + 1) * 64 + lane) * 8);
                acc = __builtin_amdgcn_mfma_f32_16x16x32_bf16(w1, hfr1, acc, 0, 0, 0);
                short8_t w2 = *(const short8_t*)(b0f + (size_t)((nt * 4 + 2) * 64 + lane) * 8);
                acc = __builtin_amdgcn_mfma_f32_16x16x32_bf16(w2, hfr2, acc, 0, 0, 0);
                short8_t w3 = *(const short8_t*)(b0f + (size_t)((nt * 4 + 3) * 64 + lane) * 8);
                acc = __builtin_amdgcn_mfma_f32_16x16x32_bf16(w3, hfr3, acc, 0, 0, 0);
            }
            if (ok) {
                int d = nt * 16 + g * 4;        // C/D: row=(l>>4)*4+reg = dim, col=c = particle
                float4 g0 = *(const float4*)(yr0 + d);
                float4 g1 = *(const float4*)(yr1 + d);
                float4 g2 = *(const float4*)(yr2 + d);
                float4 b4 = *(const float4*)(bf + d);
                float4 r;
                r.x = acc[0] + g0.x + g1.x + g2.x + b4.x;
                r.y = acc[1] + g0.y + g1.y + g2.y + b4.y;
                r.z = acc[2] + g0.z + g1.z + g2.z + b4.z;
                r.w = acc[3] + g0.w + g1.w + g2.w + b4.w;
                *(float4*)(out + (size_t)p * DD + d) = r;
            }
        }
    }
}

extern "C" void kernel_launch(void* const* d_in, const int* in_sizes, int n_in,
                              void* d_out, int out_size, void* d_ws, size_t ws_size,
                              hipStream_t stream) {
    (void)n_in; (void)out_size; (void)ws_size;
    const float* h   = (const float*)d_in[0];
    const int* inv0  = (const int*)d_in[2];
    const int* inv1  = (const int*)d_in[3];
    const int* inv2  = (const int*)d_in[4];
    const int* M0    = (const int*)d_in[5];
    const int* M1    = (const int*)d_in[6];
    const int* M2    = (const int*)d_in[7];
    const float* Wqkv = (const float*)d_in[8];
    const float* bqkv = (const float*)d_in[9];
    const float* Wo   = (const float*)d_in[10];
    const float* bo   = (const float*)d_in[11];
    const float* ln1s = (const float*)d_in[12];
    const float* ln1b = (const float*)d_in[13];
    const float* W1   = (const float*)d_in[14];
    const float* b1   = (const float*)d_in[15];
    const float* W2   = (const float*)d_in[16];
    const float* b2   = (const float*)d_in[17];
    const float* ln2s = (const float*)d_in[18];
    const float* ln2b = (const float*)d_in[19];
    const float* Wf   = (const float*)d_in[20];
    const float* bf   = (const float*)d_in[21];
    int N = in_sizes[0] / DD;

    float* ws      = (float*)d_ws;
    float* macro   = ws;                                    // NS*MC*DD
    float* counts  = macro + (size_t)NS * MC * DD;          // NS*MC
    float* qkvb    = counts + (size_t)NS * MC;              // NS*MC*3*DD
    float* attno   = qkvb + (size_t)NS * MC * 3 * DD;       // NS*MC*DD
    float* x1      = attno + (size_t)NS * MC * DD;          // NS*MC*DD
    float* x2      = x1 + (size_t)NS * MC * DD;             // NS*MC*DD
    float* yb      = x2 + (size_t)NS * MC * DD;             // NS*MC*DD
    float* b0f_f   = yb + (size_t)NS * MC * DD;             // DD*DD floats of space (b0f uses half)
    unsigned short* b0f = (unsigned short*)b0f_f;
    float* part_o  = b0f_f + (size_t)DD * DD;               // NS*NHH*64*NSPLIT*2048
    float* part_ml = part_o + (size_t)NS * NHH * 64 * NSPLIT * 2048;  // NS*NHH*64*NSPLIT*128
    int* ip        = (int*)(part_ml + (size_t)NS * NHH * 64 * NSPLIT * 128);
    int* parent10  = ip;                // MC
    int* parent21  = parent10 + MC;     // 512
    int* cnt_i     = parent21 + 512;    // MC
    int* fill      = cnt_i + MC;        // MC
    int* offs      = fill + MC;         // MC
    int* order     = offs + MC;         // N

    float* sum0 = macro;
    float* sum1 = macro + (size_t)1 * MC * DD;
    float* sum2 = macro + (size_t)2 * MC * DD;
    float* cnt0 = counts;
    float* cnt1 = counts + MC;
    float* cnt2 = counts + 2 * MC;

    hipMemsetAsync(macro, 0, ((size_t)NS * MC * DD + NS * MC) * sizeof(float), stream);
    hipMemsetAsync(cnt_i, 0, (size_t)2 * MC * sizeof(int), stream);

    int nb = (N + 255) / 256;
    k_parent<<<nb, 256, 0, stream>>>(inv0, inv1, inv2, parent10, parent21, cnt_i, N);
    k_scan<<<1, 1024, 0, stream>>>(cnt_i, offs);
    k_place<<<nb, 256, 0, stream>>>(inv0, offs, fill, order, N);
    k_pool<<<MC, 256, 0, stream>>>(h, order, offs, cnt_i, sum0, cnt0, M0);
    k_rollup<<<(MC * DD) / 256, 256, 0, stream>>>(sum0, cnt0, parent10, sum1, cnt1, M0, MC);
    k_rollup<<<(512 * DD) / 256, 256, 0, stream>>>(sum1, cnt1, parent21, sum2, cnt2, M1, 512);
    k_finalize<<<(NS * MC * DD) / 256, 256, 0, stream>>>(macro, counts, M0, M1, M2);
    k_b0frag<<<64, 256, 0, stream>>>(Wf, b0f);
    k_qkv<<<dim3(MC / 8, NS), 256, 0, stream>>>(macro, Wqkv, bqkv, qkvb, M0, M1, M2);
    k_attn_part<<<dim3(MC / 64, NHH, NS * NSPLIT), 256, 0, stream>>>(qkvb, part_o, part_ml, M0, M1, M2);
    k_attn_comb<<<dim3(MC / 64, NHH, NS), 256, 0, stream>>>(part_o, part_ml, attno, M0, M1, M2);
    k_ln1<<<dim3(MC, NS), 128, 0, stream>>>(macro, attno, Wo, bo, ln1s, ln1b, x1, M0, M1, M2);
    k_ffn<<<dim3(MC, NS), 256, 0, stream>>>(x1, W1, b1, W2, b2, ln2s, ln2b, x2, M0, M1, M2);
    k_yproj<<<dim3(MC, NS), 128, 0, stream>>>(x2, Wf, yb, M0, M1, M2);
    k_final<<<2048, 256, 0, stream>>>(h, b0f, yb, inv0, inv1, inv2, bf, (float*)d_out, N);
}

// Round 12
// 640.690 us; speedup vs baseline: 3.0840x; 1.1270x over previous
//
#include <hip/hip_runtime.h>
#include <hip/hip_bf16.h>

#define MC 4096
#define DD 128
#define NHH 4
#define DH 32
#define FFD 256
#define NS 3
#define NSPLIT 4
#define PLEN 1024

typedef __attribute__((ext_vector_type(8))) short short8_t;
typedef __attribute__((ext_vector_type(4))) float f32x4;

__device__ __forceinline__ int getM(int s, const int* M0, const int* M1, const int* M2) {
    return (s == 0) ? *M0 : (s == 1) ? *M1 : *M2;
}

__device__ __forceinline__ unsigned short f2bf(float f) {
    unsigned int u = __float_as_uint(f);
    u += 0x7FFFu + ((u >> 16) & 1u);   // RNE
    return (unsigned short)(u >> 16);
}

__device__ __forceinline__ short8_t pack8(float4 a, float4 b) {
    short8_t r;
    r[0] = (short)f2bf(a.x); r[1] = (short)f2bf(a.y);
    r[2] = (short)f2bf(a.z); r[3] = (short)f2bf(a.w);
    r[4] = (short)f2bf(b.x); r[5] = (short)f2bf(b.y);
    r[6] = (short)f2bf(b.z); r[7] = (short)f2bf(b.w);
    return r;
}

__device__ __forceinline__ f32x4 max4(f32x4 a, f32x4 b) {
    f32x4 r;
    r[0] = fmaxf(a[0], b[0]); r[1] = fmaxf(a[1], b[1]);
    r[2] = fmaxf(a[2], b[2]); r[3] = fmaxf(a[3], b[3]);
    return r;
}
__device__ __forceinline__ f32x4 shflx4(f32x4 a, int m) {
    f32x4 r;
    r[0] = __shfl_xor(a[0], m); r[1] = __shfl_xor(a[1], m);
    r[2] = __shfl_xor(a[2], m); r[3] = __shfl_xor(a[3], m);
    return r;
}
__device__ __forceinline__ f32x4 exp4(f32x4 a) {
    f32x4 r;
    r[0] = __expf(a[0]); r[1] = __expf(a[1]);
    r[2] = __expf(a[2]); r[3] = __expf(a[3]);
    return r;
}

// ---------------- parent maps + scale-0 histogram in one pass ----------------
__global__ void k_parent(const int* __restrict__ inv0, const int* __restrict__ inv1,
                         const int* __restrict__ inv2,
                         int* __restrict__ parent10, int* __restrict__ parent21,
                         int* __restrict__ cnt, int N)
{
    int n = blockIdx.x * blockDim.x + threadIdx.x;
    if (n >= N) return;
    int i0 = inv0[n];
    parent10[i0] = inv1[n];   // duplicate writes all agree (grids nest)
    parent21[inv1[n]] = inv2[n];
    atomicAdd(&cnt[i0], 1);
}

// ---------------- exclusive scan over MC=4096 bins, single block 1024 thr ----------------
__global__ void k_scan(const int* __restrict__ cnt, int* __restrict__ offs)
{
    __shared__ int arr[1024];
    int tid = threadIdx.x;
    int base = tid * 4;
    int c0 = cnt[base], c1 = cnt[base + 1], c2 = cnt[base + 2], c3 = cnt[base + 3];
    int tot = c0 + c1 + c2 + c3;
    arr[tid] = tot;
    __syncthreads();
    for (int off = 1; off < 1024; off <<= 1) {
        int v = (tid >= off) ? arr[tid - off] : 0;
        __syncthreads();
        arr[tid] += v;
        __syncthreads();
    }
    int excl = arr[tid] - tot;
    offs[base] = excl;
    offs[base + 1] = excl + c0;
    offs[base + 2] = excl + c0 + c1;
    offs[base + 3] = excl + c0 + c1 + c2;
}

// ---------------- placement: order[] groups particles by voxel ----------------
__global__ void k_place(const int* __restrict__ inv0, const int* __restrict__ offs,
                        int* __restrict__ fill, int* __restrict__ order, int N)
{
    int n = blockIdx.x * blockDim.x + threadIdx.x;
    if (n >= N) return;
    int i0 = inv0[n];
    int pos = offs[i0] + atomicAdd(&fill[i0], 1);
    order[pos] = n;
}

// ---------------- pooled sums: float4/thread, 8 row-slots, 2x unrolled ----------------
// R11: old k_pool was issue/latency-bound (occ 81%, VALU 6%, BW 9%): scalar 4B gathers,
// 2 rows in flight, 61 serial iters. Now: 32 lanes x float4 cover a row, 8 row slots
// per block, manual 2x unroll (named regs) -> 16 independent float4 gathers in flight.
__global__ __launch_bounds__(256) void k_pool(const float* __restrict__ h,
                                              const int* __restrict__ order,
                                              const int* __restrict__ offs,
                                              const int* __restrict__ cnt,
                                              float* __restrict__ sum0, float* __restrict__ cnt0,
                                              const int* __restrict__ M0)
{
    int v = blockIdx.x;
    if (v >= *M0) return;
    int beg = offs[v], len = cnt[v];
    int tid = threadIdx.x;
    int dg = tid & 31;          // dim group: dims dg*4 .. dg*4+3
    int rs = tid >> 5;          // row slot 0..7
    const int* op = order + beg;

    float ax = 0.f, ay = 0.f, az = 0.f, aw = 0.f;
    int j = rs;
    for (; j + 8 < len; j += 16) {
        int r0 = op[j];
        int r1 = op[j + 8];
        float4 a = *(const float4*)(h + (size_t)r0 * DD + dg * 4);
        float4 b = *(const float4*)(h + (size_t)r1 * DD + dg * 4);
        ax += a.x + b.x; ay += a.y + b.y; az += a.z + b.z; aw += a.w + b.w;
    }
    if (j < len) {
        int r0 = op[j];
        float4 a = *(const float4*)(h + (size_t)r0 * DD + dg * 4);
        ax += a.x; ay += a.y; az += a.z; aw += a.w;
    }

    __shared__ __align__(16) float red[8][DD];
    *(float4*)&red[rs][dg * 4] = make_float4(ax, ay, az, aw);
    __syncthreads();
    if (tid < 32) {
        float4 t0 = *(const float4*)&red[0][tid * 4];
        float4 t1 = *(const float4*)&red[1][tid * 4];
        float4 t2 = *(const float4*)&red[2][tid * 4];
        float4 t3 = *(const float4*)&red[3][tid * 4];
        float4 t4 = *(const float4*)&red[4][tid * 4];
        float4 t5 = *(const float4*)&red[5][tid * 4];
        float4 t6 = *(const float4*)&red[6][tid * 4];
        float4 t7 = *(const float4*)&red[7][tid * 4];
        float4 r;
        r.x = ((t0.x + t1.x) + (t2.x + t3.x)) + ((t4.x + t5.x) + (t6.x + t7.x));
        r.y = ((t0.y + t1.y) + (t2.y + t3.y)) + ((t4.y + t5.y) + (t6.y + t7.y));
        r.z = ((t0.z + t1.z) + (t2.z + t3.z)) + ((t4.z + t5.z) + (t6.z + t7.z));
        r.w = ((t0.w + t1.w) + (t2.w + t3.w)) + ((t4.w + t5.w) + (t6.w + t7.w));
        *(float4*)(sum0 + (size_t)v * DD + tid * 4) = r;
        if (tid == 0) cnt0[v] = (float)len;
    }
}

// ---------------- roll coarse sums up the hierarchy ----------------
__global__ void k_rollup(const float* __restrict__ sumSrc, const float* __restrict__ cntSrc,
                         const int* __restrict__ parent,
                         float* __restrict__ sumDst, float* __restrict__ cntDst,
                         const int* __restrict__ Msrc, int cap)
{
    int idx = blockIdx.x * blockDim.x + threadIdx.x;   // < cap*DD
    int v = idx >> 7, d = idx & 127;
    int Ms = *Msrc;
    if (Ms > cap) Ms = cap;
    if (v >= Ms) return;
    int p = parent[v];
    atomicAdd(&sumDst[(size_t)p * DD + d], sumSrc[idx]);
    if (d == 0) atomicAdd(&cntDst[p], cntSrc[v]);
}

// ---------------- divide by clamped counts ----------------
__global__ void k_finalize(float* __restrict__ macro, const float* __restrict__ counts,
                           const int* M0, const int* M1, const int* M2)
{
    int idx = blockIdx.x * blockDim.x + threadIdx.x;  // < NS*MC*DD
    int s = idx / (MC * DD);
    int r = (idx >> 7) & (MC - 1);
    if (r >= getM(s, M0, M1, M2)) return;
    float c = counts[s * MC + r];
    macro[idx] /= fmaxf(c, 1.0f);
}

// ---------------- b0frag: MFMA fragments of Wf[:, :128] in bf16 ----------------
__global__ void k_b0frag(const float* __restrict__ Wf, unsigned short* __restrict__ b0f)
{
    int idx = blockIdx.x * 256 + threadIdx.x;  // 16384
    int j = idx & 7, l = (idx >> 3) & 63, kt = (idx >> 9) & 3, nt = idx >> 11;
    int d = nt * 16 + (l & 15);
    int k = kt * 32 + (l >> 4) * 8 + j;
    b0f[idx] = f2bf(Wf[(size_t)d * (4 * DD) + k]);
}

// ---------------- qkv = macro @ Wqkv[s].T + bqkv[s], 8 rows/block ----------------
__global__ void k_qkv(const float* __restrict__ macro, const float* __restrict__ Wqkv,
                      const float* __restrict__ bqkv, float* __restrict__ qkv,
                      const int* M0, const int* M1, const int* M2)
{
    int s = blockIdx.y;
    int Ms = getM(s, M0, M1, M2);
    int row0 = blockIdx.x * 8;
    if (row0 >= Ms) return;
    __shared__ __align__(16) float mac[8][DD];
    int tid = threadIdx.x;
    for (int e = tid; e < 8 * DD; e += 256) {
        int r = e >> 7, d = e & 127;
        int row = row0 + r;
        mac[r][d] = (row < Ms) ? macro[(size_t)s * MC * DD + (size_t)row * DD + d] : 0.0f;
    }
    __syncthreads();
    for (int j = tid; j < 3 * DD; j += 256) {
        const float* w = Wqkv + ((size_t)s * 3 * DD + j) * DD;
        float b = bqkv[s * 3 * DD + j];
        float acc[8];
#pragma unroll
        for (int r = 0; r < 8; ++r) acc[r] = b;
        for (int k = 0; k < DD; k += 4) {
            float4 w4 = *(const float4*)(w + k);
#pragma unroll
            for (int r = 0; r < 8; ++r) {
                float4 m4 = *(const float4*)&mac[r][k];
                acc[r] += w4.x * m4.x + w4.y * m4.y + w4.z * m4.z + w4.w * m4.w;
            }
        }
        for (int r = 0; r < 8; ++r) {
            int row = row0 + r;
            if (row < Ms) qkv[((size_t)s * MC + row) * (3 * DD) + j] = acc[r];
        }
    }
}

// ---------------- MFMA flash attention partials ----------------
__global__ __launch_bounds__(256) void k_attn_part(const float* __restrict__ qkv,
                                                   float* __restrict__ part_o,
                                                   float* __restrict__ part_ml,
                                                   const int* M0, const int* M1, const int* M2)
{
    int z = blockIdx.z;
    int s = z / NSPLIT, part = z % NSPLIT;
    int head = blockIdx.y;
    int Ms = getM(s, M0, M1, M2);
    int q0 = blockIdx.x * 64;
    if (q0 >= Ms) return;
    int kstart = part * PLEN;
    if (kstart >= Ms) return;
    int kend = kstart + PLEN; if (kend > Ms) kend = Ms;

    __shared__ __align__(16) unsigned short kf[4][64][8];
    __shared__ __align__(16) unsigned short vf[2][2][64][8];
    __shared__ __align__(16) unsigned short pf[4][16][80];

    int tid = threadIdx.x;
    int wave = tid >> 6, lane = tid & 63;
    int c = lane & 15, g = lane >> 4;

    const float* base = qkv + (size_t)s * MC * 3 * DD;
    const float* Qb = base + head * DH;
    const float* Kb = base + DD + head * DH;
    const float* Vb = base + 2 * DD + head * DH;

    short8_t qfrag = {0,0,0,0,0,0,0,0};
    {
        int qr = q0 + wave * 16 + c;
        if (qr < Ms) {
            const float* qp = Qb + (size_t)qr * 3 * DD + g * 8;
            qfrag = pack8(*(const float4*)qp, *(const float4*)(qp + 4));
        }
    }

    f32x4 o0 = {0.f, 0.f, 0.f, 0.f}, o1 = {0.f, 0.f, 0.f, 0.f};
    f32x4 mreg = {-1e30f, -1e30f, -1e30f, -1e30f};
    f32x4 lreg = {0.f, 0.f, 0.f, 0.f};
    const float scale = 0.1767766952966369f;  // 1/sqrt(32)

    int sko = tid >> 2, sg = tid & 3;
    int s_nt = sko >> 4;
    int s_l  = (sko & 15) | (sg << 4);
    int s_ks = sko >> 5, s_kk = sko & 31;
    int s_j  = s_kk & 7, s_hi = (s_kk >> 3) & 3;
    int s_vnt = sg >> 1, s_db = (sg & 1) * 8;

    for (int kb = kstart; kb < kend; kb += 64) {
        __syncthreads();
        {
            int key = kb + sko;
            short8_t kv = {0,0,0,0,0,0,0,0};
            if (key < kend) {
                const float* kr = Kb + (size_t)key * 3 * DD + sg * 8;
                kv = pack8(*(const float4*)kr, *(const float4*)(kr + 4));
            }
            *(short8_t*)&kf[s_nt][s_l][0] = kv;
        }
        {
            int key = kb + sko;
            float4 a = make_float4(0.f, 0.f, 0.f, 0.f);
            float4 b = make_float4(0.f, 0.f, 0.f, 0.f);
            if (key < kend) {
                const float* vr = Vb + (size_t)key * 3 * DD + sg * 8;
                a = *(const float4*)vr;
                b = *(const float4*)(vr + 4);
            }
            unsigned short* vslot = &vf[s_ks][s_vnt][0][0];
            vslot[((s_db + 0) | (s_hi << 4)) * 8 + s_j] = f2bf(a.x);
            vslot[((s_db + 1) | (s_hi << 4)) * 8 + s_j] = f2bf(a.y);
            vslot[((s_db + 2) | (s_hi << 4)) * 8 + s_j] = f2bf(a.z);
            vslot[((s_db + 3) | (s_hi << 4)) * 8 + s_j] = f2bf(a.w);
            vslot[((s_db + 4) | (s_hi << 4)) * 8 + s_j] = f2bf(b.x);
            vslot[((s_db + 5) | (s_hi << 4)) * 8 + s_j] = f2bf(b.y);
            vslot[((s_db + 6) | (s_hi << 4)) * 8 + s_j] = f2bf(b.z);
            vslot[((s_db + 7) | (s_hi << 4)) * 8 + s_j] = f2bf(b.w);
        }
        __syncthreads();

        f32x4 zero = {0.f, 0.f, 0.f, 0.f};
        short8_t kf0 = *(const short8_t*)&kf[0][lane][0];
        short8_t kf1 = *(const short8_t*)&kf[1][lane][0];
        short8_t kf2 = *(const short8_t*)&kf[2][lane][0];
        short8_t kf3 = *(const short8_t*)&kf[3][lane][0];
        f32x4 a0 = __builtin_amdgcn_mfma_f32_16x16x32_bf16(qfrag, kf0, zero, 0, 0, 0);
        f32x4 a1 = __builtin_amdgcn_mfma_f32_16x16x32_bf16(qfrag, kf1, zero, 0, 0, 0);
        f32x4 a2 = __builtin_amdgcn_mfma_f32_16x16x32_bf16(qfrag, kf2, zero, 0, 0, 0);
        f32x4 a3 = __builtin_amdgcn_mfma_f32_16x16x32_bf16(qfrag, kf3, zero, 0, 0, 0);

        f32x4 neg = {-1e30f, -1e30f, -1e30f, -1e30f};
        a0 = (kb +  0 + c < kend) ? a0 * scale : neg;
        a1 = (kb + 16 + c < kend) ? a1 * scale : neg;
        a2 = (kb + 32 + c < kend) ? a2 * scale : neg;
        a3 = (kb + 48 + c < kend) ? a3 * scale : neg;

        f32x4 rmax = max4(max4(a0, a1), max4(a2, a3));
        rmax = max4(rmax, shflx4(rmax, 1));
        rmax = max4(rmax, shflx4(rmax, 2));
        rmax = max4(rmax, shflx4(rmax, 4));
        rmax = max4(rmax, shflx4(rmax, 8));
        f32x4 mnew = max4(mreg, rmax);
        f32x4 alpha = exp4(mreg - mnew);
        mreg = mnew;
        lreg = lreg * alpha;
        o0 = o0 * alpha;
        o1 = o1 * alpha;

        a0 = exp4(a0 - mnew);
        a1 = exp4(a1 - mnew);
        a2 = exp4(a2 - mnew);
        a3 = exp4(a3 - mnew);
        f32x4 rsum = (a0 + a1) + (a2 + a3);
        rsum = rsum + shflx4(rsum, 1);
        rsum = rsum + shflx4(rsum, 2);
        rsum = rsum + shflx4(rsum, 4);
        rsum = rsum + shflx4(rsum, 8);
        lreg = lreg + rsum;

        {
            unsigned short* prow = &pf[wave][0][0];
            int rb = g * 4;
            prow[(rb + 0) * 80 +  0 + c] = f2bf(a0[0]);
            prow[(rb + 1) * 80 +  0 + c] = f2bf(a0[1]);
            prow[(rb + 2) * 80 +  0 + c] = f2bf(a0[2]);
            prow[(rb + 3) * 80 +  0 + c] = f2bf(a0[3]);
            prow[(rb + 0) * 80 + 16 + c] = f2bf(a1[0]);
            prow[(rb + 1) * 80 + 16 + c] = f2bf(a1[1]);
            prow[(rb + 2) * 80 + 16 + c] = f2bf(a1[2]);
            prow[(rb + 3) * 80 + 16 + c] = f2bf(a1[3]);
            prow[(rb + 0) * 80 + 32 + c] = f2bf(a2[0]);
            prow[(rb + 1) * 80 + 32 + c] = f2bf(a2[1]);
            prow[(rb + 2) * 80 + 32 + c] = f2bf(a2[2]);
            prow[(rb + 3) * 80 + 32 + c] = f2bf(a2[3]);
            prow[(rb + 0) * 80 + 48 + c] = f2bf(a3[0]);
            prow[(rb + 1) * 80 + 48 + c] = f2bf(a3[1]);
            prow[(rb + 2) * 80 + 48 + c] = f2bf(a3[2]);
            prow[(rb + 3) * 80 + 48 + c] = f2bf(a3[3]);
        }

        {
            short8_t p0 = *(const short8_t*)&pf[wave][c][ 0 + g * 8];
            short8_t v00 = *(const short8_t*)&vf[0][0][lane][0];
            short8_t v01 = *(const short8_t*)&vf[0][1][lane][0];
            o0 = __builtin_amdgcn_mfma_f32_16x16x32_bf16(p0, v00, o0, 0, 0, 0);
            o1 = __builtin_amdgcn_mfma_f32_16x16x32_bf16(p0, v01, o1, 0, 0, 0);
            short8_t p1 = *(const short8_t*)&pf[wave][c][32 + g * 8];
            short8_t v10 = *(const short8_t*)&vf[1][0][lane][0];
            short8_t v11 = *(const short8_t*)&vf[1][1][lane][0];
            o0 = __builtin_amdgcn_mfma_f32_16x16x32_bf16(p1, v10, o0, 0, 0, 0);
            o1 = __builtin_amdgcn_mfma_f32_16x16x32_bf16(p1, v11, o1, 0, 0, 0);
        }
    }

    int rec = ((s * NHH + head) * 64 + blockIdx.x) * NSPLIT + part;
    float* po = part_o + (size_t)rec * 2048;
    int qb = wave * 16 + g * 4;
    po[(qb + 0) * 32 + c] = o0[0];
    po[(qb + 1) * 32 + c] = o0[1];
    po[(qb + 2) * 32 + c] = o0[2];
    po[(qb + 3) * 32 + c] = o0[3];
    po[(qb + 0) * 32 + 16 + c] = o1[0];
    po[(qb + 1) * 32 + 16 + c] = o1[1];
    po[(qb + 2) * 32 + 16 + c] = o1[2];
    po[(qb + 3) * 32 + 16 + c] = o1[3];
    if (c == 0) {
        part_ml[rec * 128 + qb + 0] = mreg[0];
        part_ml[rec * 128 + qb + 1] = mreg[1];
        part_ml[rec * 128 + qb + 2] = mreg[2];
        part_ml[rec * 128 + qb + 3] = mreg[3];
        part_ml[rec * 128 + 64 + qb + 0] = lreg[0];
        part_ml[rec * 128 + 64 + qb + 1] = lreg[1];
        part_ml[rec * 128 + 64 + qb + 2] = lreg[2];
        part_ml[rec * 128 + 64 + qb + 3] = lreg[3];
    }
}

// ---------------- merge split-K partials ----------------
__global__ void k_attn_comb(const float* __restrict__ part_o, const float* __restrict__ part_ml,
                            float* __restrict__ attno,
                            const int* M0, const int* M1, const int* M2)
{
    int s = blockIdx.z, head = blockIdx.y;
    int Ms = getM(s, M0, M1, M2);
    int q0 = blockIdx.x * 64;
    if (q0 >= Ms) return;
    int tid = threadIdx.x;
    int qi = tid >> 2, sub = tid & 3;
    int nparts = (Ms + PLEN - 1) / PLEN;
    if (nparts > NSPLIT) nparts = NSPLIT;
    int recbase = ((s * NHH + head) * 64 + blockIdx.x) * NSPLIT;

    float m = -1e30f;
    for (int p = 0; p < nparts; ++p)
        m = fmaxf(m, part_ml[(recbase + p) * 128 + qi]);
    float L = 0.f;
    float4 A0 = {0,0,0,0}, A1 = {0,0,0,0};
    for (int p = 0; p < nparts; ++p) {
        float mp = part_ml[(recbase + p) * 128 + qi];
        float lp = part_ml[(recbase + p) * 128 + 64 + qi];
        float w = __expf(mp - m);
        L += lp * w;
        const float* po = part_o + (size_t)(recbase + p) * 2048;
        float4 a = *(const float4*)(po + qi * 32 + sub * 4);
        float4 b = *(const float4*)(po + qi * 32 + (sub + 4) * 4);
        A0.x += a.x * w; A0.y += a.y * w; A0.z += a.z * w; A0.w += a.w * w;
        A1.x += b.x * w; A1.y += b.y * w; A1.z += b.z * w; A1.w += b.w * w;
    }
    if (q0 + qi < Ms) {
        float inv = 1.0f / fmaxf(L, 1e-30f);
        size_t orow = ((size_t)s * MC + q0 + qi) * DD + head * DH;
        float4 r0 = make_float4(A0.x * inv, A0.y * inv, A0.z * inv, A0.w * inv);
        float4 r1 = make_float4(A1.x * inv, A1.y * inv, A1.z * inv, A1.w * inv);
        *(float4*)(attno + orow + sub * 4) = r0;
        *(float4*)(attno + orow + (sub + 4) * 4) = r1;
    }
}

// ---------------- x1 = LN1(macro + attno @ Wo.T + bo) ----------------
__global__ void k_ln1(const float* __restrict__ macro, const float* __restrict__ attno,
                      const float* __restrict__ Wo, const float* __restrict__ bo,
                      const float* __restrict__ g, const float* __restrict__ b,
                      float* __restrict__ x1,
                      const int* M0, const int* M1, const int* M2)
{
    int s = blockIdx.y;
    int Ms = getM(s, M0, M1, M2);
    int m = blockIdx.x;
    if (m >= Ms) return;
    __shared__ __align__(16) float os[DD];
    __shared__ float red[4];
    int d = threadIdx.x;  // 128
    size_t row = (size_t)s * MC + m;
    os[d] = attno[row * DD + d];
    __syncthreads();
    const float* w = Wo + ((size_t)s * DD + d) * DD;
    float acc = bo[s * DD + d];
    for (int k = 0; k < DD; k += 4) {
        float4 w4 = *(const float4*)(w + k);
        float4 m4 = *(const float4*)&os[k];
        acc += w4.x * m4.x + w4.y * m4.y + w4.z * m4.z + w4.w * m4.w;
    }
    float xin = macro[row * DD + d] + acc;
    float sum = xin, sq = xin * xin;
    for (int off = 32; off >= 1; off >>= 1) { sum += __shfl_xor(sum, off); sq += __shfl_xor(sq, off); }
    if ((d & 63) == 0) { red[d >> 6] = sum; red[2 + (d >> 6)] = sq; }
    __syncthreads();
    sum = red[0] + red[1]; sq = red[2] + red[3];
    float mean = sum * (1.0f / DD);
    float var = fmaxf(sq * (1.0f / DD) - mean * mean, 0.0f);
    float xh = (xin - mean) * rsqrtf(var + 1e-5f);
    x1[row * DD + d] = xh * g[s * DD + d] + b[s * DD + d];
}

// ---------------- x2 = LN2(x1 + relu(x1@W1.T+b1)@W2.T + b2) ----------------
__global__ void k_ffn(const float* __restrict__ x1,
                      const float* __restrict__ W1, const float* __restrict__ b1,
                      const float* __restrict__ W2, const float* __restrict__ b2,
                      const float* __restrict__ g, const float* __restrict__ bb,
                      float* __restrict__ x2,
                      const int* M0, const int* M1, const int* M2)
{
    int s = blockIdx.y;
    int Ms = getM(s, M0, M1, M2);
    int m = blockIdx.x;
    if (m >= Ms) return;
    __shared__ __align__(16) float xr[DD];
    __shared__ __align__(16) float ts[FFD];
    __shared__ float red[8];
    int tid = threadIdx.x;  // 256
    size_t row = (size_t)s * MC + m;
    if (tid < DD) xr[tid] = x1[row * DD + tid];
    __syncthreads();
    {
        const float* w = W1 + ((size_t)s * FFD + tid) * DD;
        float acc = b1[s * FFD + tid];
        for (int k = 0; k < DD; k += 4) {
            float4 w4 = *(const float4*)(w + k);
            float4 m4 = *(const float4*)&xr[k];
            acc += w4.x * m4.x + w4.y * m4.y + w4.z * m4.z + w4.w * m4.w;
        }
        ts[tid] = fmaxf(acc, 0.0f);
    }
    __syncthreads();
    float xin = 0.0f;
    if (tid < DD) {
        const float* w = W2 + ((size_t)s * DD + tid) * FFD;
        float acc = b2[s * DD + tid];
        for (int k = 0; k < FFD; k += 4) {
            float4 w4 = *(const float4*)(w + k);
            float4 m4 = *(const float4*)&ts[k];
            acc += w4.x * m4.x + w4.y * m4.y + w4.z * m4.z + w4.w * m4.w;
        }
        xin = xr[tid] + acc;
    }
    float sum = xin, sq = xin * xin;
    for (int off = 32; off >= 1; off >>= 1) { sum += __shfl_xor(sum, off); sq += __shfl_xor(sq, off); }
    if ((tid & 63) == 0) { red[tid >> 6] = sum; red[4 + (tid >> 6)] = sq; }
    __syncthreads();
    sum = red[0] + red[1] + red[2] + red[3];
    sq = red[4] + red[5] + red[6] + red[7];
    float mean = sum * (1.0f / DD);
    float var = fmaxf(sq * (1.0f / DD) - mean * mean, 0.0f);
    if (tid < DD) {
        float xh = (xin - mean) * rsqrtf(var + 1e-5f);
        x2[row * DD + tid] = xh * g[s * DD + tid] + bb[s * DD + tid];
    }
}

// ---------------- y_s = x2_s @ Wf[:, 128*(s+1):128*(s+2)].T ----------------
__global__ void k_yproj(const float* __restrict__ x2, const float* __restrict__ Wf,
                        float* __restrict__ y,
                        const int* M0, const int* M1, const int* M2)
{
    int s = blockIdx.y;
    int Ms = getM(s, M0, M1, M2);
    int m = blockIdx.x;
    if (m >= Ms) return;
    __shared__ __align__(16) float xr[DD];
    int d = threadIdx.x;  // 128
    size_t row = (size_t)s * MC + m;
    xr[d] = x2[row * DD + d];
    __syncthreads();
    const float* w = Wf + (size_t)d * (4 * DD) + (s + 1) * DD;
    float acc = 0.0f;
    for (int k = 0; k < DD; k += 4) {
        float4 w4 = *(const float4*)(w + k);
        float4 m4 = *(const float4*)&xr[k];
        acc += w4.x * m4.x + w4.y * m4.y + w4.z * m4.z + w4.w * m4.w;
    }
    y[row * DD + d] = acc;
}

// ---------------- out = h@B0 (bf16 MFMA) + gathers + bf: NO LDS, NO barriers ----------------
__global__ __launch_bounds__(256) void k_final(const float* __restrict__ h,
                                               const unsigned short* __restrict__ b0f,
                                               const float* __restrict__ y,
                                               const int* __restrict__ inv0,
                                               const int* __restrict__ inv1,
                                               const int* __restrict__ inv2,
                                               const float* __restrict__ bf,
                                               float* __restrict__ out, int N)
{
    int tid = threadIdx.x;
    int wave = tid >> 6, lane = tid & 63;
    int c = lane & 15, g = lane >> 4;
    const float* y0 = y;
    const float* y1 = y + (size_t)MC * DD;
    const float* y2 = y + (size_t)2 * MC * DD;

    int ntasks = (N + 15) >> 4;                 // 16-particle tasks
    int task = blockIdx.x * 4 + wave;
    int tstride = gridDim.x * 4;

    for (; task < ntasks; task += tstride) {
        int p = task * 16 + c;
        bool ok = (p < N);

        short8_t hfr0 = {0,0,0,0,0,0,0,0};
        short8_t hfr1 = hfr0, hfr2 = hfr0, hfr3 = hfr0;
        int i0 = 0, i1 = 0, i2 = 0;
        if (ok) {
            const float* hrow = h + (size_t)p * DD + g * 8;
            hfr0 = pack8(*(const float4*)(hrow +  0), *(const float4*)(hrow +  4));
            hfr1 = pack8(*(const float4*)(hrow + 32), *(const float4*)(hrow + 36));
            hfr2 = pack8(*(const float4*)(hrow + 64), *(const float4*)(hrow + 68));
            hfr3 = pack8(*(const float4*)(hrow + 96), *(const float4*)(hrow + 100));
            i0 = inv0[p]; i1 = inv1[p]; i2 = inv2[p];
        }
        const float* yr0 = y0 + (size_t)i0 * DD;
        const float* yr1 = y1 + (size_t)i1 * DD;
        const float* yr2 = y2 + (size_t)i2 * DD;

#pragma unroll
        for (int nt = 0; nt < 8; ++nt) {
            f32x4 acc = {0.f, 0.f, 0.f, 0.f};
            {
                short8_t w0 = *(const short8_t*)(b0f + (size_t)((nt * 4 + 0) * 64 + lane) * 8);
                acc = __builtin_amdgcn_mfma_f32_16x16x32_bf16(w0, hfr0, acc, 0, 0, 0);
                short8_t w1 = *(const short8_t*)(b0f + (size_t)((nt * 4 + 1) * 64 + lane) * 8);
                acc = __builtin_amdgcn_mfma_f32_16x16x32_bf16(w1, hfr1, acc, 0, 0, 0);
                short8_t w2 = *(const short8_t*)(b0f + (size_t)((nt * 4 + 2) * 64 + lane) * 8);
                acc = __builtin_amdgcn_mfma_f32_16x16x32_bf16(w2, hfr2, acc, 0, 0, 0);
                short8_t w3 = *(const short8_t*)(b0f + (size_t)((nt * 4 + 3) * 64 + lane) * 8);
                acc = __builtin_amdgcn_mfma_f32_16x16x32_bf16(w3, hfr3, acc, 0, 0, 0);
            }
            if (ok) {
                int d = nt * 16 + g * 4;
                float4 g0 = *(const float4*)(yr0 + d);
                float4 g1 = *(const float4*)(yr1 + d);
                float4 g2 = *(const float4*)(yr2 + d);
                float4 b4 = *(const float4*)(bf + d);
                float4 r;
                r.x = acc[0] + g0.x + g1.x + g2.x + b4.x;
                r.y = acc[1] + g0.y + g1.y + g2.y + b4.y;
                r.z = acc[2] + g0.z + g1.z + g2.z + b4.z;
                r.w = acc[3] + g0.w + g1.w + g2.w + b4.w;
                *(float4*)(out + (size_t)p * DD + d) = r;
            }
        }
    }
}

extern "C" void kernel_launch(void* const* d_in, const int* in_sizes, int n_in,
                              void* d_out, int out_size, void* d_ws, size_t ws_size,
                              hipStream_t stream) {
    (void)n_in; (void)out_size; (void)ws_size;
    const float* h   = (const float*)d_in[0];
    const int* inv0  = (const int*)d_in[2];
    const int* inv1  = (const int*)d_in[3];
    const int* inv2  = (const int*)d_in[4];
    const int* M0    = (const int*)d_in[5];
    const int* M1    = (const int*)d_in[6];
    const int* M2    = (const int*)d_in[7];
    const float* Wqkv = (const float*)d_in[8];
    const float* bqkv = (const float*)d_in[9];
    const float* Wo   = (const float*)d_in[10];
    const float* bo   = (const float*)d_in[11];
    const float* ln1s = (const float*)d_in[12];
    const float* ln1b = (const float*)d_in[13];
    const float* W1   = (const float*)d_in[14];
    const float* b1   = (const float*)d_in[15];
    const float* W2   = (const float*)d_in[16];
    const float* b2   = (const float*)d_in[17];
    const float* ln2s = (const float*)d_in[18];
    const float* ln2b = (const float*)d_in[19];
    const float* Wf   = (const float*)d_in[20];
    const float* bf   = (const float*)d_in[21];
    int N = in_sizes[0] / DD;

    float* ws      = (float*)d_ws;
    float* macro   = ws;                                    // NS*MC*DD
    float* counts  = macro + (size_t)NS * MC * DD;          // NS*MC
    float* qkvb    = counts + (size_t)NS * MC;              // NS*MC*3*DD
    float* attno   = qkvb + (size_t)NS * MC * 3 * DD;       // NS*MC*DD
    float* x1      = attno + (size_t)NS * MC * DD;          // NS*MC*DD
    float* x2      = x1 + (size_t)NS * MC * DD;             // NS*MC*DD
    float* yb      = x2 + (size_t)NS * MC * DD;             // NS*MC*DD
    float* b0f_f   = yb + (size_t)NS * MC * DD;             // DD*DD floats of space (b0f uses half)
    unsigned short* b0f = (unsigned short*)b0f_f;
    float* part_o  = b0f_f + (size_t)DD * DD;               // NS*NHH*64*NSPLIT*2048
    float* part_ml = part_o + (size_t)NS * NHH * 64 * NSPLIT * 2048;  // NS*NHH*64*NSPLIT*128
    int* ip        = (int*)(part_ml + (size_t)NS * NHH * 64 * NSPLIT * 128);
    int* parent10  = ip;                // MC
    int* parent21  = parent10 + MC;     // 512
    int* cnt_i     = parent21 + 512;    // MC
    int* fill      = cnt_i + MC;        // MC
    int* offs      = fill + MC;         // MC
    int* order     = offs + MC;         // N

    float* sum0 = macro;
    float* sum1 = macro + (size_t)1 * MC * DD;
    float* sum2 = macro + (size_t)2 * MC * DD;
    float* cnt0 = counts;
    float* cnt1 = counts + MC;
    float* cnt2 = counts + 2 * MC;

    hipMemsetAsync(macro, 0, ((size_t)NS * MC * DD + NS * MC) * sizeof(float), stream);
    hipMemsetAsync(cnt_i, 0, (size_t)2 * MC * sizeof(int), stream);

    int nb = (N + 255) / 256;
    k_parent<<<nb, 256, 0, stream>>>(inv0, inv1, inv2, parent10, parent21, cnt_i, N);
    k_scan<<<1, 1024, 0, stream>>>(cnt_i, offs);
    k_place<<<nb, 256, 0, stream>>>(inv0, offs, fill, order, N);
    k_pool<<<MC, 256, 0, stream>>>(h, order, offs, cnt_i, sum0, cnt0, M0);
    k_rollup<<<(MC * DD) / 256, 256, 0, stream>>>(sum0, cnt0, parent10, sum1, cnt1, M0, MC);
    k_rollup<<<(512 * DD) / 256, 256, 0, stream>>>(sum1, cnt1, parent21, sum2, cnt2, M1, 512);
    k_finalize<<<(NS * MC * DD) / 256, 256, 0, stream>>>(macro, counts, M0, M1, M2);
    k_b0frag<<<64, 256, 0, stream>>>(Wf, b0f);
    k_qkv<<<dim3(MC / 8, NS), 256, 0, stream>>>(macro, Wqkv, bqkv, qkvb, M0, M1, M2);
    k_attn_part<<<dim3(MC / 64, NHH, NS * NSPLIT), 256, 0, stream>>>(qkvb, part_o, part_ml, M0, M1, M2);
    k_attn_comb<<<dim3(MC / 64, NHH, NS), 256, 0, stream>>>(part_o, part_ml, attno, M0, M1, M2);
    k_ln1<<<dim3(MC, NS), 128, 0, stream>>>(macro, attno, Wo, bo, ln1s, ln1b, x1, M0, M1, M2);
    k_ffn<<<dim3(MC, NS), 256, 0, stream>>>(x1, W1, b1, W2, b2, ln2s, ln2b, x2, M0, M1, M2);
    k_yproj<<<dim3(MC, NS), 128, 0, stream>>>(x2, Wf, yb, M0, M1, M2);
    k_final<<<2048, 256, 0, stream>>>(h, b0f, yb, inv0, inv1, inv2, bf, (float*)d_out, N);
}